// Round 3
// baseline (6423.934 us; speedup 1.0000x reference)
//
#include <hip/hip_runtime.h>
#include <hip/hip_bf16.h>
#include <math.h>

#define DEV __device__ __forceinline__

DEV float ldx(const void* p, size_t i, bool bf) {
  return bf ? __bfloat162float(((const __hip_bfloat16*)p)[i]) : ((const float*)p)[i];
}

DEV float gelu_f(float x) { return 0.5f * x * (1.0f + erff(x * 0.70710678118654752f)); }

DEV float block_reduce(float v, bool is_sum, float* red) {
#pragma unroll
  for (int off = 32; off > 0; off >>= 1) {
    float o = __shfl_down(v, off, 64);
    v = is_sum ? (v + o) : fmaxf(v, o);
  }
  __syncthreads();
  if ((threadIdx.x & 63) == 0) red[threadIdx.x >> 6] = v;
  __syncthreads();
  return is_sum ? (red[0] + red[1] + red[2] + red[3])
                : fmaxf(fmaxf(red[0], red[1]), fmaxf(red[2], red[3]));
}

__global__ void detect_kernel(const unsigned* __restrict__ ip_g, int* __restrict__ flag) {
  if (threadIdx.x == 0 && blockIdx.x == 0)
    *flag = (ip_g[0] == 0x3F800000u) ? 0 : 1;
}

// C = act(A@W + bias) (+resid). A: MxK, W: KxN (element offset woff),
// bias: N @ element offset boff (input dtype) or null. Tile 64x128.
__global__ __launch_bounds__(256) void gemm_kernel(
    const void* __restrict__ A, int a_inp, const void* __restrict__ W, int w_inp,
    size_t woff, const void* __restrict__ bias, size_t boff,
    const float* __restrict__ resid, float* __restrict__ C,
    int M, int K, int N, int act, const int* __restrict__ flagp) {
  const int KS = 16;
  __shared__ __align__(16) float As[KS][64 + 4];
  __shared__ __align__(16) float Ws[KS][128 + 4];
  const bool bfin = (*flagp != 0);
  const bool abf = a_inp && bfin;
  const bool wbf = w_inp && bfin;
  int tid = threadIdx.x;
  int tx = tid & 15, ty = tid >> 4;
  int row0 = blockIdx.y * 64, col0 = blockIdx.x * 128;
  float acc[4][8] = {};
  const int arow = tid >> 2;
  const int akk0 = (tid & 3) * 4;
  const int wkk = tid >> 4;
  const int wc0 = (tid & 15) * 8;

  for (int k0 = 0; k0 < K; k0 += KS) {
    {
      size_t base = (size_t)(row0 + arow) * K + k0 + akk0;
      As[akk0 + 0][arow] = ldx(A, base + 0, abf);
      As[akk0 + 1][arow] = ldx(A, base + 1, abf);
      As[akk0 + 2][arow] = ldx(A, base + 2, abf);
      As[akk0 + 3][arow] = ldx(A, base + 3, abf);
    }
    {
      size_t base = woff + (size_t)(k0 + wkk) * N + col0 + wc0;
#pragma unroll
      for (int v = 0; v < 8; ++v) Ws[wkk][wc0 + v] = ldx(W, base + v, wbf);
    }
    __syncthreads();
#pragma unroll
    for (int kk = 0; kk < KS; ++kk) {
      float4 av = *(const float4*)&As[kk][ty * 4];
      float4 w0 = *(const float4*)&Ws[kk][tx * 8];
      float4 w1 = *(const float4*)&Ws[kk][tx * 8 + 4];
      float a[4] = {av.x, av.y, av.z, av.w};
      float w[8] = {w0.x, w0.y, w0.z, w0.w, w1.x, w1.y, w1.z, w1.w};
#pragma unroll
      for (int u = 0; u < 4; ++u)
#pragma unroll
        for (int v = 0; v < 8; ++v) acc[u][v] = fmaf(a[u], w[v], acc[u][v]);
    }
    __syncthreads();
  }
#pragma unroll
  for (int u = 0; u < 4; ++u) {
    int r = row0 + ty * 4 + u;
    size_t rb = (size_t)r * N;
#pragma unroll
    for (int v = 0; v < 8; ++v) {
      int c = col0 + tx * 8 + v;
      float val = acc[u][v];
      if (bias) val += ldx(bias, boff + c, bfin);
      if (act) val = gelu_f(val);
      if (resid) val += resid[rb + c];
      C[rb + c] = val;
    }
  }
}

__global__ __launch_bounds__(256) void ln_kernel(
    const float* __restrict__ X, float* __restrict__ Y,
    const void* __restrict__ g, const void* __restrict__ b, size_t goff,
    int D, int do_gelu, const int* __restrict__ flagp) {
  __shared__ float red[4];
  const bool bfin = (*flagp != 0);
  int row = blockIdx.x;
  const float* x = X + (size_t)row * D;
  float s = 0.f, s2 = 0.f;
  for (int d = threadIdx.x; d < D; d += 256) {
    float v = x[d];
    s += v;
    s2 += v * v;
  }
  s = block_reduce(s, true, red);
  s2 = block_reduce(s2, true, red);
  float mean = s / D;
  float var = s2 / D - mean * mean;
  float inv = rsqrtf(var + 1e-5f);
  for (int d = threadIdx.x; d < D; d += 256) {
    float v = (x[d] - mean) * inv * ldx(g, goff + d, bfin) + ldx(b, goff + d, bfin);
    if (do_gelu) v = gelu_f(v);
    Y[(size_t)row * D + d] = v;
  }
}

#define AROWS 8
__global__ __launch_bounds__(256) void attn_kernel(
    const float* __restrict__ QKV, float* __restrict__ O,
    const void* __restrict__ Abias, const void* __restrict__ ebW,
    const void* __restrict__ ebs, size_t eoff_w, size_t eoff_s,
    int B_, int N, int NH_, int HD, const int* __restrict__ flagp) {
  __shared__ __align__(16) float qs[AROWS][64];
  __shared__ float sc[AROWS][512];
  __shared__ float red[4];
  __shared__ float ored[4][AROWS][64];
  const bool bfin = (*flagp != 0);
  int tid = threadIdx.x;
  int ngrp = N / AROWS;
  int blk = blockIdx.x;
  int rg = blk % ngrp;
  int t2 = blk / ngrp;
  int h = t2 % NH_;
  int b = t2 / NH_;
  int n0 = rg * AROWS;
  int C3 = 3 * NH_ * HD;
  const float* base = QKV + (size_t)b * N * C3;
  float scale = rsqrtf((float)HD);
  bool hasb = (Abias != nullptr);
  float bscale = 0.f;
  if (hasb) bscale = ldx(ebs, eoff_s, bfin) * ldx(ebW, eoff_w + h, bfin);

  for (int i = tid; i < AROWS * HD; i += 256) {
    int r = i / HD, d = i % HD;
    qs[r][d] = base[(size_t)(n0 + r) * C3 + h * HD + d];
  }
  __syncthreads();

  for (int m = tid; m < N; m += 256) {
    const float* krow = base + (size_t)m * C3 + NH_ * HD + h * HD;
    float acc[AROWS];
#pragma unroll
    for (int r = 0; r < AROWS; ++r) acc[r] = 0.f;
    for (int d = 0; d < HD; d += 4) {
      float4 kv = *(const float4*)(krow + d);
#pragma unroll
      for (int r = 0; r < AROWS; ++r) {
        float4 qv = *(const float4*)&qs[r][d];
        acc[r] = fmaf(qv.x, kv.x, acc[r]);
        acc[r] = fmaf(qv.y, kv.y, acc[r]);
        acc[r] = fmaf(qv.z, kv.z, acc[r]);
        acc[r] = fmaf(qv.w, kv.w, acc[r]);
      }
    }
#pragma unroll
    for (int r = 0; r < AROWS; ++r) {
      float v = acc[r] * scale;
      if (hasb) v += bscale * ldx(Abias, ((size_t)b * N + n0 + r) * N + m, bfin);
      sc[r][m] = v;
    }
  }
  __syncthreads();

  for (int r = 0; r < AROWS; ++r) {
    float lm = -1e30f;
    for (int m = tid; m < N; m += 256) lm = fmaxf(lm, sc[r][m]);
    float mx = block_reduce(lm, false, red);
    float ls = 0.f;
    for (int m = tid; m < N; m += 256) {
      float p = expf(sc[r][m] - mx);
      sc[r][m] = p;
      ls += p;
    }
    float ssum = block_reduce(ls, true, red);
    float invs = 1.f / ssum;
    for (int m = tid; m < N; m += 256) sc[r][m] *= invs;
  }
  __syncthreads();

  int d = tid & 63;
  int seg = tid >> 6;
  int mlo = seg * (N / 4), mhi = mlo + N / 4;
  float oacc[AROWS];
#pragma unroll
  for (int r = 0; r < AROWS; ++r) oacc[r] = 0.f;
  for (int m = mlo; m < mhi; ++m) {
    float vv = base[(size_t)m * C3 + 2 * NH_ * HD + h * HD + d];
#pragma unroll
    for (int r = 0; r < AROWS; ++r) oacc[r] = fmaf(sc[r][m], vv, oacc[r]);
  }
#pragma unroll
  for (int r = 0; r < AROWS; ++r) ored[seg][r][d] = oacc[r];
  __syncthreads();
  for (int i = tid; i < AROWS * 64; i += 256) {
    int r = i / 64, dd = i % 64;
    float o = ored[0][r][dd] + ored[1][r][dd] + ored[2][r][dd] + ored[3][r][dd];
    O[((size_t)b * N + n0 + r) * (NH_ * HD) + h * HD + dd] = o;
  }
}

__global__ __launch_bounds__(256) void transpose_kernel(
    const float* __restrict__ X, float* __restrict__ Y, int R, int C) {
  __shared__ float t[32][33];
  const float* xb = X + (size_t)blockIdx.z * R * C;
  float* yb = Y + (size_t)blockIdx.z * R * C;
  int c0 = blockIdx.x * 32, r0 = blockIdx.y * 32;
  int tx = threadIdx.x & 31, ty = threadIdx.x >> 5;
  for (int i = ty; i < 32; i += 8) t[i][tx] = xb[(size_t)(r0 + i) * C + c0 + tx];
  __syncthreads();
  for (int i = ty; i < 32; i += 8) yb[(size_t)(c0 + i) * R + r0 + tx] = t[tx][i];
}

__global__ __launch_bounds__(256) void build_s_kernel(
    const void* __restrict__ W, float* __restrict__ S, int D, int Kk,
    const int* __restrict__ flagp) {
  const bool bfin = (*flagp != 0);
  int i = blockIdx.x * 256 + threadIdx.x;
  if (i >= D * D) return;
  int d = i / D, e = i % D;
  float s = 0.f;
  for (int k = 0; k < Kk; ++k) {
    s += ldx(W, (size_t)k * D * D + i, bfin);
    s += ldx(W, (size_t)k * D * D + (size_t)e * D + d, bfin);
  }
  S[i] = s / (2.0f * Kk);
}

// G = T @ Hf^T (+db), softplus, upper-tri scatter. OUTPUT IS FLOAT32.
__global__ __launch_bounds__(256) void dec_out_kernel(
    const float* __restrict__ T, const float* __restrict__ Hf,
    const void* __restrict__ dec_b, float* __restrict__ out,
    int Nn, int Dd, const int* __restrict__ flagp) {
  const int KS = 16;
  __shared__ __align__(16) float As[KS][64 + 4];
  __shared__ __align__(16) float Bs[KS][64 + 4];
  const bool bfin = (*flagp != 0);
  int ntile = Nn / 64;
  int tidx = blockIdx.x;
  int bb = blockIdx.y;
  int it = 0, rem = tidx;
  while (rem >= ntile - it) { rem -= ntile - it; ++it; }
  int jt = it + rem;
  int i0 = it * 64, j0 = jt * 64;
  const float* Tb = T + (size_t)bb * Nn * Dd;
  const float* Hb = Hf + (size_t)bb * Nn * Dd;
  int tid = threadIdx.x;
  int tx = tid & 15, ty = tid >> 4;
  const int arow = tid >> 2;
  const int akk0 = (tid & 3) * 4;
  float acc[4][4] = {};
  for (int k0 = 0; k0 < Dd; k0 += KS) {
    {
      const float4 a = *(const float4*)(Tb + (size_t)(i0 + arow) * Dd + k0 + akk0);
      As[akk0 + 0][arow] = a.x;
      As[akk0 + 1][arow] = a.y;
      As[akk0 + 2][arow] = a.z;
      As[akk0 + 3][arow] = a.w;
      const float4 b = *(const float4*)(Hb + (size_t)(j0 + arow) * Dd + k0 + akk0);
      Bs[akk0 + 0][arow] = b.x;
      Bs[akk0 + 1][arow] = b.y;
      Bs[akk0 + 2][arow] = b.z;
      Bs[akk0 + 3][arow] = b.w;
    }
    __syncthreads();
#pragma unroll
    for (int kk = 0; kk < KS; ++kk) {
      float4 av = *(const float4*)&As[kk][ty * 4];
      float4 bv = *(const float4*)&Bs[kk][tx * 4];
      float a[4] = {av.x, av.y, av.z, av.w};
      float w[4] = {bv.x, bv.y, bv.z, bv.w};
#pragma unroll
      for (int u = 0; u < 4; ++u)
#pragma unroll
        for (int v = 0; v < 4; ++v) acc[u][v] = fmaf(a[u], w[v], acc[u][v]);
    }
    __syncthreads();
  }
  float db = ldx(dec_b, 0, bfin);
  size_t obase = (size_t)bb * ((size_t)Nn * (Nn - 1) / 2);
#pragma unroll
  for (int u = 0; u < 4; ++u) {
    int i = i0 + ty * 4 + u;
#pragma unroll
    for (int v = 0; v < 4; ++v) {
      int j = j0 + tx * 4 + v;
      if (j > i) {
        float x = acc[u][v] + db;
        float sp = (x > 30.f) ? x : log1pf(expf(x));
        size_t off = (size_t)i * (2 * Nn - i - 1) / 2 + (j - i - 1);
        out[obase + off] = sp;
      }
    }
  }
}

extern "C" void kernel_launch(void* const* d_in, const int* in_sizes, int n_in,
                              void* d_out, int out_size, void* d_ws, size_t ws_size,
                              hipStream_t stream) {
  const void *A_lr = d_in[0], *X_lr = d_in[1], *ip_W = d_in[2], *ip_b = d_in[3],
             *ip_g = d_in[4], *ip_bt = d_in[5], *e_n1g = d_in[6], *e_n1b = d_in[7],
             *e_qkvW = d_in[8], *e_qkvb = d_in[9], *e_projW = d_in[10],
             *e_projb = d_in[11], *e_ebW = d_in[12], *e_ebs = d_in[13],
             *e_n2g = d_in[14], *e_n2b = d_in[15], *e_f1W = d_in[16],
             *e_f1b = d_in[17], *e_f2W = d_in[18], *e_f2b = d_in[19],
             *encn_g = d_in[20], *encn_b = d_in[21], *up1W = d_in[22],
             *up1b = d_in[23], *up2W = d_in[24], *up2b = d_in[25],
             *r_n1g = d_in[26], *r_n1b = d_in[27], *r_qkvW = d_in[28],
             *r_qkvb = d_in[29], *r_projW = d_in[30], *r_projb = d_in[31],
             *r_n2g = d_in[32], *r_n2b = d_in[33], *r_f1W = d_in[34],
             *r_f1b = d_in[35], *r_f2W = d_in[36], *r_f2b = d_in[37],
             *hrn_g = d_in[38], *hrn_b = d_in[39], *dec_W = d_in[40],
             *dec_b = d_in[41];

  const int Bb = 16, NLR = 256, NHR = 512, Dm = 512, NHh = 8, HD = 64, FF = 2048, Ll = 4;

  float* ws = (float*)d_ws;
  float* H = ws;
  float* XN = ws + 4194304;
  float* AO = ws + 8388608;
  float* BIG = ws + 12582912;
  float* Tt = AO;   // decoder-time alias (AO dead)
  float* Ss = BIG;  // decoder-time alias (BIG dead)
  int* flag = (int*)(ws + 29360128);

  detect_kernel<<<1, 64, 0, stream>>>((const unsigned*)ip_g, flag);

  // ---- input projection ----
  gemm_kernel<<<dim3(4, 64), 256, 0, stream>>>(
      X_lr, 1, ip_W, 1, 0, ip_b, 0, nullptr, XN, Bb * NLR, NLR, Dm, 0, flag);
  ln_kernel<<<Bb * NLR, 256, 0, stream>>>(XN, H, ip_g, ip_bt, 0, Dm, 1, flag);

  // ---- encoder layers ----
  for (int l = 0; l < Ll; ++l) {
    ln_kernel<<<Bb * NLR, 256, 0, stream>>>(H, XN, e_n1g, e_n1b, (size_t)l * Dm, Dm, 0, flag);
    gemm_kernel<<<dim3(12, 64), 256, 0, stream>>>(
        XN, 0, e_qkvW, 1, (size_t)l * Dm * 3 * Dm, e_qkvb, (size_t)l * 3 * Dm,
        nullptr, BIG, Bb * NLR, Dm, 3 * Dm, 0, flag);
    attn_kernel<<<Bb * NHh * (NLR / AROWS), 256, 0, stream>>>(
        BIG, AO, A_lr, e_ebW, e_ebs, (size_t)l * NHh, (size_t)l, Bb, NLR, NHh, HD, flag);
    gemm_kernel<<<dim3(4, 64), 256, 0, stream>>>(
        AO, 0, e_projW, 1, (size_t)l * Dm * Dm, e_projb, (size_t)l * Dm,
        H, H, Bb * NLR, Dm, Dm, 0, flag);
    ln_kernel<<<Bb * NLR, 256, 0, stream>>>(H, XN, e_n2g, e_n2b, (size_t)l * Dm, Dm, 0, flag);
    gemm_kernel<<<dim3(16, 64), 256, 0, stream>>>(
        XN, 0, e_f1W, 1, (size_t)l * Dm * FF, e_f1b, (size_t)l * FF,
        nullptr, BIG, Bb * NLR, Dm, FF, 1, flag);
    gemm_kernel<<<dim3(4, 64), 256, 0, stream>>>(
        BIG, 0, e_f2W, 1, (size_t)l * FF * Dm, e_f2b, (size_t)l * Dm,
        H, H, Bb * NLR, FF, Dm, 0, flag);
  }

  // ---- encoder norm + upsampler ----
  ln_kernel<<<Bb * NLR, 256, 0, stream>>>(H, XN, encn_g, encn_b, 0, Dm, 0, flag);
  transpose_kernel<<<dim3(16, 8, Bb), 256, 0, stream>>>(XN, H, NLR, Dm);
  gemm_kernel<<<dim3(4, 128), 256, 0, stream>>>(
      H, 0, up1W, 1, 0, up1b, 0, nullptr, AO, Bb * Dm, NLR, NHR, 1, flag);
  gemm_kernel<<<dim3(4, 128), 256, 0, stream>>>(
      AO, 0, up2W, 1, 0, up2b, 0, nullptr, XN, Bb * Dm, NHR, NHR, 0, flag);
  transpose_kernel<<<dim3(16, 16, Bb), 256, 0, stream>>>(XN, H, Dm, NHR);

  // ---- refiner ----
  ln_kernel<<<Bb * NHR, 256, 0, stream>>>(H, XN, r_n1g, r_n1b, 0, Dm, 0, flag);
  gemm_kernel<<<dim3(12, 128), 256, 0, stream>>>(
      XN, 0, r_qkvW, 1, 0, r_qkvb, 0, nullptr, BIG, Bb * NHR, Dm, 3 * Dm, 0, flag);
  attn_kernel<<<Bb * NHh * (NHR / AROWS), 256, 0, stream>>>(
      BIG, AO, nullptr, nullptr, nullptr, 0, 0, Bb, NHR, NHh, HD, flag);
  gemm_kernel<<<dim3(4, 128), 256, 0, stream>>>(
      AO, 0, r_projW, 1, 0, r_projb, 0, H, H, Bb * NHR, Dm, Dm, 0, flag);
  ln_kernel<<<Bb * NHR, 256, 0, stream>>>(H, XN, r_n2g, r_n2b, 0, Dm, 0, flag);
  gemm_kernel<<<dim3(16, 128), 256, 0, stream>>>(
      XN, 0, r_f1W, 1, 0, r_f1b, 0, nullptr, BIG, Bb * NHR, Dm, FF, 1, flag);
  gemm_kernel<<<dim3(4, 128), 256, 0, stream>>>(
      BIG, 0, r_f2W, 1, 0, r_f2b, 0, H, H, Bb * NHR, FF, Dm, 0, flag);

  // ---- final norm + decoder ----
  ln_kernel<<<Bb * NHR, 256, 0, stream>>>(H, XN, hrn_g, hrn_b, 0, Dm, 0, flag);
  build_s_kernel<<<(512 * 512 + 255) / 256, 256, 0, stream>>>(dec_W, Ss, Dm, 4, flag);
  gemm_kernel<<<dim3(4, 128), 256, 0, stream>>>(
      XN, 0, Ss, 0, 0, nullptr, 0, nullptr, Tt, Bb * NHR, Dm, Dm, 0, flag);
  dec_out_kernel<<<dim3(36, Bb), 256, 0, stream>>>(
      Tt, XN, dec_b, (float*)d_out, NHR, Dm, flag);
}

// Round 4
// 2051.446 us; speedup vs baseline: 3.1314x; 3.1314x over previous
//
#include <hip/hip_runtime.h>
#include <hip/hip_bf16.h>
#include <math.h>

#define DEV __device__ __forceinline__

typedef __attribute__((ext_vector_type(8))) short bf16x8;
typedef __attribute__((ext_vector_type(4))) float f32x4;

DEV float gelu_f(float x) { return 0.5f * x * (1.0f + erff(x * 0.70710678118654752f)); }

DEV float block_reduce(float v, bool is_sum, float* red) {
#pragma unroll
  for (int off = 32; off > 0; off >>= 1) {
    float o = __shfl_down(v, off, 64);
    v = is_sum ? (v + o) : fmaxf(v, o);
  }
  __syncthreads();
  if ((threadIdx.x & 63) == 0) red[threadIdx.x >> 6] = v;
  __syncthreads();
  return is_sum ? (red[0] + red[1] + red[2] + red[3])
                : fmaxf(fmaxf(red[0], red[1]), fmaxf(red[2], red[3]));
}

DEV void ld8bf(const __hip_bfloat16* p, float* o) {
  uint4 u = *(const uint4*)p;
  o[0] = __uint_as_float(u.x << 16); o[1] = __uint_as_float(u.x & 0xffff0000u);
  o[2] = __uint_as_float(u.y << 16); o[3] = __uint_as_float(u.y & 0xffff0000u);
  o[4] = __uint_as_float(u.z << 16); o[5] = __uint_as_float(u.z & 0xffff0000u);
  o[6] = __uint_as_float(u.w << 16); o[7] = __uint_as_float(u.w & 0xffff0000u);
}

// ---------- conversion kernels (run each launch; ws is re-poisoned) ----------
__global__ __launch_bounds__(256) void conv_kernel(
    const float* __restrict__ X, __hip_bfloat16* __restrict__ Y, int n) {
  int i = blockIdx.x * 256 + threadIdx.x;
  if (i < n) Y[i] = __float2bfloat16(X[i]);
}

// fp32 R x C  ->  bf16 C x R (transpose+convert); grid (C/32, R/32, L)
__global__ __launch_bounds__(256) void tconv_kernel(
    const float* __restrict__ X, __hip_bfloat16* __restrict__ Y, int R, int C) {
  __shared__ float t[32][33];
  const float* xb = X + (size_t)blockIdx.z * R * C;
  __hip_bfloat16* yb = Y + (size_t)blockIdx.z * R * C;
  int c0 = blockIdx.x * 32, r0 = blockIdx.y * 32;
  int tx = threadIdx.x & 31, ty = threadIdx.x >> 5;
  for (int i = ty; i < 32; i += 8) t[i][tx] = xb[(size_t)(r0 + i) * C + c0 + tx];
  __syncthreads();
  for (int i = ty; i < 32; i += 8)
    yb[(size_t)(c0 + i) * R + r0 + tx] = __float2bfloat16(t[tx][i]);
}

__global__ __launch_bounds__(256) void build_s_kernel(
    const float* __restrict__ W, __hip_bfloat16* __restrict__ S, int D, int Kk) {
  int i = blockIdx.x * 256 + threadIdx.x;
  if (i >= D * D) return;
  int d = i / D, e = i % D;
  float s = 0.f;
  for (int k = 0; k < Kk; ++k) {
    s += W[(size_t)k * D * D + i];
    s += W[(size_t)k * D * D + (size_t)e * D + d];
  }
  S[i] = __float2bfloat16(s / (2.0f * Kk));
}

// ---------- MFMA GEMM: C = act(A @ Bt^T + bias) (+resid) ----------
// A: M x K bf16 row-major; Bt: N x K bf16 row-major. 128x128 tile, BK=64.
// 4 waves in 2x2; each wave 4x4 tiles of 16x16x32 MFMA.
__global__ __launch_bounds__(256) void mgemm_kernel(
    const __hip_bfloat16* __restrict__ A, const __hip_bfloat16* __restrict__ Bt,
    const float* __restrict__ bias, const float* __restrict__ resid,
    float* __restrict__ outf, __hip_bfloat16* __restrict__ outb,
    int M, int N, int K, int act) {
  __shared__ __align__(16) short As[128 * 64];
  __shared__ __align__(16) short Bs[128 * 64];
  const int tid = threadIdx.x;
  const int lane = tid & 63, wave = tid >> 6;
  const int mw = (wave >> 1) * 64, nw = (wave & 1) * 64;
  const int row0 = blockIdx.y * 128, col0 = blockIdx.x * 128;
  const short* Ag = (const short*)A;
  const short* Bg = (const short*)Bt;
  f32x4 acc[4][4] = {};

  for (int k0 = 0; k0 < K; k0 += 64) {
    __syncthreads();
#pragma unroll
    for (int c0i = 0; c0i < 4; ++c0i) {
      int c = c0i * 256 + tid;
      int r = c >> 3, kc = c & 7;
      *(uint4*)&As[c * 8] = *(const uint4*)&Ag[(size_t)(row0 + r) * K + k0 + kc * 8];
      *(uint4*)&Bs[c * 8] = *(const uint4*)&Bg[(size_t)(col0 + r) * K + k0 + kc * 8];
    }
    __syncthreads();
#pragma unroll
    for (int kh = 0; kh < 2; ++kh) {
      bf16x8 af[4], bq[4];
#pragma unroll
      for (int mi = 0; mi < 4; ++mi)
        af[mi] = *(const bf16x8*)&As[(mw + mi * 16 + (lane & 15)) * 64 + (lane >> 4) * 8 + kh * 32];
#pragma unroll
      for (int ni = 0; ni < 4; ++ni)
        bq[ni] = *(const bf16x8*)&Bs[(nw + ni * 16 + (lane & 15)) * 64 + (lane >> 4) * 8 + kh * 32];
#pragma unroll
      for (int mi = 0; mi < 4; ++mi)
#pragma unroll
        for (int ni = 0; ni < 4; ++ni)
          acc[mi][ni] = __builtin_amdgcn_mfma_f32_16x16x32_bf16(af[mi], bq[ni], acc[mi][ni], 0, 0, 0);
    }
  }

  const int ccol = lane & 15;
  const int crow = (lane >> 4) * 4;
#pragma unroll
  for (int mi = 0; mi < 4; ++mi) {
#pragma unroll
    for (int ni = 0; ni < 4; ++ni) {
      int cc = col0 + nw + ni * 16 + ccol;
      float bb = bias ? bias[cc] : 0.f;
#pragma unroll
      for (int r = 0; r < 4; ++r) {
        int rr = row0 + mw + mi * 16 + crow + r;
        size_t idx = (size_t)rr * N + cc;
        float v = acc[mi][ni][r] + bb;
        if (act) v = gelu_f(v);
        if (resid) v += resid[idx];
        if (outf) outf[idx] = v;
        if (outb) outb[idx] = __float2bfloat16(v);
      }
    }
  }
}

// ---------- decoder: G = T @ Hf^T (+db), softplus, packed triu ----------
__global__ __launch_bounds__(256) void dec_mfma_kernel(
    const __hip_bfloat16* __restrict__ Tb_, const __hip_bfloat16* __restrict__ Hb_,
    const float* __restrict__ dec_b, float* __restrict__ out) {
  const int Nn = 512, K = 512;
  __shared__ __align__(16) short As[128 * 64];
  __shared__ __align__(16) short Bs[128 * 64];
  int p = blockIdx.x;  // 0..9 upper-tri tile pair
  int bb = blockIdx.y;
  int it = 0, rem = p;
  while (rem >= 4 - it) { rem -= 4 - it; ++it; }
  int jt = it + rem;
  const int row0 = it * 128, col0 = jt * 128;
  const int tid = threadIdx.x;
  const int lane = tid & 63, wave = tid >> 6;
  const int mw = (wave >> 1) * 64, nw = (wave & 1) * 64;
  const short* Ag = (const short*)(Tb_ + (size_t)bb * Nn * K);
  const short* Bg = (const short*)(Hb_ + (size_t)bb * Nn * K);
  f32x4 acc[4][4] = {};

  for (int k0 = 0; k0 < K; k0 += 64) {
    __syncthreads();
#pragma unroll
    for (int c0i = 0; c0i < 4; ++c0i) {
      int c = c0i * 256 + tid;
      int r = c >> 3, kc = c & 7;
      *(uint4*)&As[c * 8] = *(const uint4*)&Ag[(size_t)(row0 + r) * K + k0 + kc * 8];
      *(uint4*)&Bs[c * 8] = *(const uint4*)&Bg[(size_t)(col0 + r) * K + k0 + kc * 8];
    }
    __syncthreads();
#pragma unroll
    for (int kh = 0; kh < 2; ++kh) {
      bf16x8 af[4], bq[4];
#pragma unroll
      for (int mi = 0; mi < 4; ++mi)
        af[mi] = *(const bf16x8*)&As[(mw + mi * 16 + (lane & 15)) * 64 + (lane >> 4) * 8 + kh * 32];
#pragma unroll
      for (int ni = 0; ni < 4; ++ni)
        bq[ni] = *(const bf16x8*)&Bs[(nw + ni * 16 + (lane & 15)) * 64 + (lane >> 4) * 8 + kh * 32];
#pragma unroll
      for (int mi = 0; mi < 4; ++mi)
#pragma unroll
        for (int ni = 0; ni < 4; ++ni)
          acc[mi][ni] = __builtin_amdgcn_mfma_f32_16x16x32_bf16(af[mi], bq[ni], acc[mi][ni], 0, 0, 0);
    }
  }

  float db = dec_b[0];
  size_t obase = (size_t)bb * ((size_t)Nn * (Nn - 1) / 2);
  const int ccol = lane & 15;
  const int crow = (lane >> 4) * 4;
#pragma unroll
  for (int mi = 0; mi < 4; ++mi) {
#pragma unroll
    for (int ni = 0; ni < 4; ++ni) {
      int j = col0 + nw + ni * 16 + ccol;
#pragma unroll
      for (int r = 0; r < 4; ++r) {
        int i = row0 + mw + mi * 16 + crow + r;
        if (j > i) {
          float x = acc[mi][ni][r] + db;
          float sp = (x > 30.f) ? x : log1pf(expf(x));
          out[obase + (size_t)i * (2 * Nn - i - 1) / 2 + (j - i - 1)] = sp;
        }
      }
    }
  }
}

// ---------- LayerNorm: fp32 in -> fp32 and/or bf16 out ----------
__global__ __launch_bounds__(256) void ln_kernel(
    const float* __restrict__ X, float* __restrict__ outf,
    __hip_bfloat16* __restrict__ outb, const float* __restrict__ g,
    const float* __restrict__ b, int D, int do_gelu) {
  __shared__ float red[4];
  int row = blockIdx.x;
  const float* x = X + (size_t)row * D;
  float s = 0.f, s2 = 0.f;
  for (int d = threadIdx.x; d < D; d += 256) {
    float v = x[d];
    s += v;
    s2 += v * v;
  }
  s = block_reduce(s, true, red);
  s2 = block_reduce(s2, true, red);
  float mean = s / D;
  float var = s2 / D - mean * mean;
  float inv = rsqrtf(var + 1e-5f);
  for (int d = threadIdx.x; d < D; d += 256) {
    float v = (x[d] - mean) * inv * g[d] + b[d];
    if (do_gelu) v = gelu_f(v);
    if (outf) outf[(size_t)row * D + d] = v;
    if (outb) outb[(size_t)row * D + d] = __float2bfloat16(v);
  }
}

// ---------- attention (bf16 QKV in, bf16 O out) ----------
#define AROWS 8
__global__ __launch_bounds__(256) void attn_kernel(
    const __hip_bfloat16* __restrict__ QKV, __hip_bfloat16* __restrict__ O,
    const float* __restrict__ Abias, const float* __restrict__ ebW,
    const float* __restrict__ ebs, int N, int NH_, int HD) {
  __shared__ __align__(16) float qs[AROWS][64];
  __shared__ float sc[AROWS][512];
  __shared__ float red[4];
  __shared__ float ored[4][AROWS][64];
  int tid = threadIdx.x;
  int ngrp = N / AROWS;
  int blk = blockIdx.x;
  int rg = blk % ngrp;
  int t2 = blk / ngrp;
  int h = t2 % NH_;
  int b = t2 / NH_;
  int n0 = rg * AROWS;
  int C3 = 3 * NH_ * HD;
  const __hip_bfloat16* base = QKV + (size_t)b * N * C3;
  float scale = rsqrtf((float)HD);
  bool hasb = (Abias != nullptr);
  float bscale = 0.f;
  if (hasb) bscale = ebs[0] * ebW[h];

  for (int i = tid; i < AROWS * HD; i += 256) {
    int r = i / HD, d = i % HD;
    qs[r][d] = __bfloat162float(base[(size_t)(n0 + r) * C3 + h * HD + d]);
  }
  __syncthreads();

  for (int m = tid; m < N; m += 256) {
    const __hip_bfloat16* krow = base + (size_t)m * C3 + NH_ * HD + h * HD;
    float acc[AROWS];
#pragma unroll
    for (int r = 0; r < AROWS; ++r) acc[r] = 0.f;
    for (int d = 0; d < HD; d += 8) {
      float kk[8];
      ld8bf(krow + d, kk);
#pragma unroll
      for (int r = 0; r < AROWS; ++r) {
        float4 q0 = *(const float4*)&qs[r][d];
        float4 q1 = *(const float4*)&qs[r][d + 4];
        acc[r] = fmaf(q0.x, kk[0], acc[r]);
        acc[r] = fmaf(q0.y, kk[1], acc[r]);
        acc[r] = fmaf(q0.z, kk[2], acc[r]);
        acc[r] = fmaf(q0.w, kk[3], acc[r]);
        acc[r] = fmaf(q1.x, kk[4], acc[r]);
        acc[r] = fmaf(q1.y, kk[5], acc[r]);
        acc[r] = fmaf(q1.z, kk[6], acc[r]);
        acc[r] = fmaf(q1.w, kk[7], acc[r]);
      }
    }
#pragma unroll
    for (int r = 0; r < AROWS; ++r) {
      float v = acc[r] * scale;
      if (hasb) v += bscale * Abias[((size_t)b * N + n0 + r) * N + m];
      sc[r][m] = v;
    }
  }
  __syncthreads();

  for (int r = 0; r < AROWS; ++r) {
    float lm = -1e30f;
    for (int m = tid; m < N; m += 256) lm = fmaxf(lm, sc[r][m]);
    float mx = block_reduce(lm, false, red);
    float ls = 0.f;
    for (int m = tid; m < N; m += 256) {
      float p = expf(sc[r][m] - mx);
      sc[r][m] = p;
      ls += p;
    }
    float ssum = block_reduce(ls, true, red);
    float invs = 1.f / ssum;
    for (int m = tid; m < N; m += 256) sc[r][m] *= invs;
  }
  __syncthreads();

  int d = tid & 63;
  int seg = tid >> 6;
  int mlo = seg * (N / 4), mhi = mlo + N / 4;
  float oacc[AROWS];
#pragma unroll
  for (int r = 0; r < AROWS; ++r) oacc[r] = 0.f;
  for (int m = mlo; m < mhi; ++m) {
    float vv = __bfloat162float(base[(size_t)m * C3 + 2 * NH_ * HD + h * HD + d]);
#pragma unroll
    for (int r = 0; r < AROWS; ++r) oacc[r] = fmaf(sc[r][m], vv, oacc[r]);
  }
#pragma unroll
  for (int r = 0; r < AROWS; ++r) ored[seg][r][d] = oacc[r];
  __syncthreads();
  for (int i = tid; i < AROWS * 64; i += 256) {
    int r = i / 64, dd = i % 64;
    float o = ored[0][r][dd] + ored[1][r][dd] + ored[2][r][dd] + ored[3][r][dd];
    O[((size_t)b * N + n0 + r) * (NH_ * HD) + h * HD + dd] = __float2bfloat16(o);
  }
}

// ---------- batched transpose (B,R,C)->(B,C,R), any 4/2-byte T ----------
template <typename T>
__global__ __launch_bounds__(256) void transpose_kernel(
    const T* __restrict__ X, T* __restrict__ Y, int R, int C) {
  __shared__ T t[32][33];
  const T* xb = X + (size_t)blockIdx.z * R * C;
  T* yb = Y + (size_t)blockIdx.z * R * C;
  int c0 = blockIdx.x * 32, r0 = blockIdx.y * 32;
  int tx = threadIdx.x & 31, ty = threadIdx.x >> 5;
  for (int i = ty; i < 32; i += 8) t[i][tx] = xb[(size_t)(r0 + i) * C + c0 + tx];
  __syncthreads();
  for (int i = ty; i < 32; i += 8) yb[(size_t)(c0 + i) * R + r0 + tx] = t[tx][i];
}

// ---------- host ----------
extern "C" void kernel_launch(void* const* d_in, const int* in_sizes, int n_in,
                              void* d_out, int out_size, void* d_ws, size_t ws_size,
                              hipStream_t stream) {
  const float *A_lr = (const float*)d_in[0], *X_lr = (const float*)d_in[1],
              *ip_W = (const float*)d_in[2], *ip_b = (const float*)d_in[3],
              *ip_g = (const float*)d_in[4], *ip_bt = (const float*)d_in[5],
              *e_n1g = (const float*)d_in[6], *e_n1b = (const float*)d_in[7],
              *e_qkvW = (const float*)d_in[8], *e_qkvb = (const float*)d_in[9],
              *e_projW = (const float*)d_in[10], *e_projb = (const float*)d_in[11],
              *e_ebW = (const float*)d_in[12], *e_ebs = (const float*)d_in[13],
              *e_n2g = (const float*)d_in[14], *e_n2b = (const float*)d_in[15],
              *e_f1W = (const float*)d_in[16], *e_f1b = (const float*)d_in[17],
              *e_f2W = (const float*)d_in[18], *e_f2b = (const float*)d_in[19],
              *encn_g = (const float*)d_in[20], *encn_b = (const float*)d_in[21],
              *up1W = (const float*)d_in[22], *up1b = (const float*)d_in[23],
              *up2W = (const float*)d_in[24], *up2b = (const float*)d_in[25],
              *r_n1g = (const float*)d_in[26], *r_n1b = (const float*)d_in[27],
              *r_qkvW = (const float*)d_in[28], *r_qkvb = (const float*)d_in[29],
              *r_projW = (const float*)d_in[30], *r_projb = (const float*)d_in[31],
              *r_n2g = (const float*)d_in[32], *r_n2b = (const float*)d_in[33],
              *r_f1W = (const float*)d_in[34], *r_f1b = (const float*)d_in[35],
              *r_f2W = (const float*)d_in[36], *r_f2b = (const float*)d_in[37],
              *hrn_g = (const float*)d_in[38], *hrn_b = (const float*)d_in[39],
              *dec_W = (const float*)d_in[40], *dec_b = (const float*)d_in[41];

  const int Bb = 16, NLR = 256, NHR = 512, Dm = 512, NHh = 8, HD = 64, FF = 2048, Ll = 4;
  typedef __hip_bfloat16 bf;

  float* ws = (float*)d_ws;
  float* H = ws;                                  // 4M fp32
  float* Hf = ws + 4194304;                       // 4M fp32 (ip out / XNf)
  bf* XNb = (bf*)(ws + 8388608);                  // 4M bf16
  bf* AOb = (bf*)(ws + 10485760);                 // 4M bf16 (also Htb / Ttb)
  bf* BIGb = (bf*)(ws + 12582912);                // 16.78M bf16 (QKV / FFN hidden)
  bf* WB = (bf*)(ws + 20971520);                  // 16.52M bf16 weights
  bf* Xlrb = (bf*)(ws + 29229056);                // 1.05M bf16

  // weight slab layout (bf16 elements, each W^T = N x K)
  size_t o = 0;
  bf* ipWt = WB + o;   o += (size_t)512 * 256;
  bf* eqkvT = WB + o;  o += (size_t)4 * 1536 * 512;
  bf* eprojT = WB + o; o += (size_t)4 * 512 * 512;
  bf* ef1T = WB + o;   o += (size_t)4 * 2048 * 512;
  bf* ef2T = WB + o;   o += (size_t)4 * 512 * 2048;
  bf* up1T = WB + o;   o += (size_t)512 * 256;
  bf* up2T = WB + o;   o += (size_t)512 * 512;
  bf* rqkvT = WB + o;  o += (size_t)1536 * 512;
  bf* rprojT = WB + o; o += (size_t)512 * 512;
  bf* rf1T = WB + o;   o += (size_t)2048 * 512;
  bf* rf2T = WB + o;   o += (size_t)512 * 2048;
  bf* Sb = WB + o;     o += (size_t)512 * 512;

  // ---- conversions ----
  tconv_kernel<<<dim3(16, 8, 1), 256, 0, stream>>>(ip_W, ipWt, 256, 512);
  tconv_kernel<<<dim3(48, 16, 4), 256, 0, stream>>>(e_qkvW, eqkvT, 512, 1536);
  tconv_kernel<<<dim3(16, 16, 4), 256, 0, stream>>>(e_projW, eprojT, 512, 512);
  tconv_kernel<<<dim3(64, 16, 4), 256, 0, stream>>>(e_f1W, ef1T, 512, 2048);
  tconv_kernel<<<dim3(16, 64, 4), 256, 0, stream>>>(e_f2W, ef2T, 2048, 512);
  tconv_kernel<<<dim3(16, 8, 1), 256, 0, stream>>>(up1W, up1T, 256, 512);
  tconv_kernel<<<dim3(16, 16, 1), 256, 0, stream>>>(up2W, up2T, 512, 512);
  tconv_kernel<<<dim3(48, 16, 1), 256, 0, stream>>>(r_qkvW, rqkvT, 512, 1536);
  tconv_kernel<<<dim3(16, 16, 1), 256, 0, stream>>>(r_projW, rprojT, 512, 512);
  tconv_kernel<<<dim3(64, 16, 1), 256, 0, stream>>>(r_f1W, rf1T, 512, 2048);
  tconv_kernel<<<dim3(16, 64, 1), 256, 0, stream>>>(r_f2W, rf2T, 2048, 512);
  conv_kernel<<<(1048576 + 255) / 256, 256, 0, stream>>>(X_lr, Xlrb, 1048576);
  build_s_kernel<<<(512 * 512 + 255) / 256, 256, 0, stream>>>(dec_W, Sb, Dm, 4);

  // ---- input projection ----
  mgemm_kernel<<<dim3(4, 32), 256, 0, stream>>>(
      Xlrb, ipWt, ip_b, nullptr, Hf, nullptr, Bb * NLR, Dm, NLR, 0);
  ln_kernel<<<Bb * NLR, 256, 0, stream>>>(Hf, H, nullptr, ip_g, ip_bt, Dm, 1);

  // ---- encoder ----
  for (int l = 0; l < Ll; ++l) {
    ln_kernel<<<Bb * NLR, 256, 0, stream>>>(H, nullptr, XNb, e_n1g + l * Dm, e_n1b + l * Dm, Dm, 0);
    mgemm_kernel<<<dim3(12, 32), 256, 0, stream>>>(
        XNb, eqkvT + (size_t)l * 1536 * 512, e_qkvb + l * 1536, nullptr,
        nullptr, BIGb, Bb * NLR, 3 * Dm, Dm, 0);
    attn_kernel<<<Bb * NHh * (NLR / AROWS), 256, 0, stream>>>(
        BIGb, AOb, A_lr, e_ebW + l * NHh, e_ebs + l, NLR, NHh, HD);
    mgemm_kernel<<<dim3(4, 32), 256, 0, stream>>>(
        AOb, eprojT + (size_t)l * 512 * 512, e_projb + l * Dm, H,
        H, nullptr, Bb * NLR, Dm, Dm, 0);
    ln_kernel<<<Bb * NLR, 256, 0, stream>>>(H, nullptr, XNb, e_n2g + l * Dm, e_n2b + l * Dm, Dm, 0);
    mgemm_kernel<<<dim3(16, 32), 256, 0, stream>>>(
        XNb, ef1T + (size_t)l * 2048 * 512, e_f1b + l * FF, nullptr,
        nullptr, BIGb, Bb * NLR, FF, Dm, 1);
    mgemm_kernel<<<dim3(4, 32), 256, 0, stream>>>(
        BIGb, ef2T + (size_t)l * 512 * 2048, e_f2b + l * Dm, H,
        H, nullptr, Bb * NLR, Dm, FF, 0);
  }

  // ---- upsampler ----
  ln_kernel<<<Bb * NLR, 256, 0, stream>>>(H, nullptr, XNb, encn_g, encn_b, Dm, 0);
  transpose_kernel<bf><<<dim3(16, 8, Bb), 256, 0, stream>>>(XNb, AOb, NLR, Dm);  // Htb in AOb
  mgemm_kernel<<<dim3(4, 64), 256, 0, stream>>>(
      AOb, up1T, up1b, nullptr, nullptr, BIGb, Bb * Dm, NHR, NLR, 1);
  mgemm_kernel<<<dim3(4, 64), 256, 0, stream>>>(
      BIGb, up2T, up2b, nullptr, Hf, nullptr, Bb * Dm, NHR, NHR, 0);
  transpose_kernel<float><<<dim3(16, 16, Bb), 256, 0, stream>>>(Hf, H, Dm, NHR);

  // ---- refiner ----
  ln_kernel<<<Bb * NHR, 256, 0, stream>>>(H, nullptr, XNb, r_n1g, r_n1b, Dm, 0);
  mgemm_kernel<<<dim3(12, 64), 256, 0, stream>>>(
      XNb, rqkvT, r_qkvb, nullptr, nullptr, BIGb, Bb * NHR, 3 * Dm, Dm, 0);
  attn_kernel<<<Bb * NHh * (NHR / AROWS), 256, 0, stream>>>(
      BIGb, AOb, nullptr, nullptr, nullptr, NHR, NHh, HD);
  mgemm_kernel<<<dim3(4, 64), 256, 0, stream>>>(
      AOb, rprojT, r_projb, H, H, nullptr, Bb * NHR, Dm, Dm, 0);
  ln_kernel<<<Bb * NHR, 256, 0, stream>>>(H, nullptr, XNb, r_n2g, r_n2b, Dm, 0);
  mgemm_kernel<<<dim3(16, 64), 256, 0, stream>>>(
      XNb, rf1T, r_f1b, nullptr, nullptr, BIGb, Bb * NHR, FF, Dm, 1);
  mgemm_kernel<<<dim3(4, 64), 256, 0, stream>>>(
      BIGb, rf2T, r_f2b, H, H, nullptr, Bb * NHR, Dm, FF, 0);

  // ---- decoder ----
  ln_kernel<<<Bb * NHR, 256, 0, stream>>>(H, nullptr, XNb, hrn_g, hrn_b, Dm, 0);
  mgemm_kernel<<<dim3(4, 64), 256, 0, stream>>>(
      XNb, Sb, nullptr, nullptr, nullptr, AOb, Bb * NHR, Dm, Dm, 0);  // Ttb in AOb
  dec_mfma_kernel<<<dim3(10, Bb), 256, 0, stream>>>(
      AOb, XNb, dec_b, (float*)d_out);
}

// Round 5
// 1485.757 us; speedup vs baseline: 4.3237x; 1.3807x over previous
//
#include <hip/hip_runtime.h>
#include <hip/hip_bf16.h>
#include <math.h>

#define DEV __device__ __forceinline__

typedef __attribute__((ext_vector_type(8))) short bf16x8;
typedef __attribute__((ext_vector_type(4))) float f32x4;

DEV float gelu_f(float x) { return 0.5f * x * (1.0f + erff(x * 0.70710678118654752f)); }

DEV float block_reduce(float v, bool is_sum, float* red) {
#pragma unroll
  for (int off = 32; off > 0; off >>= 1) {
    float o = __shfl_down(v, off, 64);
    v = is_sum ? (v + o) : fmaxf(v, o);
  }
  __syncthreads();
  if ((threadIdx.x & 63) == 0) red[threadIdx.x >> 6] = v;
  __syncthreads();
  return is_sum ? (red[0] + red[1] + red[2] + red[3])
                : fmaxf(fmaxf(red[0], red[1]), fmaxf(red[2], red[3]));
}

DEV short bf16s(float x) {
  __hip_bfloat16 v = __float2bfloat16(x);
  return *reinterpret_cast<short*>(&v);
}

// ---------- conversion kernels ----------
__global__ __launch_bounds__(256) void conv_kernel(
    const float* __restrict__ X, __hip_bfloat16* __restrict__ Y, int n) {
  int i = blockIdx.x * 256 + threadIdx.x;
  if (i < n) Y[i] = __float2bfloat16(X[i]);
}

// fp32 R x C -> bf16 C x R
__global__ __launch_bounds__(256) void tconv_kernel(
    const float* __restrict__ X, __hip_bfloat16* __restrict__ Y, int R, int C) {
  __shared__ float t[32][33];
  const float* xb = X + (size_t)blockIdx.z * R * C;
  __hip_bfloat16* yb = Y + (size_t)blockIdx.z * R * C;
  int c0 = blockIdx.x * 32, r0 = blockIdx.y * 32;
  int tx = threadIdx.x & 31, ty = threadIdx.x >> 5;
  for (int i = ty; i < 32; i += 8) t[i][tx] = xb[(size_t)(r0 + i) * C + c0 + tx];
  __syncthreads();
  for (int i = ty; i < 32; i += 8)
    yb[(size_t)(c0 + i) * R + r0 + tx] = __float2bfloat16(t[tx][i]);
}

__global__ __launch_bounds__(256) void build_s_kernel(
    const float* __restrict__ W, __hip_bfloat16* __restrict__ S, int D, int Kk) {
  int i = blockIdx.x * 256 + threadIdx.x;
  if (i >= D * D) return;
  int d = i / D, e = i % D;
  float s = 0.f;
  for (int k = 0; k < Kk; ++k) {
    s += W[(size_t)k * D * D + i];
    s += W[(size_t)k * D * D + (size_t)e * D + d];
  }
  S[i] = __float2bfloat16(s / (2.0f * Kk));
}

// ---------- MFMA GEMM: C = act(A @ Bt^T + bias) (+resid) ----------
__global__ __launch_bounds__(256) void mgemm_kernel(
    const __hip_bfloat16* __restrict__ A, const __hip_bfloat16* __restrict__ Bt,
    const float* __restrict__ bias, const float* __restrict__ resid,
    float* __restrict__ outf, __hip_bfloat16* __restrict__ outb,
    int M, int N, int K, int act) {
  __shared__ __align__(16) short As[128 * 64];
  __shared__ __align__(16) short Bs[128 * 64];
  const int tid = threadIdx.x;
  const int lane = tid & 63, wave = tid >> 6;
  const int mw = (wave >> 1) * 64, nw = (wave & 1) * 64;
  const int row0 = blockIdx.y * 128, col0 = blockIdx.x * 128;
  const short* Ag = (const short*)A;
  const short* Bg = (const short*)Bt;
  f32x4 acc[4][4] = {};

  for (int k0 = 0; k0 < K; k0 += 64) {
    __syncthreads();
#pragma unroll
    for (int c0i = 0; c0i < 4; ++c0i) {
      int c = c0i * 256 + tid;
      int r = c >> 3, kc = c & 7;
      *(uint4*)&As[c * 8] = *(const uint4*)&Ag[(size_t)(row0 + r) * K + k0 + kc * 8];
      *(uint4*)&Bs[c * 8] = *(const uint4*)&Bg[(size_t)(col0 + r) * K + k0 + kc * 8];
    }
    __syncthreads();
#pragma unroll
    for (int kh = 0; kh < 2; ++kh) {
      bf16x8 af[4], bq[4];
#pragma unroll
      for (int mi = 0; mi < 4; ++mi)
        af[mi] = *(const bf16x8*)&As[(mw + mi * 16 + (lane & 15)) * 64 + (lane >> 4) * 8 + kh * 32];
#pragma unroll
      for (int ni = 0; ni < 4; ++ni)
        bq[ni] = *(const bf16x8*)&Bs[(nw + ni * 16 + (lane & 15)) * 64 + (lane >> 4) * 8 + kh * 32];
#pragma unroll
      for (int mi = 0; mi < 4; ++mi)
#pragma unroll
        for (int ni = 0; ni < 4; ++ni)
          acc[mi][ni] = __builtin_amdgcn_mfma_f32_16x16x32_bf16(af[mi], bq[ni], acc[mi][ni], 0, 0, 0);
    }
  }

  const int ccol = lane & 15;
  const int crow = (lane >> 4) * 4;
#pragma unroll
  for (int mi = 0; mi < 4; ++mi) {
#pragma unroll
    for (int ni = 0; ni < 4; ++ni) {
      int cc = col0 + nw + ni * 16 + ccol;
      float bb = bias ? bias[cc] : 0.f;
#pragma unroll
      for (int r = 0; r < 4; ++r) {
        int rr = row0 + mw + mi * 16 + crow + r;
        size_t idx = (size_t)rr * N + cc;
        float v = acc[mi][ni][r] + bb;
        if (act) v = gelu_f(v);
        if (resid) v += resid[idx];
        if (outf) outf[idx] = v;
        if (outb) outb[idx] = __float2bfloat16(v);
      }
    }
  }
}

// ---------- QKV GEMM with head-layout scatter epilogue ----------
// A: (B*nseq) x 512 bf16; Bt: 1536 x 512 bf16. Writes:
//   Q[b][h][n][64] at qkv, K at qkv+S, Vt[b][h][64][n] at qkv+2S, S=B*8*nseq*64
__global__ __launch_bounds__(256) void qkv_gemm_kernel(
    const __hip_bfloat16* __restrict__ A, const __hip_bfloat16* __restrict__ Bt,
    const float* __restrict__ bias, __hip_bfloat16* __restrict__ qkv,
    int M, int K, int nseq, int lgn) {
  const int N = 1536;
  __shared__ __align__(16) short As[128 * 64];
  __shared__ __align__(16) short Bs[128 * 64];
  const int tid = threadIdx.x;
  const int lane = tid & 63, wave = tid >> 6;
  const int mw = (wave >> 1) * 64, nw = (wave & 1) * 64;
  const int row0 = blockIdx.y * 128, col0 = blockIdx.x * 128;
  const short* Ag = (const short*)A;
  const short* Bg = (const short*)Bt;
  f32x4 acc[4][4] = {};

  for (int k0 = 0; k0 < K; k0 += 64) {
    __syncthreads();
#pragma unroll
    for (int c0i = 0; c0i < 4; ++c0i) {
      int c = c0i * 256 + tid;
      int r = c >> 3, kc = c & 7;
      *(uint4*)&As[c * 8] = *(const uint4*)&Ag[(size_t)(row0 + r) * K + k0 + kc * 8];
      *(uint4*)&Bs[c * 8] = *(const uint4*)&Bg[(size_t)(col0 + r) * K + k0 + kc * 8];
    }
    __syncthreads();
#pragma unroll
    for (int kh = 0; kh < 2; ++kh) {
      bf16x8 af[4], bq[4];
#pragma unroll
      for (int mi = 0; mi < 4; ++mi)
        af[mi] = *(const bf16x8*)&As[(mw + mi * 16 + (lane & 15)) * 64 + (lane >> 4) * 8 + kh * 32];
#pragma unroll
      for (int ni = 0; ni < 4; ++ni)
        bq[ni] = *(const bf16x8*)&Bs[(nw + ni * 16 + (lane & 15)) * 64 + (lane >> 4) * 8 + kh * 32];
#pragma unroll
      for (int mi = 0; mi < 4; ++mi)
#pragma unroll
        for (int ni = 0; ni < 4; ++ni)
          acc[mi][ni] = __builtin_amdgcn_mfma_f32_16x16x32_bf16(af[mi], bq[ni], acc[mi][ni], 0, 0, 0);
    }
  }

  const size_t S = (size_t)(M) * 64 * 8 / 1;  // B*nseq*512 = M*512; per-part = M*512/... 
  // per-part size = B * 8 * nseq * 64 = M * 512
  const size_t PART = (size_t)M * 512;
  const int ccol = lane & 15;
  const int crow = (lane >> 4) * 4;
#pragma unroll
  for (int mi = 0; mi < 4; ++mi) {
#pragma unroll
    for (int ni = 0; ni < 4; ++ni) {
      int cc = col0 + nw + ni * 16 + ccol;  // 0..1535
      float bb = bias ? bias[cc] : 0.f;
      int which = cc >> 9;
      int h = (cc >> 6) & 7;
      int d = cc & 63;
#pragma unroll
      for (int r = 0; r < 4; ++r) {
        int rr = row0 + mw + mi * 16 + crow + r;
        int b = rr >> lgn;
        int nn = rr & (nseq - 1);
        float v = acc[mi][ni][r] + bb;
        size_t dst;
        if (which == 2) {
          dst = 2 * PART + (((size_t)b * 8 + h) * 64 + d) * nseq + nn;
        } else {
          dst = (size_t)which * PART + (((size_t)b * 8 + h) * nseq + nn) * 64 + d;
        }
        qkv[dst] = __float2bfloat16(v);
      }
    }
  }
}

// ---------- fused flash attention (MFMA) ----------
// grid: (N/64, NH, B); block 256 = 4 waves, wave w owns Q-rows [64*qt + 16w, +16)
__global__ __launch_bounds__(256) void fattn_kernel(
    const __hip_bfloat16* __restrict__ Qh, const __hip_bfloat16* __restrict__ Kh,
    const __hip_bfloat16* __restrict__ Vt, __hip_bfloat16* __restrict__ O,
    const float* __restrict__ Abias, const float* __restrict__ ebW,
    const float* __restrict__ ebs, int N) {
  __shared__ __align__(16) short Ks[64][72];
  __shared__ __align__(16) short Vs[64][72];
  __shared__ __align__(16) short Ps[4][16][72];
  const int qt = blockIdx.x, h = blockIdx.y, b = blockIdx.z;
  const int tid = threadIdx.x, lane = tid & 63, wave = tid >> 6;
  const int quad = lane >> 4, l15 = lane & 15;
  const size_t hb = (size_t)b * 8 + h;
  const short* Qg = (const short*)Qh + hb * N * 64;
  const short* Kg = (const short*)Kh + hb * N * 64;
  const short* Vg = (const short*)Vt + hb * 64 * N;
  const float scale = 0.125f;  // 1/sqrt(64)
  const bool hasb = (Abias != nullptr);
  const float bscale = hasb ? ebs[0] * ebW[h] : 0.f;
  const int qrow_w = qt * 64 + wave * 16;

  // Q A-frags in registers for the whole block lifetime
  bf16x8 qf0 = *(const bf16x8*)&Qg[(size_t)(qrow_w + l15) * 64 + quad * 8];
  bf16x8 qf1 = *(const bf16x8*)&Qg[(size_t)(qrow_w + l15) * 64 + quad * 8 + 32];

  float m_i[4], l_i[4];
  f32x4 oacc[4] = {};
#pragma unroll
  for (int r = 0; r < 4; ++r) { m_i[r] = -1e30f; l_i[r] = 0.f; }

  for (int k0 = 0; k0 < N; k0 += 64) {
    __syncthreads();
#pragma unroll
    for (int i = 0; i < 2; ++i) {
      int idx = i * 256 + tid;       // 0..511
      int r = idx >> 3, ch = idx & 7;
      *(uint4*)&Ks[r][ch * 8] = *(const uint4*)&Kg[(size_t)(k0 + r) * 64 + ch * 8];
      *(uint4*)&Vs[r][ch * 8] = *(const uint4*)&Vg[(size_t)r * N + k0 + ch * 8];
    }
    __syncthreads();

    // S-tile: 16 (q rows) x 64 (keys) per wave
    f32x4 s[4] = {};
#pragma unroll
    for (int ni = 0; ni < 4; ++ni) {
      bf16x8 kf0 = *(const bf16x8*)&Ks[ni * 16 + l15][quad * 8];
      bf16x8 kf1 = *(const bf16x8*)&Ks[ni * 16 + l15][quad * 8 + 32];
      s[ni] = __builtin_amdgcn_mfma_f32_16x16x32_bf16(qf0, kf0, s[ni], 0, 0, 0);
      s[ni] = __builtin_amdgcn_mfma_f32_16x16x32_bf16(qf1, kf1, s[ni], 0, 0, 0);
    }
    if (hasb) {
#pragma unroll
      for (int ni = 0; ni < 4; ++ni)
#pragma unroll
        for (int r = 0; r < 4; ++r) {
          int qq = qrow_w + quad * 4 + r;
          int kk = k0 + ni * 16 + l15;
          s[ni][r] = s[ni][r] * scale + bscale * Abias[((size_t)b * N + qq) * N + kk];
        }
    } else {
#pragma unroll
      for (int ni = 0; ni < 4; ++ni)
#pragma unroll
        for (int r = 0; r < 4; ++r) s[ni][r] *= scale;
    }

    // row max over 64 keys: 4 accs + shfl_xor within 16-lane groups
    float mt[4];
#pragma unroll
    for (int r = 0; r < 4; ++r)
      mt[r] = fmaxf(fmaxf(s[0][r], s[1][r]), fmaxf(s[2][r], s[3][r]));
#pragma unroll
    for (int off = 1; off < 16; off <<= 1)
#pragma unroll
      for (int r = 0; r < 4; ++r) mt[r] = fmaxf(mt[r], __shfl_xor(mt[r], off, 64));

    float alpha[4];
#pragma unroll
    for (int r = 0; r < 4; ++r) {
      float mn = fmaxf(m_i[r], mt[r]);
      alpha[r] = __expf(m_i[r] - mn);
      m_i[r] = mn;
    }
    float ls[4] = {0.f, 0.f, 0.f, 0.f};
#pragma unroll
    for (int ni = 0; ni < 4; ++ni)
#pragma unroll
      for (int r = 0; r < 4; ++r) {
        float p = __expf(s[ni][r] - m_i[r]);
        s[ni][r] = p;
        ls[r] += p;
      }
#pragma unroll
    for (int off = 1; off < 16; off <<= 1)
#pragma unroll
      for (int r = 0; r < 4; ++r) ls[r] += __shfl_xor(ls[r], off, 64);
#pragma unroll
    for (int r = 0; r < 4; ++r) l_i[r] = l_i[r] * alpha[r] + ls[r];
#pragma unroll
    for (int ni = 0; ni < 4; ++ni)
#pragma unroll
      for (int r = 0; r < 4; ++r) oacc[ni][r] *= alpha[r];

    // P: C-layout -> LDS row-major (wave-private slab; no barrier needed)
#pragma unroll
    for (int ni = 0; ni < 4; ++ni)
#pragma unroll
      for (int r = 0; r < 4; ++r)
        Ps[wave][quad * 4 + r][ni * 16 + l15] = bf16s(s[ni][r]);

    bf16x8 pf0 = *(const bf16x8*)&Ps[wave][l15][quad * 8];
    bf16x8 pf1 = *(const bf16x8*)&Ps[wave][l15][quad * 8 + 32];
#pragma unroll
    for (int ni = 0; ni < 4; ++ni) {
      bf16x8 vf0 = *(const bf16x8*)&Vs[ni * 16 + l15][quad * 8];
      bf16x8 vf1 = *(const bf16x8*)&Vs[ni * 16 + l15][quad * 8 + 32];
      oacc[ni] = __builtin_amdgcn_mfma_f32_16x16x32_bf16(pf0, vf0, oacc[ni], 0, 0, 0);
      oacc[ni] = __builtin_amdgcn_mfma_f32_16x16x32_bf16(pf1, vf1, oacc[ni], 0, 0, 0);
    }
  }

  float inv[4];
#pragma unroll
  for (int r = 0; r < 4; ++r) inv[r] = 1.f / l_i[r];
#pragma unroll
  for (int ni = 0; ni < 4; ++ni)
#pragma unroll
    for (int r = 0; r < 4; ++r) {
      int nn = qrow_w + quad * 4 + r;
      int col = h * 64 + ni * 16 + l15;
      O[((size_t)b * N + nn) * 512 + col] = __float2bfloat16(oacc[ni][r] * inv[r]);
    }
}

// ---------- decoder: G = T @ Hf^T (+db), softplus, packed triu ----------
__global__ __launch_bounds__(256) void dec_mfma_kernel(
    const __hip_bfloat16* __restrict__ Tb_, const __hip_bfloat16* __restrict__ Hb_,
    const float* __restrict__ dec_b, float* __restrict__ out) {
  const int Nn = 512, K = 512;
  __shared__ __align__(16) short As[128 * 64];
  __shared__ __align__(16) short Bs[128 * 64];
  int p = blockIdx.x;
  int bb = blockIdx.y;
  int it = 0, rem = p;
  while (rem >= 4 - it) { rem -= 4 - it; ++it; }
  int jt = it + rem;
  const int row0 = it * 128, col0 = jt * 128;
  const int tid = threadIdx.x;
  const int lane = tid & 63, wave = tid >> 6;
  const int mw = (wave >> 1) * 64, nw = (wave & 1) * 64;
  const short* Ag = (const short*)(Tb_ + (size_t)bb * Nn * K);
  const short* Bg = (const short*)(Hb_ + (size_t)bb * Nn * K);
  f32x4 acc[4][4] = {};

  for (int k0 = 0; k0 < K; k0 += 64) {
    __syncthreads();
#pragma unroll
    for (int c0i = 0; c0i < 4; ++c0i) {
      int c = c0i * 256 + tid;
      int r = c >> 3, kc = c & 7;
      *(uint4*)&As[c * 8] = *(const uint4*)&Ag[(size_t)(row0 + r) * K + k0 + kc * 8];
      *(uint4*)&Bs[c * 8] = *(const uint4*)&Bg[(size_t)(col0 + r) * K + k0 + kc * 8];
    }
    __syncthreads();
#pragma unroll
    for (int kh = 0; kh < 2; ++kh) {
      bf16x8 af[4], bq[4];
#pragma unroll
      for (int mi = 0; mi < 4; ++mi)
        af[mi] = *(const bf16x8*)&As[(mw + mi * 16 + (lane & 15)) * 64 + (lane >> 4) * 8 + kh * 32];
#pragma unroll
      for (int ni = 0; ni < 4; ++ni)
        bq[ni] = *(const bf16x8*)&Bs[(nw + ni * 16 + (lane & 15)) * 64 + (lane >> 4) * 8 + kh * 32];
#pragma unroll
      for (int mi = 0; mi < 4; ++mi)
#pragma unroll
        for (int ni = 0; ni < 4; ++ni)
          acc[mi][ni] = __builtin_amdgcn_mfma_f32_16x16x32_bf16(af[mi], bq[ni], acc[mi][ni], 0, 0, 0);
    }
  }

  float db = dec_b[0];
  size_t obase = (size_t)bb * ((size_t)Nn * (Nn - 1) / 2);
  const int ccol = lane & 15;
  const int crow = (lane >> 4) * 4;
#pragma unroll
  for (int mi = 0; mi < 4; ++mi) {
#pragma unroll
    for (int ni = 0; ni < 4; ++ni) {
      int j = col0 + nw + ni * 16 + ccol;
#pragma unroll
      for (int r = 0; r < 4; ++r) {
        int i = row0 + mw + mi * 16 + crow + r;
        if (j > i) {
          float x = acc[mi][ni][r] + db;
          float sp = (x > 30.f) ? x : log1pf(expf(x));
          out[obase + (size_t)i * (2 * Nn - i - 1) / 2 + (j - i - 1)] = sp;
        }
      }
    }
  }
}

// ---------- LayerNorm ----------
__global__ __launch_bounds__(256) void ln_kernel(
    const float* __restrict__ X, float* __restrict__ outf,
    __hip_bfloat16* __restrict__ outb, const float* __restrict__ g,
    const float* __restrict__ b, int D, int do_gelu) {
  __shared__ float red[4];
  int row = blockIdx.x;
  const float* x = X + (size_t)row * D;
  float s = 0.f, s2 = 0.f;
  for (int d = threadIdx.x; d < D; d += 256) {
    float v = x[d];
    s += v;
    s2 += v * v;
  }
  s = block_reduce(s, true, red);
  s2 = block_reduce(s2, true, red);
  float mean = s / D;
  float var = s2 / D - mean * mean;
  float inv = rsqrtf(var + 1e-5f);
  for (int d = threadIdx.x; d < D; d += 256) {
    float v = (x[d] - mean) * inv * g[d] + b[d];
    if (do_gelu) v = gelu_f(v);
    if (outf) outf[(size_t)row * D + d] = v;
    if (outb) outb[(size_t)row * D + d] = __float2bfloat16(v);
  }
}

// ---------- batched transpose ----------
template <typename T>
__global__ __launch_bounds__(256) void transpose_kernel(
    const T* __restrict__ X, T* __restrict__ Y, int R, int C) {
  __shared__ T t[32][33];
  const T* xb = X + (size_t)blockIdx.z * R * C;
  T* yb = Y + (size_t)blockIdx.z * R * C;
  int c0 = blockIdx.x * 32, r0 = blockIdx.y * 32;
  int tx = threadIdx.x & 31, ty = threadIdx.x >> 5;
  for (int i = ty; i < 32; i += 8) t[i][tx] = xb[(size_t)(r0 + i) * C + c0 + tx];
  __syncthreads();
  for (int i = ty; i < 32; i += 8) yb[(size_t)(c0 + i) * R + r0 + tx] = t[tx][i];
}

// ---------- host ----------
extern "C" void kernel_launch(void* const* d_in, const int* in_sizes, int n_in,
                              void* d_out, int out_size, void* d_ws, size_t ws_size,
                              hipStream_t stream) {
  const float *A_lr = (const float*)d_in[0], *X_lr = (const float*)d_in[1],
              *ip_W = (const float*)d_in[2], *ip_b = (const float*)d_in[3],
              *ip_g = (const float*)d_in[4], *ip_bt = (const float*)d_in[5],
              *e_n1g = (const float*)d_in[6], *e_n1b = (const float*)d_in[7],
              *e_qkvW = (const float*)d_in[8], *e_qkvb = (const float*)d_in[9],
              *e_projW = (const float*)d_in[10], *e_projb = (const float*)d_in[11],
              *e_ebW = (const float*)d_in[12], *e_ebs = (const float*)d_in[13],
              *e_n2g = (const float*)d_in[14], *e_n2b = (const float*)d_in[15],
              *e_f1W = (const float*)d_in[16], *e_f1b = (const float*)d_in[17],
              *e_f2W = (const float*)d_in[18], *e_f2b = (const float*)d_in[19],
              *encn_g = (const float*)d_in[20], *encn_b = (const float*)d_in[21],
              *up1W = (const float*)d_in[22], *up1b = (const float*)d_in[23],
              *up2W = (const float*)d_in[24], *up2b = (const float*)d_in[25],
              *r_n1g = (const float*)d_in[26], *r_n1b = (const float*)d_in[27],
              *r_qkvW = (const float*)d_in[28], *r_qkvb = (const float*)d_in[29],
              *r_projW = (const float*)d_in[30], *r_projb = (const float*)d_in[31],
              *r_n2g = (const float*)d_in[32], *r_n2b = (const float*)d_in[33],
              *r_f1W = (const float*)d_in[34], *r_f1b = (const float*)d_in[35],
              *r_f2W = (const float*)d_in[36], *r_f2b = (const float*)d_in[37],
              *hrn_g = (const float*)d_in[38], *hrn_b = (const float*)d_in[39],
              *dec_W = (const float*)d_in[40], *dec_b = (const float*)d_in[41];

  const int Bb = 16, NLR = 256, NHR = 512, Dm = 512, NHh = 8, FF = 2048, Ll = 4;
  typedef __hip_bfloat16 bf;

  float* ws = (float*)d_ws;
  float* H = ws;                                  // 4M fp32
  float* Hf = ws + 4194304;                       // 4M fp32
  bf* XNb = (bf*)(ws + 8388608);                  // 4M bf16
  bf* AOb = (bf*)(ws + 10485760);                 // 4M bf16 (Htb / Ttb / attn out)
  bf* BIGb = (bf*)(ws + 12582912);                // 16.78M bf16 (QKV slab / FFN hidden)
  bf* WB = (bf*)(ws + 20971520);                  // bf16 weights
  bf* Xlrb = (bf*)(ws + 29229056);                // 1.05M bf16

  size_t o = 0;
  bf* ipWt = WB + o;   o += (size_t)512 * 256;
  bf* eqkvT = WB + o;  o += (size_t)4 * 1536 * 512;
  bf* eprojT = WB + o; o += (size_t)4 * 512 * 512;
  bf* ef1T = WB + o;   o += (size_t)4 * 2048 * 512;
  bf* ef2T = WB + o;   o += (size_t)4 * 512 * 2048;
  bf* up1T = WB + o;   o += (size_t)512 * 256;
  bf* up2T = WB + o;   o += (size_t)512 * 512;
  bf* rqkvT = WB + o;  o += (size_t)1536 * 512;
  bf* rprojT = WB + o; o += (size_t)512 * 512;
  bf* rf1T = WB + o;   o += (size_t)2048 * 512;
  bf* rf2T = WB + o;   o += (size_t)512 * 2048;
  bf* Sb = WB + o;     o += (size_t)512 * 512;

  // QKV slab views (inside BIGb): per-part = B*8*nseq*64 = M*512
  bf* Q_e = BIGb;                     // encoder: M=4096 -> part 2097152
  bf* K_e = BIGb + 2097152;
  bf* V_e = BIGb + 4194304;
  bf* Q_r = BIGb;                     // refiner: M=8192 -> part 4194304
  bf* K_r = BIGb + 4194304;
  bf* V_r = BIGb + 8388608;

  // ---- conversions ----
  tconv_kernel<<<dim3(16, 8, 1), 256, 0, stream>>>(ip_W, ipWt, 256, 512);
  tconv_kernel<<<dim3(48, 16, 4), 256, 0, stream>>>(e_qkvW, eqkvT, 512, 1536);
  tconv_kernel<<<dim3(16, 16, 4), 256, 0, stream>>>(e_projW, eprojT, 512, 512);
  tconv_kernel<<<dim3(64, 16, 4), 256, 0, stream>>>(e_f1W, ef1T, 512, 2048);
  tconv_kernel<<<dim3(16, 64, 4), 256, 0, stream>>>(e_f2W, ef2T, 2048, 512);
  tconv_kernel<<<dim3(16, 8, 1), 256, 0, stream>>>(up1W, up1T, 256, 512);
  tconv_kernel<<<dim3(16, 16, 1), 256, 0, stream>>>(up2W, up2T, 512, 512);
  tconv_kernel<<<dim3(48, 16, 1), 256, 0, stream>>>(r_qkvW, rqkvT, 512, 1536);
  tconv_kernel<<<dim3(16, 16, 1), 256, 0, stream>>>(r_projW, rprojT, 512, 512);
  tconv_kernel<<<dim3(64, 16, 1), 256, 0, stream>>>(r_f1W, rf1T, 512, 2048);
  tconv_kernel<<<dim3(16, 64, 1), 256, 0, stream>>>(r_f2W, rf2T, 2048, 512);
  conv_kernel<<<(1048576 + 255) / 256, 256, 0, stream>>>(X_lr, Xlrb, 1048576);
  build_s_kernel<<<(512 * 512 + 255) / 256, 256, 0, stream>>>(dec_W, Sb, Dm, 4);

  // ---- input projection ----
  mgemm_kernel<<<dim3(4, 32), 256, 0, stream>>>(
      Xlrb, ipWt, ip_b, nullptr, Hf, nullptr, Bb * NLR, Dm, NLR, 0);
  ln_kernel<<<Bb * NLR, 256, 0, stream>>>(Hf, H, nullptr, ip_g, ip_bt, Dm, 1);

  // ---- encoder ----
  for (int l = 0; l < Ll; ++l) {
    ln_kernel<<<Bb * NLR, 256, 0, stream>>>(H, nullptr, XNb, e_n1g + l * Dm, e_n1b + l * Dm, Dm, 0);
    qkv_gemm_kernel<<<dim3(12, 32), 256, 0, stream>>>(
        XNb, eqkvT + (size_t)l * 1536 * 512, e_qkvb + l * 1536, BIGb,
        Bb * NLR, Dm, NLR, 8);
    fattn_kernel<<<dim3(4, 8, 16), 256, 0, stream>>>(
        Q_e, K_e, V_e, AOb, A_lr, e_ebW + l * NHh, e_ebs + l, NLR);
    mgemm_kernel<<<dim3(4, 32), 256, 0, stream>>>(
        AOb, eprojT + (size_t)l * 512 * 512, e_projb + l * Dm, H,
        H, nullptr, Bb * NLR, Dm, Dm, 0);
    ln_kernel<<<Bb * NLR, 256, 0, stream>>>(H, nullptr, XNb, e_n2g + l * Dm, e_n2b + l * Dm, Dm, 0);
    mgemm_kernel<<<dim3(16, 32), 256, 0, stream>>>(
        XNb, ef1T + (size_t)l * 2048 * 512, e_f1b + l * FF, nullptr,
        nullptr, BIGb, Bb * NLR, FF, Dm, 1);
    mgemm_kernel<<<dim3(4, 32), 256, 0, stream>>>(
        BIGb, ef2T + (size_t)l * 512 * 2048, e_f2b + l * Dm, H,
        H, nullptr, Bb * NLR, Dm, FF, 0);
  }

  // ---- upsampler ----
  ln_kernel<<<Bb * NLR, 256, 0, stream>>>(H, nullptr, XNb, encn_g, encn_b, Dm, 0);
  transpose_kernel<bf><<<dim3(16, 8, Bb), 256, 0, stream>>>(XNb, AOb, NLR, Dm);
  mgemm_kernel<<<dim3(4, 64), 256, 0, stream>>>(
      AOb, up1T, up1b, nullptr, nullptr, BIGb, Bb * Dm, NHR, NLR, 1);
  mgemm_kernel<<<dim3(4, 64), 256, 0, stream>>>(
      BIGb, up2T, up2b, nullptr, Hf, nullptr, Bb * Dm, NHR, NHR, 0);
  transpose_kernel<float><<<dim3(16, 16, Bb), 256, 0, stream>>>(Hf, H, Dm, NHR);

  // ---- refiner ----
  ln_kernel<<<Bb * NHR, 256, 0, stream>>>(H, nullptr, XNb, r_n1g, r_n1b, Dm, 0);
  qkv_gemm_kernel<<<dim3(12, 64), 256, 0, stream>>>(
      XNb, rqkvT, r_qkvb, BIGb, Bb * NHR, Dm, NHR, 9);
  fattn_kernel<<<dim3(8, 8, 16), 256, 0, stream>>>(
      Q_r, K_r, V_r, AOb, nullptr, nullptr, nullptr, NHR);
  mgemm_kernel<<<dim3(4, 64), 256, 0, stream>>>(
      AOb, rprojT, r_projb, H, H, nullptr, Bb * NHR, Dm, Dm, 0);
  ln_kernel<<<Bb * NHR, 256, 0, stream>>>(H, nullptr, XNb, r_n2g, r_n2b, Dm, 0);
  mgemm_kernel<<<dim3(16, 64), 256, 0, stream>>>(
      XNb, rf1T, r_f1b, nullptr, nullptr, BIGb, Bb * NHR, FF, Dm, 1);
  mgemm_kernel<<<dim3(4, 64), 256, 0, stream>>>(
      BIGb, rf2T, r_f2b, H, H, nullptr, Bb * NHR, Dm, FF, 0);

  // ---- decoder ----
  ln_kernel<<<Bb * NHR, 256, 0, stream>>>(H, nullptr, XNb, hrn_g, hrn_b, Dm, 0);
  mgemm_kernel<<<dim3(4, 64), 256, 0, stream>>>(
      XNb, Sb, nullptr, nullptr, nullptr, AOb, Bb * NHR, Dm, Dm, 0);
  dec_mfma_kernel<<<dim3(10, Bb), 256, 0, stream>>>(
      AOb, XNb, dec_b, (float*)d_out);
}

// Round 6
// 1235.170 us; speedup vs baseline: 5.2009x; 1.2029x over previous
//
#include <hip/hip_runtime.h>
#include <hip/hip_bf16.h>
#include <math.h>

#define DEV __device__ __forceinline__

typedef __attribute__((ext_vector_type(8))) short bf16x8;
typedef __attribute__((ext_vector_type(4))) float f32x4;

DEV float gelu_f(float x) { return 0.5f * x * (1.0f + erff(x * 0.70710678118654752f)); }

DEV float block_reduce(float v, bool is_sum, float* red) {
#pragma unroll
  for (int off = 32; off > 0; off >>= 1) {
    float o = __shfl_down(v, off, 64);
    v = is_sum ? (v + o) : fmaxf(v, o);
  }
  __syncthreads();
  if ((threadIdx.x & 63) == 0) red[threadIdx.x >> 6] = v;
  __syncthreads();
  return is_sum ? (red[0] + red[1] + red[2] + red[3])
                : fmaxf(fmaxf(red[0], red[1]), fmaxf(red[2], red[3]));
}

DEV short bf16s(float x) {
  __hip_bfloat16 v = __float2bfloat16(x);
  return *reinterpret_cast<short*>(&v);
}

// async 16B global->LDS (gfx950). lds must be wave-uniform base; dest = base + lane*16.
DEV void async16(void* lds, const void* g) {
  __builtin_amdgcn_global_load_lds(
      (const __attribute__((address_space(1))) unsigned int*)g,
      (__attribute__((address_space(3))) unsigned int*)lds, 16, 0, 0);
}

// ---------- conversion kernels ----------
__global__ __launch_bounds__(256) void conv_kernel(
    const float* __restrict__ X, __hip_bfloat16* __restrict__ Y, int n) {
  int i = blockIdx.x * 256 + threadIdx.x;
  if (i < n) Y[i] = __float2bfloat16(X[i]);
}

__global__ __launch_bounds__(256) void tconv_kernel(
    const float* __restrict__ X, __hip_bfloat16* __restrict__ Y, int R, int C) {
  __shared__ float t[32][33];
  const float* xb = X + (size_t)blockIdx.z * R * C;
  __hip_bfloat16* yb = Y + (size_t)blockIdx.z * R * C;
  int c0 = blockIdx.x * 32, r0 = blockIdx.y * 32;
  int tx = threadIdx.x & 31, ty = threadIdx.x >> 5;
  for (int i = ty; i < 32; i += 8) t[i][tx] = xb[(size_t)(r0 + i) * C + c0 + tx];
  __syncthreads();
  for (int i = ty; i < 32; i += 8)
    yb[(size_t)(c0 + i) * R + r0 + tx] = __float2bfloat16(t[tx][i]);
}

__global__ __launch_bounds__(256) void build_s_kernel(
    const float* __restrict__ W, __hip_bfloat16* __restrict__ S, int D, int Kk) {
  int i = blockIdx.x * 256 + threadIdx.x;
  if (i >= D * D) return;
  int d = i / D, e = i % D;
  float s = 0.f;
  for (int k = 0; k < Kk; ++k) {
    s += W[(size_t)k * D * D + i];
    s += W[(size_t)k * D * D + (size_t)e * D + d];
  }
  S[i] = __float2bfloat16(s / (2.0f * Kk));
}

// ---------- MFMA GEMM (swizzled LDS + async staging) ----------
// C = act(A @ Bt^T + bias) (+resid). A: MxK bf16, Bt: NxK bf16. 128x128, BK=64.
__global__ __launch_bounds__(256) void mgemm_kernel(
    const __hip_bfloat16* __restrict__ A, const __hip_bfloat16* __restrict__ Bt,
    const float* __restrict__ bias, const float* __restrict__ resid,
    float* __restrict__ outf, __hip_bfloat16* __restrict__ outb,
    int M, int N, int K, int act) {
  __shared__ __align__(16) short As[128 * 64];
  __shared__ __align__(16) short Bs[128 * 64];
  const int tid = threadIdx.x;
  const int lane = tid & 63, wave = tid >> 6;
  const int quad = lane >> 4, l15 = lane & 15;
  const int mw = (wave >> 1) * 64, nw = (wave & 1) * 64;
  const int row0 = blockIdx.y * 128, col0 = blockIdx.x * 128;
  const short* Ag = (const short*)A;
  const short* Bg = (const short*)Bt;
  f32x4 acc[4][4] = {};

  for (int k0 = 0; k0 < K; k0 += 64) {
    __syncthreads();
#pragma unroll
    for (int i = 0; i < 4; ++i) {
      int c = (wave * 4 + i) * 64 + lane;  // chunk id 0..1023
      int r = c >> 3, p = c & 7;
      int kc = p ^ (r & 7);                // logical chunk stored at physical p
      async16(&As[(wave * 4 + i) * 512], &Ag[(size_t)(row0 + r) * K + k0 + kc * 8]);
      async16(&Bs[(wave * 4 + i) * 512], &Bg[(size_t)(col0 + r) * K + k0 + kc * 8]);
    }
    __syncthreads();
#pragma unroll
    for (int kh = 0; kh < 2; ++kh) {
      const int sw = l15 & 7;
      const int ch = ((quad + kh * 4) ^ sw) * 8;
      bf16x8 af[4], bq[4];
#pragma unroll
      for (int mi = 0; mi < 4; ++mi)
        af[mi] = *(const bf16x8*)&As[(mw + mi * 16 + l15) * 64 + (((quad + kh * 4) ^ sw) * 8)];
#pragma unroll
      for (int ni = 0; ni < 4; ++ni)
        bq[ni] = *(const bf16x8*)&Bs[(nw + ni * 16 + l15) * 64 + ch];
#pragma unroll
      for (int mi = 0; mi < 4; ++mi)
#pragma unroll
        for (int ni = 0; ni < 4; ++ni)
          acc[mi][ni] = __builtin_amdgcn_mfma_f32_16x16x32_bf16(af[mi], bq[ni], acc[mi][ni], 0, 0, 0);
    }
  }

#pragma unroll
  for (int mi = 0; mi < 4; ++mi) {
#pragma unroll
    for (int ni = 0; ni < 4; ++ni) {
      int cc = col0 + nw + ni * 16 + l15;
      float bb = bias ? bias[cc] : 0.f;
#pragma unroll
      for (int r = 0; r < 4; ++r) {
        int rr = row0 + mw + mi * 16 + quad * 4 + r;
        size_t idx = (size_t)rr * N + cc;
        float v = acc[mi][ni][r] + bb;
        if (act) v = gelu_f(v);
        if (resid) v += resid[idx];
        if (outf) outf[idx] = v;
        if (outb) outb[idx] = __float2bfloat16(v);
      }
    }
  }
}

// ---------- QKV GEMM with head-layout scatter epilogue ----------
__global__ __launch_bounds__(256) void qkv_gemm_kernel(
    const __hip_bfloat16* __restrict__ A, const __hip_bfloat16* __restrict__ Bt,
    const float* __restrict__ bias, __hip_bfloat16* __restrict__ qkv,
    int M, int K, int nseq, int lgn) {
  __shared__ __align__(16) short As[128 * 64];
  __shared__ __align__(16) short Bs[128 * 64];
  const int tid = threadIdx.x;
  const int lane = tid & 63, wave = tid >> 6;
  const int quad = lane >> 4, l15 = lane & 15;
  const int mw = (wave >> 1) * 64, nw = (wave & 1) * 64;
  const int row0 = blockIdx.y * 128, col0 = blockIdx.x * 128;
  const short* Ag = (const short*)A;
  const short* Bg = (const short*)Bt;
  f32x4 acc[4][4] = {};

  for (int k0 = 0; k0 < K; k0 += 64) {
    __syncthreads();
#pragma unroll
    for (int i = 0; i < 4; ++i) {
      int c = (wave * 4 + i) * 64 + lane;
      int r = c >> 3, p = c & 7;
      int kc = p ^ (r & 7);
      async16(&As[(wave * 4 + i) * 512], &Ag[(size_t)(row0 + r) * K + k0 + kc * 8]);
      async16(&Bs[(wave * 4 + i) * 512], &Bg[(size_t)(col0 + r) * K + k0 + kc * 8]);
    }
    __syncthreads();
#pragma unroll
    for (int kh = 0; kh < 2; ++kh) {
      const int sw = l15 & 7;
      const int ch = ((quad + kh * 4) ^ sw) * 8;
      bf16x8 af[4], bq[4];
#pragma unroll
      for (int mi = 0; mi < 4; ++mi)
        af[mi] = *(const bf16x8*)&As[(mw + mi * 16 + l15) * 64 + ch];
#pragma unroll
      for (int ni = 0; ni < 4; ++ni)
        bq[ni] = *(const bf16x8*)&Bs[(nw + ni * 16 + l15) * 64 + ch];
#pragma unroll
      for (int mi = 0; mi < 4; ++mi)
#pragma unroll
        for (int ni = 0; ni < 4; ++ni)
          acc[mi][ni] = __builtin_amdgcn_mfma_f32_16x16x32_bf16(af[mi], bq[ni], acc[mi][ni], 0, 0, 0);
    }
  }

  const size_t PART = (size_t)M * 512;
#pragma unroll
  for (int mi = 0; mi < 4; ++mi) {
#pragma unroll
    for (int ni = 0; ni < 4; ++ni) {
      int cc = col0 + nw + ni * 16 + l15;  // 0..1535
      float bb = bias ? bias[cc] : 0.f;
      int which = cc >> 9;
      int h = (cc >> 6) & 7;
      int d = cc & 63;
#pragma unroll
      for (int r = 0; r < 4; ++r) {
        int rr = row0 + mw + mi * 16 + quad * 4 + r;
        int b = rr >> lgn;
        int nn = rr & (nseq - 1);
        float v = acc[mi][ni][r] + bb;
        size_t dst;
        if (which == 2) {
          dst = 2 * PART + (((size_t)b * 8 + h) * 64 + d) * nseq + nn;
        } else {
          dst = (size_t)which * PART + (((size_t)b * 8 + h) * nseq + nn) * 64 + d;
        }
        qkv[dst] = __float2bfloat16(v);
      }
    }
  }
}

// ---------- fused flash attention (MFMA) ----------
__global__ __launch_bounds__(256) void fattn_kernel(
    const __hip_bfloat16* __restrict__ Qh, const __hip_bfloat16* __restrict__ Kh,
    const __hip_bfloat16* __restrict__ Vt, __hip_bfloat16* __restrict__ O,
    const float* __restrict__ Abias, const float* __restrict__ ebW,
    const float* __restrict__ ebs, int N) {
  __shared__ __align__(16) short Ks[64][72];
  __shared__ __align__(16) short Vs[64][72];
  __shared__ __align__(16) short Ps[4][16][72];
  const int qt = blockIdx.x, h = blockIdx.y, b = blockIdx.z;
  const int tid = threadIdx.x, lane = tid & 63, wave = tid >> 6;
  const int quad = lane >> 4, l15 = lane & 15;
  const size_t hb = (size_t)b * 8 + h;
  const short* Qg = (const short*)Qh + hb * N * 64;
  const short* Kg = (const short*)Kh + hb * N * 64;
  const short* Vg = (const short*)Vt + hb * 64 * N;
  const float scale = 0.125f;
  const bool hasb = (Abias != nullptr);
  const float bscale = hasb ? ebs[0] * ebW[h] : 0.f;
  const int qrow_w = qt * 64 + wave * 16;

  bf16x8 qf0 = *(const bf16x8*)&Qg[(size_t)(qrow_w + l15) * 64 + quad * 8];
  bf16x8 qf1 = *(const bf16x8*)&Qg[(size_t)(qrow_w + l15) * 64 + quad * 8 + 32];

  float m_i[4], l_i[4];
  f32x4 oacc[4] = {};
#pragma unroll
  for (int r = 0; r < 4; ++r) { m_i[r] = -1e30f; l_i[r] = 0.f; }

  for (int k0 = 0; k0 < N; k0 += 64) {
    __syncthreads();
#pragma unroll
    for (int i = 0; i < 2; ++i) {
      int idx = i * 256 + tid;
      int r = idx >> 3, ch = idx & 7;
      *(uint4*)&Ks[r][ch * 8] = *(const uint4*)&Kg[(size_t)(k0 + r) * 64 + ch * 8];
      *(uint4*)&Vs[r][ch * 8] = *(const uint4*)&Vg[(size_t)r * N + k0 + ch * 8];
    }
    __syncthreads();

    f32x4 s[4] = {};
#pragma unroll
    for (int ni = 0; ni < 4; ++ni) {
      bf16x8 kf0 = *(const bf16x8*)&Ks[ni * 16 + l15][quad * 8];
      bf16x8 kf1 = *(const bf16x8*)&Ks[ni * 16 + l15][quad * 8 + 32];
      s[ni] = __builtin_amdgcn_mfma_f32_16x16x32_bf16(qf0, kf0, s[ni], 0, 0, 0);
      s[ni] = __builtin_amdgcn_mfma_f32_16x16x32_bf16(qf1, kf1, s[ni], 0, 0, 0);
    }
    if (hasb) {
#pragma unroll
      for (int ni = 0; ni < 4; ++ni)
#pragma unroll
        for (int r = 0; r < 4; ++r) {
          int qq = qrow_w + quad * 4 + r;
          int kk = k0 + ni * 16 + l15;
          s[ni][r] = s[ni][r] * scale + bscale * Abias[((size_t)b * N + qq) * N + kk];
        }
    } else {
#pragma unroll
      for (int ni = 0; ni < 4; ++ni)
#pragma unroll
        for (int r = 0; r < 4; ++r) s[ni][r] *= scale;
    }

    float mt[4];
#pragma unroll
    for (int r = 0; r < 4; ++r)
      mt[r] = fmaxf(fmaxf(s[0][r], s[1][r]), fmaxf(s[2][r], s[3][r]));
#pragma unroll
    for (int off = 1; off < 16; off <<= 1)
#pragma unroll
      for (int r = 0; r < 4; ++r) mt[r] = fmaxf(mt[r], __shfl_xor(mt[r], off, 64));

    float alpha[4];
#pragma unroll
    for (int r = 0; r < 4; ++r) {
      float mn = fmaxf(m_i[r], mt[r]);
      alpha[r] = __expf(m_i[r] - mn);
      m_i[r] = mn;
    }
    float ls[4] = {0.f, 0.f, 0.f, 0.f};
#pragma unroll
    for (int ni = 0; ni < 4; ++ni)
#pragma unroll
      for (int r = 0; r < 4; ++r) {
        float p = __expf(s[ni][r] - m_i[r]);
        s[ni][r] = p;
        ls[r] += p;
      }
#pragma unroll
    for (int off = 1; off < 16; off <<= 1)
#pragma unroll
      for (int r = 0; r < 4; ++r) ls[r] += __shfl_xor(ls[r], off, 64);
#pragma unroll
    for (int r = 0; r < 4; ++r) l_i[r] = l_i[r] * alpha[r] + ls[r];
#pragma unroll
    for (int ni = 0; ni < 4; ++ni)
#pragma unroll
      for (int r = 0; r < 4; ++r) oacc[ni][r] *= alpha[r];

#pragma unroll
    for (int ni = 0; ni < 4; ++ni)
#pragma unroll
      for (int r = 0; r < 4; ++r)
        Ps[wave][quad * 4 + r][ni * 16 + l15] = bf16s(s[ni][r]);

    bf16x8 pf0 = *(const bf16x8*)&Ps[wave][l15][quad * 8];
    bf16x8 pf1 = *(const bf16x8*)&Ps[wave][l15][quad * 8 + 32];
#pragma unroll
    for (int ni = 0; ni < 4; ++ni) {
      bf16x8 vf0 = *(const bf16x8*)&Vs[ni * 16 + l15][quad * 8];
      bf16x8 vf1 = *(const bf16x8*)&Vs[ni * 16 + l15][quad * 8 + 32];
      oacc[ni] = __builtin_amdgcn_mfma_f32_16x16x32_bf16(pf0, vf0, oacc[ni], 0, 0, 0);
      oacc[ni] = __builtin_amdgcn_mfma_f32_16x16x32_bf16(pf1, vf1, oacc[ni], 0, 0, 0);
    }
  }

  float inv[4];
#pragma unroll
  for (int r = 0; r < 4; ++r) inv[r] = 1.f / l_i[r];
#pragma unroll
  for (int ni = 0; ni < 4; ++ni)
#pragma unroll
    for (int r = 0; r < 4; ++r) {
      int nn = qrow_w + quad * 4 + r;
      int col = h * 64 + ni * 16 + l15;
      O[((size_t)b * N + nn) * 512 + col] = __float2bfloat16(oacc[ni][r] * inv[r]);
    }
}

// ---------- decoder: 64x64 tiles, 36 triu pairs x 16 batches ----------
__global__ __launch_bounds__(256) void dec_mfma_kernel(
    const __hip_bfloat16* __restrict__ Tb_, const __hip_bfloat16* __restrict__ Hb_,
    const float* __restrict__ dec_b, float* __restrict__ out) {
  const int Nn = 512, K = 512;
  __shared__ __align__(16) short As[64 * 64];
  __shared__ __align__(16) short Bs[64 * 64];
  int p = blockIdx.x;  // 0..35
  int bb = blockIdx.y;
  int it = 0, rem = p;
  while (rem >= 8 - it) { rem -= 8 - it; ++it; }
  int jt = it + rem;
  const int row0 = it * 64, col0 = jt * 64;
  const int tid = threadIdx.x;
  const int lane = tid & 63, wave = tid >> 6;
  const int quad = lane >> 4, l15 = lane & 15;
  const int wr = (wave >> 1) * 32, wc = (wave & 1) * 32;
  const short* Ag = (const short*)(Tb_ + (size_t)bb * Nn * K);
  const short* Bg = (const short*)(Hb_ + (size_t)bb * Nn * K);
  f32x4 acc[2][2] = {};

  for (int k0 = 0; k0 < K; k0 += 64) {
    __syncthreads();
#pragma unroll
    for (int i = 0; i < 2; ++i) {
      int c = (wave * 2 + i) * 64 + lane;  // chunk 0..511
      int r = c >> 3, pp = c & 7;
      int kc = pp ^ (r & 7);
      async16(&As[(wave * 2 + i) * 512], &Ag[(size_t)(row0 + r) * K + k0 + kc * 8]);
      async16(&Bs[(wave * 2 + i) * 512], &Bg[(size_t)(col0 + r) * K + k0 + kc * 8]);
    }
    __syncthreads();
#pragma unroll
    for (int kh = 0; kh < 2; ++kh) {
      const int sw = l15 & 7;
      const int ch = ((quad + kh * 4) ^ sw) * 8;
      bf16x8 af[2], bq[2];
#pragma unroll
      for (int mi = 0; mi < 2; ++mi)
        af[mi] = *(const bf16x8*)&As[(wr + mi * 16 + l15) * 64 + ch];
#pragma unroll
      for (int ni = 0; ni < 2; ++ni)
        bq[ni] = *(const bf16x8*)&Bs[(wc + ni * 16 + l15) * 64 + ch];
#pragma unroll
      for (int mi = 0; mi < 2; ++mi)
#pragma unroll
        for (int ni = 0; ni < 2; ++ni)
          acc[mi][ni] = __builtin_amdgcn_mfma_f32_16x16x32_bf16(af[mi], bq[ni], acc[mi][ni], 0, 0, 0);
    }
  }

  float db = dec_b[0];
  size_t obase = (size_t)bb * ((size_t)Nn * (Nn - 1) / 2);
#pragma unroll
  for (int mi = 0; mi < 2; ++mi) {
#pragma unroll
    for (int ni = 0; ni < 2; ++ni) {
      int j = col0 + wc + ni * 16 + l15;
#pragma unroll
      for (int r = 0; r < 4; ++r) {
        int i = row0 + wr + mi * 16 + quad * 4 + r;
        if (j > i) {
          float x = acc[mi][ni][r] + db;
          float sp = fmaxf(x, 0.f) + __logf(1.f + __expf(-fabsf(x)));
          out[obase + (size_t)i * (2 * Nn - i - 1) / 2 + (j - i - 1)] = sp;
        }
      }
    }
  }
}

// ---------- LayerNorm ----------
__global__ __launch_bounds__(256) void ln_kernel(
    const float* __restrict__ X, float* __restrict__ outf,
    __hip_bfloat16* __restrict__ outb, const float* __restrict__ g,
    const float* __restrict__ b, int D, int do_gelu) {
  __shared__ float red[4];
  int row = blockIdx.x;
  const float* x = X + (size_t)row * D;
  float s = 0.f, s2 = 0.f;
  for (int d = threadIdx.x; d < D; d += 256) {
    float v = x[d];
    s += v;
    s2 += v * v;
  }
  s = block_reduce(s, true, red);
  s2 = block_reduce(s2, true, red);
  float mean = s / D;
  float var = s2 / D - mean * mean;
  float inv = rsqrtf(var + 1e-5f);
  for (int d = threadIdx.x; d < D; d += 256) {
    float v = (x[d] - mean) * inv * g[d] + b[d];
    if (do_gelu) v = gelu_f(v);
    if (outf) outf[(size_t)row * D + d] = v;
    if (outb) outb[(size_t)row * D + d] = __float2bfloat16(v);
  }
}

// ---------- batched transpose ----------
template <typename T>
__global__ __launch_bounds__(256) void transpose_kernel(
    const T* __restrict__ X, T* __restrict__ Y, int R, int C) {
  __shared__ T t[32][33];
  const T* xb = X + (size_t)blockIdx.z * R * C;
  T* yb = Y + (size_t)blockIdx.z * R * C;
  int c0 = blockIdx.x * 32, r0 = blockIdx.y * 32;
  int tx = threadIdx.x & 31, ty = threadIdx.x >> 5;
  for (int i = ty; i < 32; i += 8) t[i][tx] = xb[(size_t)(r0 + i) * C + c0 + tx];
  __syncthreads();
  for (int i = ty; i < 32; i += 8) yb[(size_t)(c0 + i) * R + r0 + tx] = t[tx][i];
}

// ---------- host ----------
extern "C" void kernel_launch(void* const* d_in, const int* in_sizes, int n_in,
                              void* d_out, int out_size, void* d_ws, size_t ws_size,
                              hipStream_t stream) {
  const float *A_lr = (const float*)d_in[0], *X_lr = (const float*)d_in[1],
              *ip_W = (const float*)d_in[2], *ip_b = (const float*)d_in[3],
              *ip_g = (const float*)d_in[4], *ip_bt = (const float*)d_in[5],
              *e_n1g = (const float*)d_in[6], *e_n1b = (const float*)d_in[7],
              *e_qkvW = (const float*)d_in[8], *e_qkvb = (const float*)d_in[9],
              *e_projW = (const float*)d_in[10], *e_projb = (const float*)d_in[11],
              *e_ebW = (const float*)d_in[12], *e_ebs = (const float*)d_in[13],
              *e_n2g = (const float*)d_in[14], *e_n2b = (const float*)d_in[15],
              *e_f1W = (const float*)d_in[16], *e_f1b = (const float*)d_in[17],
              *e_f2W = (const float*)d_in[18], *e_f2b = (const float*)d_in[19],
              *encn_g = (const float*)d_in[20], *encn_b = (const float*)d_in[21],
              *up1W = (const float*)d_in[22], *up1b = (const float*)d_in[23],
              *up2W = (const float*)d_in[24], *up2b = (const float*)d_in[25],
              *r_n1g = (const float*)d_in[26], *r_n1b = (const float*)d_in[27],
              *r_qkvW = (const float*)d_in[28], *r_qkvb = (const float*)d_in[29],
              *r_projW = (const float*)d_in[30], *r_projb = (const float*)d_in[31],
              *r_n2g = (const float*)d_in[32], *r_n2b = (const float*)d_in[33],
              *r_f1W = (const float*)d_in[34], *r_f1b = (const float*)d_in[35],
              *r_f2W = (const float*)d_in[36], *r_f2b = (const float*)d_in[37],
              *hrn_g = (const float*)d_in[38], *hrn_b = (const float*)d_in[39],
              *dec_W = (const float*)d_in[40], *dec_b = (const float*)d_in[41];

  const int Bb = 16, NLR = 256, NHR = 512, Dm = 512, NHh = 8, FF = 2048, Ll = 4;
  typedef __hip_bfloat16 bf;

  float* ws = (float*)d_ws;
  float* H = ws;                                  // 4M fp32
  float* Hf = ws + 4194304;                       // 4M fp32
  bf* XNb = (bf*)(ws + 8388608);                  // 4M bf16
  bf* AOb = (bf*)(ws + 10485760);                 // 4M bf16 (Htb / Ttb / attn out)
  bf* BIGb = (bf*)(ws + 12582912);                // 16.78M bf16 (QKV slab / FFN hidden)
  bf* WB = (bf*)(ws + 20971520);                  // bf16 weights
  bf* Xlrb = (bf*)(ws + 29229056);                // 1.05M bf16

  size_t o = 0;
  bf* ipWt = WB + o;   o += (size_t)512 * 256;
  bf* eqkvT = WB + o;  o += (size_t)4 * 1536 * 512;
  bf* eprojT = WB + o; o += (size_t)4 * 512 * 512;
  bf* ef1T = WB + o;   o += (size_t)4 * 2048 * 512;
  bf* ef2T = WB + o;   o += (size_t)4 * 512 * 2048;
  bf* up1T = WB + o;   o += (size_t)512 * 256;
  bf* up2T = WB + o;   o += (size_t)512 * 512;
  bf* rqkvT = WB + o;  o += (size_t)1536 * 512;
  bf* rprojT = WB + o; o += (size_t)512 * 512;
  bf* rf1T = WB + o;   o += (size_t)2048 * 512;
  bf* rf2T = WB + o;   o += (size_t)512 * 2048;
  bf* Sb = WB + o;     o += (size_t)512 * 512;

  bf* Q_e = BIGb;
  bf* K_e = BIGb + 2097152;
  bf* V_e = BIGb + 4194304;
  bf* Q_r = BIGb;
  bf* K_r = BIGb + 4194304;
  bf* V_r = BIGb + 8388608;

  // ---- conversions ----
  tconv_kernel<<<dim3(16, 8, 1), 256, 0, stream>>>(ip_W, ipWt, 256, 512);
  tconv_kernel<<<dim3(48, 16, 4), 256, 0, stream>>>(e_qkvW, eqkvT, 512, 1536);
  tconv_kernel<<<dim3(16, 16, 4), 256, 0, stream>>>(e_projW, eprojT, 512, 512);
  tconv_kernel<<<dim3(64, 16, 4), 256, 0, stream>>>(e_f1W, ef1T, 512, 2048);
  tconv_kernel<<<dim3(16, 64, 4), 256, 0, stream>>>(e_f2W, ef2T, 2048, 512);
  tconv_kernel<<<dim3(16, 8, 1), 256, 0, stream>>>(up1W, up1T, 256, 512);
  tconv_kernel<<<dim3(16, 16, 1), 256, 0, stream>>>(up2W, up2T, 512, 512);
  tconv_kernel<<<dim3(48, 16, 1), 256, 0, stream>>>(r_qkvW, rqkvT, 512, 1536);
  tconv_kernel<<<dim3(16, 16, 1), 256, 0, stream>>>(r_projW, rprojT, 512, 512);
  tconv_kernel<<<dim3(64, 16, 1), 256, 0, stream>>>(r_f1W, rf1T, 512, 2048);
  tconv_kernel<<<dim3(16, 64, 1), 256, 0, stream>>>(r_f2W, rf2T, 2048, 512);
  conv_kernel<<<(1048576 + 255) / 256, 256, 0, stream>>>(X_lr, Xlrb, 1048576);
  build_s_kernel<<<(512 * 512 + 255) / 256, 256, 0, stream>>>(dec_W, Sb, Dm, 4);

  // ---- input projection ----
  mgemm_kernel<<<dim3(4, 32), 256, 0, stream>>>(
      Xlrb, ipWt, ip_b, nullptr, Hf, nullptr, Bb * NLR, Dm, NLR, 0);
  ln_kernel<<<Bb * NLR, 256, 0, stream>>>(Hf, H, nullptr, ip_g, ip_bt, Dm, 1);

  // ---- encoder ----
  for (int l = 0; l < Ll; ++l) {
    ln_kernel<<<Bb * NLR, 256, 0, stream>>>(H, nullptr, XNb, e_n1g + l * Dm, e_n1b + l * Dm, Dm, 0);
    qkv_gemm_kernel<<<dim3(12, 32), 256, 0, stream>>>(
        XNb, eqkvT + (size_t)l * 1536 * 512, e_qkvb + l * 1536, BIGb,
        Bb * NLR, Dm, NLR, 8);
    fattn_kernel<<<dim3(4, 8, 16), 256, 0, stream>>>(
        Q_e, K_e, V_e, AOb, A_lr, e_ebW + l * NHh, e_ebs + l, NLR);
    mgemm_kernel<<<dim3(4, 32), 256, 0, stream>>>(
        AOb, eprojT + (size_t)l * 512 * 512, e_projb + l * Dm, H,
        H, nullptr, Bb * NLR, Dm, Dm, 0);
    ln_kernel<<<Bb * NLR, 256, 0, stream>>>(H, nullptr, XNb, e_n2g + l * Dm, e_n2b + l * Dm, Dm, 0);
    mgemm_kernel<<<dim3(16, 32), 256, 0, stream>>>(
        XNb, ef1T + (size_t)l * 2048 * 512, e_f1b + l * FF, nullptr,
        nullptr, BIGb, Bb * NLR, FF, Dm, 1);
    mgemm_kernel<<<dim3(4, 32), 256, 0, stream>>>(
        BIGb, ef2T + (size_t)l * 512 * 2048, e_f2b + l * Dm, H,
        H, nullptr, Bb * NLR, Dm, FF, 0);
  }

  // ---- upsampler ----
  ln_kernel<<<Bb * NLR, 256, 0, stream>>>(H, nullptr, XNb, encn_g, encn_b, Dm, 0);
  transpose_kernel<bf><<<dim3(16, 8, Bb), 256, 0, stream>>>(XNb, AOb, NLR, Dm);
  mgemm_kernel<<<dim3(4, 64), 256, 0, stream>>>(
      AOb, up1T, up1b, nullptr, nullptr, BIGb, Bb * Dm, NHR, NLR, 1);
  mgemm_kernel<<<dim3(4, 64), 256, 0, stream>>>(
      BIGb, up2T, up2b, nullptr, Hf, nullptr, Bb * Dm, NHR, NHR, 0);
  transpose_kernel<float><<<dim3(16, 16, Bb), 256, 0, stream>>>(Hf, H, Dm, NHR);

  // ---- refiner ----
  ln_kernel<<<Bb * NHR, 256, 0, stream>>>(H, nullptr, XNb, r_n1g, r_n1b, Dm, 0);
  qkv_gemm_kernel<<<dim3(12, 64), 256, 0, stream>>>(
      XNb, rqkvT, r_qkvb, BIGb, Bb * NHR, Dm, NHR, 9);
  fattn_kernel<<<dim3(8, 8, 16), 256, 0, stream>>>(
      Q_r, K_r, V_r, AOb, nullptr, nullptr, nullptr, NHR);
  mgemm_kernel<<<dim3(4, 64), 256, 0, stream>>>(
      AOb, rprojT, r_projb, H, H, nullptr, Bb * NHR, Dm, Dm, 0);
  ln_kernel<<<Bb * NHR, 256, 0, stream>>>(H, nullptr, XNb, r_n2g, r_n2b, Dm, 0);
  mgemm_kernel<<<dim3(16, 64), 256, 0, stream>>>(
      XNb, rf1T, r_f1b, nullptr, nullptr, BIGb, Bb * NHR, FF, Dm, 1);
  mgemm_kernel<<<dim3(4, 64), 256, 0, stream>>>(
      BIGb, rf2T, r_f2b, H, H, nullptr, Bb * NHR, Dm, FF, 0);

  // ---- decoder ----
  ln_kernel<<<Bb * NHR, 256, 0, stream>>>(H, nullptr, XNb, hrn_g, hrn_b, Dm, 0);
  mgemm_kernel<<<dim3(4, 64), 256, 0, stream>>>(
      XNb, Sb, nullptr, nullptr, nullptr, AOb, Bb * NHR, Dm, Dm, 0);
  dec_mfma_kernel<<<dim3(36, Bb), 256, 0, stream>>>(
      AOb, XNb, dec_b, (float*)d_out);
}

// Round 7
// 1209.553 us; speedup vs baseline: 5.3110x; 1.0212x over previous
//
#include <hip/hip_runtime.h>
#include <hip/hip_bf16.h>
#include <math.h>

#define DEV __device__ __forceinline__

typedef __attribute__((ext_vector_type(8))) short bf16x8;
typedef __attribute__((ext_vector_type(4))) float f32x4;

DEV float gelu_f(float x) { return 0.5f * x * (1.0f + erff(x * 0.70710678118654752f)); }

DEV float block_reduce(float v, bool is_sum, float* red) {
#pragma unroll
  for (int off = 32; off > 0; off >>= 1) {
    float o = __shfl_down(v, off, 64);
    v = is_sum ? (v + o) : fmaxf(v, o);
  }
  __syncthreads();
  if ((threadIdx.x & 63) == 0) red[threadIdx.x >> 6] = v;
  __syncthreads();
  return is_sum ? (red[0] + red[1] + red[2] + red[3])
                : fmaxf(fmaxf(red[0], red[1]), fmaxf(red[2], red[3]));
}

DEV short bf16s(float x) {
  __hip_bfloat16 v = __float2bfloat16(x);
  return *reinterpret_cast<short*>(&v);
}

// async 16B global->LDS (gfx950). dest = wave-uniform base + lane*16.
DEV void async16(void* lds, const void* g) {
  __builtin_amdgcn_global_load_lds(
      (const __attribute__((address_space(1))) unsigned int*)g,
      (__attribute__((address_space(3))) unsigned int*)lds, 16, 0, 0);
}

// ---------- conversion kernels ----------
__global__ __launch_bounds__(256) void conv_kernel(
    const float* __restrict__ X, __hip_bfloat16* __restrict__ Y, int n) {
  int i = blockIdx.x * 256 + threadIdx.x;
  if (i < n) Y[i] = __float2bfloat16(X[i]);
}

__global__ __launch_bounds__(256) void tconv_kernel(
    const float* __restrict__ X, __hip_bfloat16* __restrict__ Y, int R, int C) {
  __shared__ float t[32][33];
  const float* xb = X + (size_t)blockIdx.z * R * C;
  __hip_bfloat16* yb = Y + (size_t)blockIdx.z * R * C;
  int c0 = blockIdx.x * 32, r0 = blockIdx.y * 32;
  int tx = threadIdx.x & 31, ty = threadIdx.x >> 5;
  for (int i = ty; i < 32; i += 8) t[i][tx] = xb[(size_t)(r0 + i) * C + c0 + tx];
  __syncthreads();
  for (int i = ty; i < 32; i += 8)
    yb[(size_t)(c0 + i) * R + r0 + tx] = __float2bfloat16(t[tx][i]);
}

__global__ __launch_bounds__(256) void build_s_kernel(
    const float* __restrict__ W, __hip_bfloat16* __restrict__ S, int D, int Kk) {
  int i = blockIdx.x * 256 + threadIdx.x;
  if (i >= D * D) return;
  int d = i / D, e = i % D;
  float s = 0.f;
  for (int k = 0; k < Kk; ++k) {
    s += W[(size_t)k * D * D + i];
    s += W[(size_t)k * D * D + (size_t)e * D + d];
  }
  S[i] = __float2bfloat16(s / (2.0f * Kk));
}

// ---------- MFMA GEMM (swizzled LDS + async staging + XCD-local tiles) ----------
// 1D grid of nb*mb blocks; XCD g = bid&7 owns m-tiles [g*mgrp, (g+1)*mgrp),
// iterating m fastest (B-tile stays hot), so per-XCD L2 set = A-slice + B.
__global__ __launch_bounds__(256) void mgemm_kernel(
    const __hip_bfloat16* __restrict__ A, const __hip_bfloat16* __restrict__ Bt,
    const float* __restrict__ bias, const float* __restrict__ resid,
    float* __restrict__ outf, __hip_bfloat16* __restrict__ outb,
    int M, int N, int K, int act, int mgrp) {
  __shared__ __align__(16) short As[128 * 64];
  __shared__ __align__(16) short Bs[128 * 64];
  const int tid = threadIdx.x;
  const int lane = tid & 63, wave = tid >> 6;
  const int quad = lane >> 4, l15 = lane & 15;
  const int mw = (wave >> 1) * 64, nw = (wave & 1) * 64;
  const int bid = blockIdx.x;
  const int g = bid & 7, sidx = bid >> 3;
  const int mt = g * mgrp + sidx % mgrp;
  const int nt = sidx / mgrp;
  const int row0 = mt * 128, col0 = nt * 128;
  const short* Ag = (const short*)A;
  const short* Bg = (const short*)Bt;
  f32x4 acc[4][4] = {};

  for (int k0 = 0; k0 < K; k0 += 64) {
    __syncthreads();
#pragma unroll
    for (int i = 0; i < 4; ++i) {
      int c = (wave * 4 + i) * 64 + lane;  // chunk id 0..1023
      int r = c >> 3, p = c & 7;
      int kc = p ^ (r & 7);
      async16(&As[(wave * 4 + i) * 512], &Ag[(size_t)(row0 + r) * K + k0 + kc * 8]);
      async16(&Bs[(wave * 4 + i) * 512], &Bg[(size_t)(col0 + r) * K + k0 + kc * 8]);
    }
    __syncthreads();
#pragma unroll
    for (int kh = 0; kh < 2; ++kh) {
      const int sw = l15 & 7;
      const int ch = ((quad + kh * 4) ^ sw) * 8;
      bf16x8 af[4], bq[4];
#pragma unroll
      for (int mi = 0; mi < 4; ++mi)
        af[mi] = *(const bf16x8*)&As[(mw + mi * 16 + l15) * 64 + ch];
#pragma unroll
      for (int ni = 0; ni < 4; ++ni)
        bq[ni] = *(const bf16x8*)&Bs[(nw + ni * 16 + l15) * 64 + ch];
#pragma unroll
      for (int mi = 0; mi < 4; ++mi)
#pragma unroll
        for (int ni = 0; ni < 4; ++ni)
          acc[mi][ni] = __builtin_amdgcn_mfma_f32_16x16x32_bf16(af[mi], bq[ni], acc[mi][ni], 0, 0, 0);
    }
  }

#pragma unroll
  for (int mi = 0; mi < 4; ++mi) {
#pragma unroll
    for (int ni = 0; ni < 4; ++ni) {
      int cc = col0 + nw + ni * 16 + l15;
      float bb = bias ? bias[cc] : 0.f;
#pragma unroll
      for (int r = 0; r < 4; ++r) {
        int rr = row0 + mw + mi * 16 + quad * 4 + r;
        size_t idx = (size_t)rr * N + cc;
        float v = acc[mi][ni][r] + bb;
        if (act) v = gelu_f(v);
        if (resid) v += resid[idx];
        if (outf) outf[idx] = v;
        if (outb) outb[idx] = __float2bfloat16(v);
      }
    }
  }
}

// ---------- QKV GEMM with head-layout scatter epilogue (swizzled tiles) ----------
__global__ __launch_bounds__(256) void qkv_gemm_kernel(
    const __hip_bfloat16* __restrict__ A, const __hip_bfloat16* __restrict__ Bt,
    const float* __restrict__ bias, __hip_bfloat16* __restrict__ qkv,
    int M, int K, int nseq, int lgn, int mgrp) {
  __shared__ __align__(16) short As[128 * 64];
  __shared__ __align__(16) short Bs[128 * 64];
  const int tid = threadIdx.x;
  const int lane = tid & 63, wave = tid >> 6;
  const int quad = lane >> 4, l15 = lane & 15;
  const int mw = (wave >> 1) * 64, nw = (wave & 1) * 64;
  const int bid = blockIdx.x;
  const int g = bid & 7, sidx = bid >> 3;
  const int mt = g * mgrp + sidx % mgrp;
  const int nt = sidx / mgrp;
  const int row0 = mt * 128, col0 = nt * 128;
  const short* Ag = (const short*)A;
  const short* Bg = (const short*)Bt;
  f32x4 acc[4][4] = {};

  for (int k0 = 0; k0 < K; k0 += 64) {
    __syncthreads();
#pragma unroll
    for (int i = 0; i < 4; ++i) {
      int c = (wave * 4 + i) * 64 + lane;
      int r = c >> 3, p = c & 7;
      int kc = p ^ (r & 7);
      async16(&As[(wave * 4 + i) * 512], &Ag[(size_t)(row0 + r) * K + k0 + kc * 8]);
      async16(&Bs[(wave * 4 + i) * 512], &Bg[(size_t)(col0 + r) * K + k0 + kc * 8]);
    }
    __syncthreads();
#pragma unroll
    for (int kh = 0; kh < 2; ++kh) {
      const int sw = l15 & 7;
      const int ch = ((quad + kh * 4) ^ sw) * 8;
      bf16x8 af[4], bq[4];
#pragma unroll
      for (int mi = 0; mi < 4; ++mi)
        af[mi] = *(const bf16x8*)&As[(mw + mi * 16 + l15) * 64 + ch];
#pragma unroll
      for (int ni = 0; ni < 4; ++ni)
        bq[ni] = *(const bf16x8*)&Bs[(nw + ni * 16 + l15) * 64 + ch];
#pragma unroll
      for (int mi = 0; mi < 4; ++mi)
#pragma unroll
        for (int ni = 0; ni < 4; ++ni)
          acc[mi][ni] = __builtin_amdgcn_mfma_f32_16x16x32_bf16(af[mi], bq[ni], acc[mi][ni], 0, 0, 0);
    }
  }

  const size_t PART = (size_t)M * 512;
#pragma unroll
  for (int mi = 0; mi < 4; ++mi) {
#pragma unroll
    for (int ni = 0; ni < 4; ++ni) {
      int cc = col0 + nw + ni * 16 + l15;  // 0..1535
      float bb = bias ? bias[cc] : 0.f;
      int which = cc >> 9;
      int h = (cc >> 6) & 7;
      int d = cc & 63;
#pragma unroll
      for (int r = 0; r < 4; ++r) {
        int rr = row0 + mw + mi * 16 + quad * 4 + r;
        int b = rr >> lgn;
        int nn = rr & (nseq - 1);
        float v = acc[mi][ni][r] + bb;
        size_t dst;
        if (which == 2) {
          dst = 2 * PART + (((size_t)b * 8 + h) * 64 + d) * nseq + nn;
        } else {
          dst = (size_t)which * PART + (((size_t)b * 8 + h) * nseq + nn) * 64 + d;
        }
        qkv[dst] = __float2bfloat16(v);
      }
    }
  }
}

// ---------- fused flash attention (MFMA) ----------
__global__ __launch_bounds__(256) void fattn_kernel(
    const __hip_bfloat16* __restrict__ Qh, const __hip_bfloat16* __restrict__ Kh,
    const __hip_bfloat16* __restrict__ Vt, __hip_bfloat16* __restrict__ O,
    const float* __restrict__ Abias, const float* __restrict__ ebW,
    const float* __restrict__ ebs, int N) {
  __shared__ __align__(16) short Ks[64][72];
  __shared__ __align__(16) short Vs[64][72];
  __shared__ __align__(16) short Ps[4][16][72];
  const int qt = blockIdx.x, h = blockIdx.y, b = blockIdx.z;
  const int tid = threadIdx.x, lane = tid & 63, wave = tid >> 6;
  const int quad = lane >> 4, l15 = lane & 15;
  const size_t hb = (size_t)b * 8 + h;
  const short* Qg = (const short*)Qh + hb * N * 64;
  const short* Kg = (const short*)Kh + hb * N * 64;
  const short* Vg = (const short*)Vt + hb * 64 * N;
  const float scale = 0.125f;
  const bool hasb = (Abias != nullptr);
  const float bscale = hasb ? ebs[0] * ebW[h] : 0.f;
  const int qrow_w = qt * 64 + wave * 16;

  bf16x8 qf0 = *(const bf16x8*)&Qg[(size_t)(qrow_w + l15) * 64 + quad * 8];
  bf16x8 qf1 = *(const bf16x8*)&Qg[(size_t)(qrow_w + l15) * 64 + quad * 8 + 32];

  float m_i[4], l_i[4];
  f32x4 oacc[4] = {};
#pragma unroll
  for (int r = 0; r < 4; ++r) { m_i[r] = -1e30f; l_i[r] = 0.f; }

  for (int k0 = 0; k0 < N; k0 += 64) {
    __syncthreads();
#pragma unroll
    for (int i = 0; i < 2; ++i) {
      int idx = i * 256 + tid;
      int r = idx >> 3, ch = idx & 7;
      *(uint4*)&Ks[r][ch * 8] = *(const uint4*)&Kg[(size_t)(k0 + r) * 64 + ch * 8];
      *(uint4*)&Vs[r][ch * 8] = *(const uint4*)&Vg[(size_t)r * N + k0 + ch * 8];
    }
    __syncthreads();

    f32x4 s[4] = {};
#pragma unroll
    for (int ni = 0; ni < 4; ++ni) {
      bf16x8 kf0 = *(const bf16x8*)&Ks[ni * 16 + l15][quad * 8];
      bf16x8 kf1 = *(const bf16x8*)&Ks[ni * 16 + l15][quad * 8 + 32];
      s[ni] = __builtin_amdgcn_mfma_f32_16x16x32_bf16(qf0, kf0, s[ni], 0, 0, 0);
      s[ni] = __builtin_amdgcn_mfma_f32_16x16x32_bf16(qf1, kf1, s[ni], 0, 0, 0);
    }
    if (hasb) {
#pragma unroll
      for (int ni = 0; ni < 4; ++ni)
#pragma unroll
        for (int r = 0; r < 4; ++r) {
          int qq = qrow_w + quad * 4 + r;
          int kk = k0 + ni * 16 + l15;
          s[ni][r] = s[ni][r] * scale + bscale * Abias[((size_t)b * N + qq) * N + kk];
        }
    } else {
#pragma unroll
      for (int ni = 0; ni < 4; ++ni)
#pragma unroll
        for (int r = 0; r < 4; ++r) s[ni][r] *= scale;
    }

    float mt[4];
#pragma unroll
    for (int r = 0; r < 4; ++r)
      mt[r] = fmaxf(fmaxf(s[0][r], s[1][r]), fmaxf(s[2][r], s[3][r]));
#pragma unroll
    for (int off = 1; off < 16; off <<= 1)
#pragma unroll
      for (int r = 0; r < 4; ++r) mt[r] = fmaxf(mt[r], __shfl_xor(mt[r], off, 64));

    float alpha[4];
#pragma unroll
    for (int r = 0; r < 4; ++r) {
      float mn = fmaxf(m_i[r], mt[r]);
      alpha[r] = __expf(m_i[r] - mn);
      m_i[r] = mn;
    }
    float ls[4] = {0.f, 0.f, 0.f, 0.f};
#pragma unroll
    for (int ni = 0; ni < 4; ++ni)
#pragma unroll
      for (int r = 0; r < 4; ++r) {
        float p = __expf(s[ni][r] - m_i[r]);
        s[ni][r] = p;
        ls[r] += p;
      }
#pragma unroll
    for (int off = 1; off < 16; off <<= 1)
#pragma unroll
      for (int r = 0; r < 4; ++r) ls[r] += __shfl_xor(ls[r], off, 64);
#pragma unroll
    for (int r = 0; r < 4; ++r) l_i[r] = l_i[r] * alpha[r] + ls[r];
#pragma unroll
    for (int ni = 0; ni < 4; ++ni)
#pragma unroll
      for (int r = 0; r < 4; ++r) oacc[ni][r] *= alpha[r];

#pragma unroll
    for (int ni = 0; ni < 4; ++ni)
#pragma unroll
      for (int r = 0; r < 4; ++r)
        Ps[wave][quad * 4 + r][ni * 16 + l15] = bf16s(s[ni][r]);

    bf16x8 pf0 = *(const bf16x8*)&Ps[wave][l15][quad * 8];
    bf16x8 pf1 = *(const bf16x8*)&Ps[wave][l15][quad * 8 + 32];
#pragma unroll
    for (int ni = 0; ni < 4; ++ni) {
      bf16x8 vf0 = *(const bf16x8*)&Vs[ni * 16 + l15][quad * 8];
      bf16x8 vf1 = *(const bf16x8*)&Vs[ni * 16 + l15][quad * 8 + 32];
      oacc[ni] = __builtin_amdgcn_mfma_f32_16x16x32_bf16(pf0, vf0, oacc[ni], 0, 0, 0);
      oacc[ni] = __builtin_amdgcn_mfma_f32_16x16x32_bf16(pf1, vf1, oacc[ni], 0, 0, 0);
    }
  }

  float inv[4];
#pragma unroll
  for (int r = 0; r < 4; ++r) inv[r] = 1.f / l_i[r];
#pragma unroll
  for (int ni = 0; ni < 4; ++ni)
#pragma unroll
    for (int r = 0; r < 4; ++r) {
      int nn = qrow_w + quad * 4 + r;
      int col = h * 64 + ni * 16 + l15;
      O[((size_t)b * N + nn) * 512 + col] = __float2bfloat16(oacc[ni][r] * inv[r]);
    }
}

// ---------- decoder: 64x64 tiles, 36 triu pairs x 16 batches ----------
__global__ __launch_bounds__(256) void dec_mfma_kernel(
    const __hip_bfloat16* __restrict__ Tb_, const __hip_bfloat16* __restrict__ Hb_,
    const float* __restrict__ dec_b, float* __restrict__ out) {
  const int Nn = 512, K = 512;
  __shared__ __align__(16) short As[64 * 64];
  __shared__ __align__(16) short Bs[64 * 64];
  int p = blockIdx.x;  // 0..35
  int bb = blockIdx.y;
  int it = 0, rem = p;
  while (rem >= 8 - it) { rem -= 8 - it; ++it; }
  int jt = it + rem;
  const int row0 = it * 64, col0 = jt * 64;
  const int tid = threadIdx.x;
  const int lane = tid & 63, wave = tid >> 6;
  const int quad = lane >> 4, l15 = lane & 15;
  const int wr = (wave >> 1) * 32, wc = (wave & 1) * 32;
  const short* Ag = (const short*)(Tb_ + (size_t)bb * Nn * K);
  const short* Bg = (const short*)(Hb_ + (size_t)bb * Nn * K);
  f32x4 acc[2][2] = {};

  for (int k0 = 0; k0 < K; k0 += 64) {
    __syncthreads();
#pragma unroll
    for (int i = 0; i < 2; ++i) {
      int c = (wave * 2 + i) * 64 + lane;
      int r = c >> 3, pp = c & 7;
      int kc = pp ^ (r & 7);
      async16(&As[(wave * 2 + i) * 512], &Ag[(size_t)(row0 + r) * K + k0 + kc * 8]);
      async16(&Bs[(wave * 2 + i) * 512], &Bg[(size_t)(col0 + r) * K + k0 + kc * 8]);
    }
    __syncthreads();
#pragma unroll
    for (int kh = 0; kh < 2; ++kh) {
      const int sw = l15 & 7;
      const int ch = ((quad + kh * 4) ^ sw) * 8;
      bf16x8 af[2], bq[2];
#pragma unroll
      for (int mi = 0; mi < 2; ++mi)
        af[mi] = *(const bf16x8*)&As[(wr + mi * 16 + l15) * 64 + ch];
#pragma unroll
      for (int ni = 0; ni < 2; ++ni)
        bq[ni] = *(const bf16x8*)&Bs[(wc + ni * 16 + l15) * 64 + ch];
#pragma unroll
      for (int mi = 0; mi < 2; ++mi)
#pragma unroll
        for (int ni = 0; ni < 2; ++ni)
          acc[mi][ni] = __builtin_amdgcn_mfma_f32_16x16x32_bf16(af[mi], bq[ni], acc[mi][ni], 0, 0, 0);
    }
  }

  float db = dec_b[0];
  size_t obase = (size_t)bb * ((size_t)Nn * (Nn - 1) / 2);
#pragma unroll
  for (int mi = 0; mi < 2; ++mi) {
#pragma unroll
    for (int ni = 0; ni < 2; ++ni) {
      int j = col0 + wc + ni * 16 + l15;
#pragma unroll
      for (int r = 0; r < 4; ++r) {
        int i = row0 + wr + mi * 16 + quad * 4 + r;
        if (j > i) {
          float x = acc[mi][ni][r] + db;
          float sp = fmaxf(x, 0.f) + __logf(1.f + __expf(-fabsf(x)));
          out[obase + (size_t)i * (2 * Nn - i - 1) / 2 + (j - i - 1)] = sp;
        }
      }
    }
  }
}

// ---------- LayerNorm ----------
__global__ __launch_bounds__(256) void ln_kernel(
    const float* __restrict__ X, float* __restrict__ outf,
    __hip_bfloat16* __restrict__ outb, const float* __restrict__ g,
    const float* __restrict__ b, int D, int do_gelu) {
  __shared__ float red[4];
  int row = blockIdx.x;
  const float* x = X + (size_t)row * D;
  float s = 0.f, s2 = 0.f;
  for (int d = threadIdx.x; d < D; d += 256) {
    float v = x[d];
    s += v;
    s2 += v * v;
  }
  s = block_reduce(s, true, red);
  s2 = block_reduce(s2, true, red);
  float mean = s / D;
  float var = s2 / D - mean * mean;
  float inv = rsqrtf(var + 1e-5f);
  for (int d = threadIdx.x; d < D; d += 256) {
    float v = (x[d] - mean) * inv * g[d] + b[d];
    if (do_gelu) v = gelu_f(v);
    if (outf) outf[(size_t)row * D + d] = v;
    if (outb) outb[(size_t)row * D + d] = __float2bfloat16(v);
  }
}

// ---------- batched transpose ----------
template <typename T>
__global__ __launch_bounds__(256) void transpose_kernel(
    const T* __restrict__ X, T* __restrict__ Y, int R, int C) {
  __shared__ T t[32][33];
  const T* xb = X + (size_t)blockIdx.z * R * C;
  T* yb = Y + (size_t)blockIdx.z * R * C;
  int c0 = blockIdx.x * 32, r0 = blockIdx.y * 32;
  int tx = threadIdx.x & 31, ty = threadIdx.x >> 5;
  for (int i = ty; i < 32; i += 8) t[i][tx] = xb[(size_t)(r0 + i) * C + c0 + tx];
  __syncthreads();
  for (int i = ty; i < 32; i += 8) yb[(size_t)(c0 + i) * R + r0 + tx] = t[tx][i];
}

// ---------- host ----------
extern "C" void kernel_launch(void* const* d_in, const int* in_sizes, int n_in,
                              void* d_out, int out_size, void* d_ws, size_t ws_size,
                              hipStream_t stream) {
  const float *A_lr = (const float*)d_in[0], *X_lr = (const float*)d_in[1],
              *ip_W = (const float*)d_in[2], *ip_b = (const float*)d_in[3],
              *ip_g = (const float*)d_in[4], *ip_bt = (const float*)d_in[5],
              *e_n1g = (const float*)d_in[6], *e_n1b = (const float*)d_in[7],
              *e_qkvW = (const float*)d_in[8], *e_qkvb = (const float*)d_in[9],
              *e_projW = (const float*)d_in[10], *e_projb = (const float*)d_in[11],
              *e_ebW = (const float*)d_in[12], *e_ebs = (const float*)d_in[13],
              *e_n2g = (const float*)d_in[14], *e_n2b = (const float*)d_in[15],
              *e_f1W = (const float*)d_in[16], *e_f1b = (const float*)d_in[17],
              *e_f2W = (const float*)d_in[18], *e_f2b = (const float*)d_in[19],
              *encn_g = (const float*)d_in[20], *encn_b = (const float*)d_in[21],
              *up1W = (const float*)d_in[22], *up1b = (const float*)d_in[23],
              *up2W = (const float*)d_in[24], *up2b = (const float*)d_in[25],
              *r_n1g = (const float*)d_in[26], *r_n1b = (const float*)d_in[27],
              *r_qkvW = (const float*)d_in[28], *r_qkvb = (const float*)d_in[29],
              *r_projW = (const float*)d_in[30], *r_projb = (const float*)d_in[31],
              *r_n2g = (const float*)d_in[32], *r_n2b = (const float*)d_in[33],
              *r_f1W = (const float*)d_in[34], *r_f1b = (const float*)d_in[35],
              *r_f2W = (const float*)d_in[36], *r_f2b = (const float*)d_in[37],
              *hrn_g = (const float*)d_in[38], *hrn_b = (const float*)d_in[39],
              *dec_W = (const float*)d_in[40], *dec_b = (const float*)d_in[41];

  const int Bb = 16, NLR = 256, NHR = 512, Dm = 512, NHh = 8, FF = 2048, Ll = 4;
  typedef __hip_bfloat16 bf;

  float* ws = (float*)d_ws;
  float* H = ws;                                  // 4M fp32
  float* Hf = ws + 4194304;                       // 4M fp32
  bf* XNb = (bf*)(ws + 8388608);                  // 4M bf16
  bf* AOb = (bf*)(ws + 10485760);                 // 4M bf16 (Htb / Ttb / attn out)
  bf* BIGb = (bf*)(ws + 12582912);                // 16.78M bf16 (QKV slab / FFN hidden)
  bf* WB = (bf*)(ws + 20971520);                  // bf16 weights
  bf* Xlrb = (bf*)(ws + 29229056);                // 1.05M bf16

  size_t o = 0;
  bf* ipWt = WB + o;   o += (size_t)512 * 256;
  bf* eqkvT = WB + o;  o += (size_t)4 * 1536 * 512;
  bf* eprojT = WB + o; o += (size_t)4 * 512 * 512;
  bf* ef1T = WB + o;   o += (size_t)4 * 2048 * 512;
  bf* ef2T = WB + o;   o += (size_t)4 * 512 * 2048;
  bf* up1T = WB + o;   o += (size_t)512 * 256;
  bf* up2T = WB + o;   o += (size_t)512 * 512;
  bf* rqkvT = WB + o;  o += (size_t)1536 * 512;
  bf* rprojT = WB + o; o += (size_t)512 * 512;
  bf* rf1T = WB + o;   o += (size_t)2048 * 512;
  bf* rf2T = WB + o;   o += (size_t)512 * 2048;
  bf* Sb = WB + o;     o += (size_t)512 * 512;

  bf* Q_e = BIGb;
  bf* K_e = BIGb + 2097152;
  bf* V_e = BIGb + 4194304;
  bf* Q_r = BIGb;
  bf* K_r = BIGb + 4194304;
  bf* V_r = BIGb + 8388608;

  // ---- conversions ----
  tconv_kernel<<<dim3(16, 8, 1), 256, 0, stream>>>(ip_W, ipWt, 256, 512);
  tconv_kernel<<<dim3(48, 16, 4), 256, 0, stream>>>(e_qkvW, eqkvT, 512, 1536);
  tconv_kernel<<<dim3(16, 16, 4), 256, 0, stream>>>(e_projW, eprojT, 512, 512);
  tconv_kernel<<<dim3(64, 16, 4), 256, 0, stream>>>(e_f1W, ef1T, 512, 2048);
  tconv_kernel<<<dim3(16, 64, 4), 256, 0, stream>>>(e_f2W, ef2T, 2048, 512);
  tconv_kernel<<<dim3(16, 8, 1), 256, 0, stream>>>(up1W, up1T, 256, 512);
  tconv_kernel<<<dim3(16, 16, 1), 256, 0, stream>>>(up2W, up2T, 512, 512);
  tconv_kernel<<<dim3(48, 16, 1), 256, 0, stream>>>(r_qkvW, rqkvT, 512, 1536);
  tconv_kernel<<<dim3(16, 16, 1), 256, 0, stream>>>(r_projW, rprojT, 512, 512);
  tconv_kernel<<<dim3(64, 16, 1), 256, 0, stream>>>(r_f1W, rf1T, 512, 2048);
  tconv_kernel<<<dim3(16, 64, 1), 256, 0, stream>>>(r_f2W, rf2T, 2048, 512);
  conv_kernel<<<(1048576 + 255) / 256, 256, 0, stream>>>(X_lr, Xlrb, 1048576);
  build_s_kernel<<<(512 * 512 + 255) / 256, 256, 0, stream>>>(dec_W, Sb, Dm, 4);

  // ---- input projection ----  (grid = nb*mb 1D; mgrp = mb/8)
  mgemm_kernel<<<4 * 32, 256, 0, stream>>>(
      Xlrb, ipWt, ip_b, nullptr, Hf, nullptr, Bb * NLR, Dm, NLR, 0, 4);
  ln_kernel<<<Bb * NLR, 256, 0, stream>>>(Hf, H, nullptr, ip_g, ip_bt, Dm, 1);

  // ---- encoder ----
  for (int l = 0; l < Ll; ++l) {
    ln_kernel<<<Bb * NLR, 256, 0, stream>>>(H, nullptr, XNb, e_n1g + l * Dm, e_n1b + l * Dm, Dm, 0);
    qkv_gemm_kernel<<<12 * 32, 256, 0, stream>>>(
        XNb, eqkvT + (size_t)l * 1536 * 512, e_qkvb + l * 1536, BIGb,
        Bb * NLR, Dm, NLR, 8, 4);
    fattn_kernel<<<dim3(4, 8, 16), 256, 0, stream>>>(
        Q_e, K_e, V_e, AOb, A_lr, e_ebW + l * NHh, e_ebs + l, NLR);
    mgemm_kernel<<<4 * 32, 256, 0, stream>>>(
        AOb, eprojT + (size_t)l * 512 * 512, e_projb + l * Dm, H,
        H, nullptr, Bb * NLR, Dm, Dm, 0, 4);
    ln_kernel<<<Bb * NLR, 256, 0, stream>>>(H, nullptr, XNb, e_n2g + l * Dm, e_n2b + l * Dm, Dm, 0);
    mgemm_kernel<<<16 * 32, 256, 0, stream>>>(
        XNb, ef1T + (size_t)l * 2048 * 512, e_f1b + l * FF, nullptr,
        nullptr, BIGb, Bb * NLR, FF, Dm, 1, 4);
    mgemm_kernel<<<4 * 32, 256, 0, stream>>>(
        BIGb, ef2T + (size_t)l * 512 * 2048, e_f2b + l * Dm, H,
        H, nullptr, Bb * NLR, Dm, FF, 0, 4);
  }

  // ---- upsampler ----
  ln_kernel<<<Bb * NLR, 256, 0, stream>>>(H, nullptr, XNb, encn_g, encn_b, Dm, 0);
  transpose_kernel<bf><<<dim3(16, 8, Bb), 256, 0, stream>>>(XNb, AOb, NLR, Dm);
  mgemm_kernel<<<4 * 64, 256, 0, stream>>>(
      AOb, up1T, up1b, nullptr, nullptr, BIGb, Bb * Dm, NHR, NLR, 1, 8);
  mgemm_kernel<<<4 * 64, 256, 0, stream>>>(
      BIGb, up2T, up2b, nullptr, Hf, nullptr, Bb * Dm, NHR, NHR, 0, 8);
  transpose_kernel<float><<<dim3(16, 16, Bb), 256, 0, stream>>>(Hf, H, Dm, NHR);

  // ---- refiner ----
  ln_kernel<<<Bb * NHR, 256, 0, stream>>>(H, nullptr, XNb, r_n1g, r_n1b, Dm, 0);
  qkv_gemm_kernel<<<12 * 64, 256, 0, stream>>>(
      XNb, rqkvT, r_qkvb, BIGb, Bb * NHR, Dm, NHR, 9, 8);
  fattn_kernel<<<dim3(8, 8, 16), 256, 0, stream>>>(
      Q_r, K_r, V_r, AOb, nullptr, nullptr, nullptr, NHR);
  mgemm_kernel<<<4 * 64, 256, 0, stream>>>(
      AOb, rprojT, r_projb, H, H, nullptr, Bb * NHR, Dm, Dm, 0, 8);
  ln_kernel<<<Bb * NHR, 256, 0, stream>>>(H, nullptr, XNb, r_n2g, r_n2b, Dm, 0);
  mgemm_kernel<<<16 * 64, 256, 0, stream>>>(
      XNb, rf1T, r_f1b, nullptr, nullptr, BIGb, Bb * NHR, FF, Dm, 1, 8);
  mgemm_kernel<<<4 * 64, 256, 0, stream>>>(
      BIGb, rf2T, r_f2b, H, H, nullptr, Bb * NHR, Dm, FF, 0, 8);

  // ---- decoder ----
  ln_kernel<<<Bb * NHR, 256, 0, stream>>>(H, nullptr, XNb, hrn_g, hrn_b, Dm, 0);
  mgemm_kernel<<<4 * 64, 256, 0, stream>>>(
      XNb, Sb, nullptr, nullptr, nullptr, AOb, Bb * NHR, Dm, Dm, 0, 8);
  dec_mfma_kernel<<<dim3(36, Bb), 256, 0, stream>>>(
      AOb, XNb, dec_b, (float*)d_out);
}

// Round 8
// 911.396 us; speedup vs baseline: 7.0485x; 1.3271x over previous
//
#include <hip/hip_runtime.h>
#include <hip/hip_bf16.h>
#include <math.h>

#define DEV __device__ __forceinline__

typedef __attribute__((ext_vector_type(8))) short bf16x8;
typedef __attribute__((ext_vector_type(4))) float f32x4;

DEV float gelu_f(float x) { return 0.5f * x * (1.0f + erff(x * 0.70710678118654752f)); }

DEV float block_reduce(float v, bool is_sum, float* red) {
#pragma unroll
  for (int off = 32; off > 0; off >>= 1) {
    float o = __shfl_down(v, off, 64);
    v = is_sum ? (v + o) : fmaxf(v, o);
  }
  __syncthreads();
  if ((threadIdx.x & 63) == 0) red[threadIdx.x >> 6] = v;
  __syncthreads();
  return is_sum ? (red[0] + red[1] + red[2] + red[3])
                : fmaxf(fmaxf(red[0], red[1]), fmaxf(red[2], red[3]));
}

DEV short bf16s(float x) {
  __hip_bfloat16 v = __float2bfloat16(x);
  return *reinterpret_cast<short*>(&v);
}

// async 16B global->LDS (gfx950). dest = wave-uniform base + lane*16.
DEV void async16(void* lds, const void* g) {
  __builtin_amdgcn_global_load_lds(
      (const __attribute__((address_space(1))) unsigned int*)g,
      (__attribute__((address_space(3))) unsigned int*)lds, 16, 0, 0);
}

// ---------- conversion kernels ----------
__global__ __launch_bounds__(256) void conv_kernel(
    const float* __restrict__ X, __hip_bfloat16* __restrict__ Y, int n) {
  int i = blockIdx.x * 256 + threadIdx.x;
  if (i < n) Y[i] = __float2bfloat16(X[i]);
}

__global__ __launch_bounds__(256) void tconv_kernel(
    const float* __restrict__ X, __hip_bfloat16* __restrict__ Y, int R, int C) {
  __shared__ float t[32][33];
  const float* xb = X + (size_t)blockIdx.z * R * C;
  __hip_bfloat16* yb = Y + (size_t)blockIdx.z * R * C;
  int c0 = blockIdx.x * 32, r0 = blockIdx.y * 32;
  int tx = threadIdx.x & 31, ty = threadIdx.x >> 5;
  for (int i = ty; i < 32; i += 8) t[i][tx] = xb[(size_t)(r0 + i) * C + c0 + tx];
  __syncthreads();
  for (int i = ty; i < 32; i += 8)
    yb[(size_t)(c0 + i) * R + r0 + tx] = __float2bfloat16(t[tx][i]);
}

__global__ __launch_bounds__(256) void build_s_kernel(
    const float* __restrict__ W, __hip_bfloat16* __restrict__ S, int D, int Kk) {
  int i = blockIdx.x * 256 + threadIdx.x;
  if (i >= D * D) return;
  int d = i / D, e = i % D;
  float s = 0.f;
  for (int k = 0; k < Kk; ++k) {
    s += W[(size_t)k * D * D + i];
    s += W[(size_t)k * D * D + (size_t)e * D + d];
  }
  S[i] = __float2bfloat16(s / (2.0f * Kk));
}

// ---------- MFMA GEMM: 64x64 tile, swizzled LDS, async staging, XCD-local ----------
// 1D grid = (M/64)*(N/64); XCD g = bid&7 owns m-tiles [g*mgrp,(g+1)*mgrp), m fastest.
// 4 waves; wave w computes rows [w*16, w*16+16) x all 64 cols.
__global__ __launch_bounds__(256) void mgemm_kernel(
    const __hip_bfloat16* __restrict__ A, const __hip_bfloat16* __restrict__ Bt,
    const float* __restrict__ bias, const float* __restrict__ resid,
    float* __restrict__ outf, __hip_bfloat16* __restrict__ outb,
    int M, int N, int K, int act, int mgrp) {
  __shared__ __align__(16) short As[64 * 64];
  __shared__ __align__(16) short Bs[64 * 64];
  const int tid = threadIdx.x;
  const int lane = tid & 63, wave = tid >> 6;
  const int quad = lane >> 4, l15 = lane & 15;
  const int bid = blockIdx.x;
  const int g = bid & 7, sidx = bid >> 3;
  const int mt = g * mgrp + sidx % mgrp;
  const int nt = sidx / mgrp;
  const int row0 = mt * 64, col0 = nt * 64;
  const short* Ag = (const short*)A;
  const short* Bg = (const short*)Bt;
  f32x4 acc[4] = {};

  for (int k0 = 0; k0 < K; k0 += 64) {
    __syncthreads();
#pragma unroll
    for (int i = 0; i < 2; ++i) {
      int c = (wave * 2 + i) * 64 + lane;  // chunk 0..511
      int r = c >> 3, pp = c & 7;
      int kc = pp ^ (r & 7);
      async16(&As[(wave * 2 + i) * 512], &Ag[(size_t)(row0 + r) * K + k0 + kc * 8]);
      async16(&Bs[(wave * 2 + i) * 512], &Bg[(size_t)(col0 + r) * K + k0 + kc * 8]);
    }
    __syncthreads();
#pragma unroll
    for (int kh = 0; kh < 2; ++kh) {
      const int ch = ((quad + kh * 4) ^ (l15 & 7)) * 8;
      bf16x8 af = *(const bf16x8*)&As[(wave * 16 + l15) * 64 + ch];
#pragma unroll
      for (int ni = 0; ni < 4; ++ni) {
        bf16x8 bq = *(const bf16x8*)&Bs[(ni * 16 + l15) * 64 + ch];
        acc[ni] = __builtin_amdgcn_mfma_f32_16x16x32_bf16(af, bq, acc[ni], 0, 0, 0);
      }
    }
  }

#pragma unroll
  for (int ni = 0; ni < 4; ++ni) {
    int cc = col0 + ni * 16 + l15;
    float bb = bias ? bias[cc] : 0.f;
#pragma unroll
    for (int r = 0; r < 4; ++r) {
      int rr = row0 + wave * 16 + quad * 4 + r;
      size_t idx = (size_t)rr * N + cc;
      float v = acc[ni][r] + bb;
      if (act) v = gelu_f(v);
      if (resid) v += resid[idx];
      if (outf) outf[idx] = v;
      if (outb) outb[idx] = __float2bfloat16(v);
    }
  }
}

// ---------- QKV GEMM (64x64) with head-layout scatter epilogue ----------
__global__ __launch_bounds__(256) void qkv_gemm_kernel(
    const __hip_bfloat16* __restrict__ A, const __hip_bfloat16* __restrict__ Bt,
    const float* __restrict__ bias, __hip_bfloat16* __restrict__ qkv,
    int M, int K, int nseq, int lgn, int mgrp) {
  __shared__ __align__(16) short As[64 * 64];
  __shared__ __align__(16) short Bs[64 * 64];
  const int tid = threadIdx.x;
  const int lane = tid & 63, wave = tid >> 6;
  const int quad = lane >> 4, l15 = lane & 15;
  const int bid = blockIdx.x;
  const int g = bid & 7, sidx = bid >> 3;
  const int mt = g * mgrp + sidx % mgrp;
  const int nt = sidx / mgrp;
  const int row0 = mt * 64, col0 = nt * 64;
  const short* Ag = (const short*)A;
  const short* Bg = (const short*)Bt;
  f32x4 acc[4] = {};

  for (int k0 = 0; k0 < K; k0 += 64) {
    __syncthreads();
#pragma unroll
    for (int i = 0; i < 2; ++i) {
      int c = (wave * 2 + i) * 64 + lane;
      int r = c >> 3, pp = c & 7;
      int kc = pp ^ (r & 7);
      async16(&As[(wave * 2 + i) * 512], &Ag[(size_t)(row0 + r) * K + k0 + kc * 8]);
      async16(&Bs[(wave * 2 + i) * 512], &Bg[(size_t)(col0 + r) * K + k0 + kc * 8]);
    }
    __syncthreads();
#pragma unroll
    for (int kh = 0; kh < 2; ++kh) {
      const int ch = ((quad + kh * 4) ^ (l15 & 7)) * 8;
      bf16x8 af = *(const bf16x8*)&As[(wave * 16 + l15) * 64 + ch];
#pragma unroll
      for (int ni = 0; ni < 4; ++ni) {
        bf16x8 bq = *(const bf16x8*)&Bs[(ni * 16 + l15) * 64 + ch];
        acc[ni] = __builtin_amdgcn_mfma_f32_16x16x32_bf16(af, bq, acc[ni], 0, 0, 0);
      }
    }
  }

  const size_t PART = (size_t)M * 512;
#pragma unroll
  for (int ni = 0; ni < 4; ++ni) {
    int cc = col0 + ni * 16 + l15;  // 0..1535
    float bb = bias ? bias[cc] : 0.f;
    int which = cc >> 9;
    int h = (cc >> 6) & 7;
    int d = cc & 63;
#pragma unroll
    for (int r = 0; r < 4; ++r) {
      int rr = row0 + wave * 16 + quad * 4 + r;
      int b = rr >> lgn;
      int nn = rr & (nseq - 1);
      float v = acc[ni][r] + bb;
      size_t dst;
      if (which == 2) {
        dst = 2 * PART + (((size_t)b * 8 + h) * 64 + d) * nseq + nn;
      } else {
        dst = (size_t)which * PART + (((size_t)b * 8 + h) * nseq + nn) * 64 + d;
      }
      qkv[dst] = __float2bfloat16(v);
    }
  }
}

// ---------- fused flash attention (MFMA) ----------
__global__ __launch_bounds__(256) void fattn_kernel(
    const __hip_bfloat16* __restrict__ Qh, const __hip_bfloat16* __restrict__ Kh,
    const __hip_bfloat16* __restrict__ Vt, __hip_bfloat16* __restrict__ O,
    const float* __restrict__ Abias, const float* __restrict__ ebW,
    const float* __restrict__ ebs, int N) {
  __shared__ __align__(16) short Ks[64][72];
  __shared__ __align__(16) short Vs[64][72];
  __shared__ __align__(16) short Ps[4][16][72];
  const int qt = blockIdx.x, h = blockIdx.y, b = blockIdx.z;
  const int tid = threadIdx.x, lane = tid & 63, wave = tid >> 6;
  const int quad = lane >> 4, l15 = lane & 15;
  const size_t hb = (size_t)b * 8 + h;
  const short* Qg = (const short*)Qh + hb * N * 64;
  const short* Kg = (const short*)Kh + hb * N * 64;
  const short* Vg = (const short*)Vt + hb * 64 * N;
  const float scale = 0.125f;
  const bool hasb = (Abias != nullptr);
  const float bscale = hasb ? ebs[0] * ebW[h] : 0.f;
  const int qrow_w = qt * 64 + wave * 16;

  bf16x8 qf0 = *(const bf16x8*)&Qg[(size_t)(qrow_w + l15) * 64 + quad * 8];
  bf16x8 qf1 = *(const bf16x8*)&Qg[(size_t)(qrow_w + l15) * 64 + quad * 8 + 32];

  float m_i[4], l_i[4];
  f32x4 oacc[4] = {};
#pragma unroll
  for (int r = 0; r < 4; ++r) { m_i[r] = -1e30f; l_i[r] = 0.f; }

  for (int k0 = 0; k0 < N; k0 += 64) {
    __syncthreads();
#pragma unroll
    for (int i = 0; i < 2; ++i) {
      int idx = i * 256 + tid;
      int r = idx >> 3, ch = idx & 7;
      *(uint4*)&Ks[r][ch * 8] = *(const uint4*)&Kg[(size_t)(k0 + r) * 64 + ch * 8];
      *(uint4*)&Vs[r][ch * 8] = *(const uint4*)&Vg[(size_t)r * N + k0 + ch * 8];
    }
    __syncthreads();

    f32x4 s[4] = {};
#pragma unroll
    for (int ni = 0; ni < 4; ++ni) {
      bf16x8 kf0 = *(const bf16x8*)&Ks[ni * 16 + l15][quad * 8];
      bf16x8 kf1 = *(const bf16x8*)&Ks[ni * 16 + l15][quad * 8 + 32];
      s[ni] = __builtin_amdgcn_mfma_f32_16x16x32_bf16(qf0, kf0, s[ni], 0, 0, 0);
      s[ni] = __builtin_amdgcn_mfma_f32_16x16x32_bf16(qf1, kf1, s[ni], 0, 0, 0);
    }
    if (hasb) {
#pragma unroll
      for (int ni = 0; ni < 4; ++ni)
#pragma unroll
        for (int r = 0; r < 4; ++r) {
          int qq = qrow_w + quad * 4 + r;
          int kk = k0 + ni * 16 + l15;
          s[ni][r] = s[ni][r] * scale + bscale * Abias[((size_t)b * N + qq) * N + kk];
        }
    } else {
#pragma unroll
      for (int ni = 0; ni < 4; ++ni)
#pragma unroll
        for (int r = 0; r < 4; ++r) s[ni][r] *= scale;
    }

    float mt[4];
#pragma unroll
    for (int r = 0; r < 4; ++r)
      mt[r] = fmaxf(fmaxf(s[0][r], s[1][r]), fmaxf(s[2][r], s[3][r]));
#pragma unroll
    for (int off = 1; off < 16; off <<= 1)
#pragma unroll
      for (int r = 0; r < 4; ++r) mt[r] = fmaxf(mt[r], __shfl_xor(mt[r], off, 64));

    float alpha[4];
#pragma unroll
    for (int r = 0; r < 4; ++r) {
      float mn = fmaxf(m_i[r], mt[r]);
      alpha[r] = __expf(m_i[r] - mn);
      m_i[r] = mn;
    }
    float ls[4] = {0.f, 0.f, 0.f, 0.f};
#pragma unroll
    for (int ni = 0; ni < 4; ++ni)
#pragma unroll
      for (int r = 0; r < 4; ++r) {
        float p = __expf(s[ni][r] - m_i[r]);
        s[ni][r] = p;
        ls[r] += p;
      }
#pragma unroll
    for (int off = 1; off < 16; off <<= 1)
#pragma unroll
      for (int r = 0; r < 4; ++r) ls[r] += __shfl_xor(ls[r], off, 64);
#pragma unroll
    for (int r = 0; r < 4; ++r) l_i[r] = l_i[r] * alpha[r] + ls[r];
#pragma unroll
    for (int ni = 0; ni < 4; ++ni)
#pragma unroll
      for (int r = 0; r < 4; ++r) oacc[ni][r] *= alpha[r];

#pragma unroll
    for (int ni = 0; ni < 4; ++ni)
#pragma unroll
      for (int r = 0; r < 4; ++r)
        Ps[wave][quad * 4 + r][ni * 16 + l15] = bf16s(s[ni][r]);

    bf16x8 pf0 = *(const bf16x8*)&Ps[wave][l15][quad * 8];
    bf16x8 pf1 = *(const bf16x8*)&Ps[wave][l15][quad * 8 + 32];
#pragma unroll
    for (int ni = 0; ni < 4; ++ni) {
      bf16x8 vf0 = *(const bf16x8*)&Vs[ni * 16 + l15][quad * 8];
      bf16x8 vf1 = *(const bf16x8*)&Vs[ni * 16 + l15][quad * 8 + 32];
      oacc[ni] = __builtin_amdgcn_mfma_f32_16x16x32_bf16(pf0, vf0, oacc[ni], 0, 0, 0);
      oacc[ni] = __builtin_amdgcn_mfma_f32_16x16x32_bf16(pf1, vf1, oacc[ni], 0, 0, 0);
    }
  }

  float inv[4];
#pragma unroll
  for (int r = 0; r < 4; ++r) inv[r] = 1.f / l_i[r];
#pragma unroll
  for (int ni = 0; ni < 4; ++ni)
#pragma unroll
    for (int r = 0; r < 4; ++r) {
      int nn = qrow_w + quad * 4 + r;
      int col = h * 64 + ni * 16 + l15;
      O[((size_t)b * N + nn) * 512 + col] = __float2bfloat16(oacc[ni][r] * inv[r]);
    }
}

// ---------- decoder: 64x64 tiles, 36 triu pairs x 16 batches ----------
__global__ __launch_bounds__(256) void dec_mfma_kernel(
    const __hip_bfloat16* __restrict__ Tb_, const __hip_bfloat16* __restrict__ Hb_,
    const float* __restrict__ dec_b, float* __restrict__ out) {
  const int Nn = 512, K = 512;
  __shared__ __align__(16) short As[64 * 64];
  __shared__ __align__(16) short Bs[64 * 64];
  int p = blockIdx.x;  // 0..35
  int bb = blockIdx.y;
  int it = 0, rem = p;
  while (rem >= 8 - it) { rem -= 8 - it; ++it; }
  int jt = it + rem;
  const int row0 = it * 64, col0 = jt * 64;
  const int tid = threadIdx.x;
  const int lane = tid & 63, wave = tid >> 6;
  const int quad = lane >> 4, l15 = lane & 15;
  const int wr = (wave >> 1) * 32, wc = (wave & 1) * 32;
  const short* Ag = (const short*)(Tb_ + (size_t)bb * Nn * K);
  const short* Bg = (const short*)(Hb_ + (size_t)bb * Nn * K);
  f32x4 acc[2][2] = {};

  for (int k0 = 0; k0 < K; k0 += 64) {
    __syncthreads();
#pragma unroll
    for (int i = 0; i < 2; ++i) {
      int c = (wave * 2 + i) * 64 + lane;
      int r = c >> 3, pp = c & 7;
      int kc = pp ^ (r & 7);
      async16(&As[(wave * 2 + i) * 512], &Ag[(size_t)(row0 + r) * K + k0 + kc * 8]);
      async16(&Bs[(wave * 2 + i) * 512], &Bg[(size_t)(col0 + r) * K + k0 + kc * 8]);
    }
    __syncthreads();
#pragma unroll
    for (int kh = 0; kh < 2; ++kh) {
      const int ch = ((quad + kh * 4) ^ (l15 & 7)) * 8;
      bf16x8 af[2], bq[2];
#pragma unroll
      for (int mi = 0; mi < 2; ++mi)
        af[mi] = *(const bf16x8*)&As[(wr + mi * 16 + l15) * 64 + ch];
#pragma unroll
      for (int ni = 0; ni < 2; ++ni)
        bq[ni] = *(const bf16x8*)&Bs[(wc + ni * 16 + l15) * 64 + ch];
#pragma unroll
      for (int mi = 0; mi < 2; ++mi)
#pragma unroll
        for (int ni = 0; ni < 2; ++ni)
          acc[mi][ni] = __builtin_amdgcn_mfma_f32_16x16x32_bf16(af[mi], bq[ni], acc[mi][ni], 0, 0, 0);
    }
  }

  float db = dec_b[0];
  size_t obase = (size_t)bb * ((size_t)Nn * (Nn - 1) / 2);
#pragma unroll
  for (int mi = 0; mi < 2; ++mi) {
#pragma unroll
    for (int ni = 0; ni < 2; ++ni) {
      int j = col0 + wc + ni * 16 + l15;
#pragma unroll
      for (int r = 0; r < 4; ++r) {
        int i = row0 + wr + mi * 16 + quad * 4 + r;
        if (j > i) {
          float x = acc[mi][ni][r] + db;
          float sp = fmaxf(x, 0.f) + __logf(1.f + __expf(-fabsf(x)));
          out[obase + (size_t)i * (2 * Nn - i - 1) / 2 + (j - i - 1)] = sp;
        }
      }
    }
  }
}

// ---------- LayerNorm ----------
__global__ __launch_bounds__(256) void ln_kernel(
    const float* __restrict__ X, float* __restrict__ outf,
    __hip_bfloat16* __restrict__ outb, const float* __restrict__ g,
    const float* __restrict__ b, int D, int do_gelu) {
  __shared__ float red[4];
  int row = blockIdx.x;
  const float* x = X + (size_t)row * D;
  float s = 0.f, s2 = 0.f;
  for (int d = threadIdx.x; d < D; d += 256) {
    float v = x[d];
    s += v;
    s2 += v * v;
  }
  s = block_reduce(s, true, red);
  s2 = block_reduce(s2, true, red);
  float mean = s / D;
  float var = s2 / D - mean * mean;
  float inv = rsqrtf(var + 1e-5f);
  for (int d = threadIdx.x; d < D; d += 256) {
    float v = (x[d] - mean) * inv * g[d] + b[d];
    if (do_gelu) v = gelu_f(v);
    if (outf) outf[(size_t)row * D + d] = v;
    if (outb) outb[(size_t)row * D + d] = __float2bfloat16(v);
  }
}

// ---------- batched transpose ----------
template <typename T>
__global__ __launch_bounds__(256) void transpose_kernel(
    const T* __restrict__ X, T* __restrict__ Y, int R, int C) {
  __shared__ T t[32][33];
  const T* xb = X + (size_t)blockIdx.z * R * C;
  T* yb = Y + (size_t)blockIdx.z * R * C;
  int c0 = blockIdx.x * 32, r0 = blockIdx.y * 32;
  int tx = threadIdx.x & 31, ty = threadIdx.x >> 5;
  for (int i = ty; i < 32; i += 8) t[i][tx] = xb[(size_t)(r0 + i) * C + c0 + tx];
  __syncthreads();
  for (int i = ty; i < 32; i += 8) yb[(size_t)(c0 + i) * R + r0 + tx] = t[tx][i];
}

// ---------- host ----------
extern "C" void kernel_launch(void* const* d_in, const int* in_sizes, int n_in,
                              void* d_out, int out_size, void* d_ws, size_t ws_size,
                              hipStream_t stream) {
  const float *A_lr = (const float*)d_in[0], *X_lr = (const float*)d_in[1],
              *ip_W = (const float*)d_in[2], *ip_b = (const float*)d_in[3],
              *ip_g = (const float*)d_in[4], *ip_bt = (const float*)d_in[5],
              *e_n1g = (const float*)d_in[6], *e_n1b = (const float*)d_in[7],
              *e_qkvW = (const float*)d_in[8], *e_qkvb = (const float*)d_in[9],
              *e_projW = (const float*)d_in[10], *e_projb = (const float*)d_in[11],
              *e_ebW = (const float*)d_in[12], *e_ebs = (const float*)d_in[13],
              *e_n2g = (const float*)d_in[14], *e_n2b = (const float*)d_in[15],
              *e_f1W = (const float*)d_in[16], *e_f1b = (const float*)d_in[17],
              *e_f2W = (const float*)d_in[18], *e_f2b = (const float*)d_in[19],
              *encn_g = (const float*)d_in[20], *encn_b = (const float*)d_in[21],
              *up1W = (const float*)d_in[22], *up1b = (const float*)d_in[23],
              *up2W = (const float*)d_in[24], *up2b = (const float*)d_in[25],
              *r_n1g = (const float*)d_in[26], *r_n1b = (const float*)d_in[27],
              *r_qkvW = (const float*)d_in[28], *r_qkvb = (const float*)d_in[29],
              *r_projW = (const float*)d_in[30], *r_projb = (const float*)d_in[31],
              *r_n2g = (const float*)d_in[32], *r_n2b = (const float*)d_in[33],
              *r_f1W = (const float*)d_in[34], *r_f1b = (const float*)d_in[35],
              *r_f2W = (const float*)d_in[36], *r_f2b = (const float*)d_in[37],
              *hrn_g = (const float*)d_in[38], *hrn_b = (const float*)d_in[39],
              *dec_W = (const float*)d_in[40], *dec_b = (const float*)d_in[41];

  const int Bb = 16, NLR = 256, NHR = 512, Dm = 512, NHh = 8, FF = 2048, Ll = 4;
  typedef __hip_bfloat16 bf;

  float* ws = (float*)d_ws;
  float* H = ws;                                  // 4M fp32
  float* Hf = ws + 4194304;                       // 4M fp32
  bf* XNb = (bf*)(ws + 8388608);                  // 4M bf16
  bf* AOb = (bf*)(ws + 10485760);                 // 4M bf16 (Htb / Ttb / attn out)
  bf* BIGb = (bf*)(ws + 12582912);                // 16.78M bf16 (QKV slab / FFN hidden)
  bf* WB = (bf*)(ws + 20971520);                  // bf16 weights
  bf* Xlrb = (bf*)(ws + 29229056);                // 1.05M bf16

  size_t o = 0;
  bf* ipWt = WB + o;   o += (size_t)512 * 256;
  bf* eqkvT = WB + o;  o += (size_t)4 * 1536 * 512;
  bf* eprojT = WB + o; o += (size_t)4 * 512 * 512;
  bf* ef1T = WB + o;   o += (size_t)4 * 2048 * 512;
  bf* ef2T = WB + o;   o += (size_t)4 * 512 * 2048;
  bf* up1T = WB + o;   o += (size_t)512 * 256;
  bf* up2T = WB + o;   o += (size_t)512 * 512;
  bf* rqkvT = WB + o;  o += (size_t)1536 * 512;
  bf* rprojT = WB + o; o += (size_t)512 * 512;
  bf* rf1T = WB + o;   o += (size_t)2048 * 512;
  bf* rf2T = WB + o;   o += (size_t)512 * 2048;
  bf* Sb = WB + o;     o += (size_t)512 * 512;

  bf* Q_e = BIGb;
  bf* K_e = BIGb + 2097152;
  bf* V_e = BIGb + 4194304;
  bf* Q_r = BIGb;
  bf* K_r = BIGb + 4194304;
  bf* V_r = BIGb + 8388608;

  // ---- conversions ----
  tconv_kernel<<<dim3(16, 8, 1), 256, 0, stream>>>(ip_W, ipWt, 256, 512);
  tconv_kernel<<<dim3(48, 16, 4), 256, 0, stream>>>(e_qkvW, eqkvT, 512, 1536);
  tconv_kernel<<<dim3(16, 16, 4), 256, 0, stream>>>(e_projW, eprojT, 512, 512);
  tconv_kernel<<<dim3(64, 16, 4), 256, 0, stream>>>(e_f1W, ef1T, 512, 2048);
  tconv_kernel<<<dim3(16, 64, 4), 256, 0, stream>>>(e_f2W, ef2T, 2048, 512);
  tconv_kernel<<<dim3(16, 8, 1), 256, 0, stream>>>(up1W, up1T, 256, 512);
  tconv_kernel<<<dim3(16, 16, 1), 256, 0, stream>>>(up2W, up2T, 512, 512);
  tconv_kernel<<<dim3(48, 16, 1), 256, 0, stream>>>(r_qkvW, rqkvT, 512, 1536);
  tconv_kernel<<<dim3(16, 16, 1), 256, 0, stream>>>(r_projW, rprojT, 512, 512);
  tconv_kernel<<<dim3(64, 16, 1), 256, 0, stream>>>(r_f1W, rf1T, 512, 2048);
  tconv_kernel<<<dim3(16, 64, 1), 256, 0, stream>>>(r_f2W, rf2T, 2048, 512);
  conv_kernel<<<(1048576 + 255) / 256, 256, 0, stream>>>(X_lr, Xlrb, 1048576);
  build_s_kernel<<<(512 * 512 + 255) / 256, 256, 0, stream>>>(dec_W, Sb, Dm, 4);

  // ---- input projection ----  (1D grid = (M/64)*(N/64); mgrp = (M/64)/8)
  mgemm_kernel<<<64 * 8, 256, 0, stream>>>(
      Xlrb, ipWt, ip_b, nullptr, Hf, nullptr, Bb * NLR, Dm, NLR, 0, 8);
  ln_kernel<<<Bb * NLR, 256, 0, stream>>>(Hf, H, nullptr, ip_g, ip_bt, Dm, 1);

  // ---- encoder ----  (M=4096: 64 m-tiles, mgrp=8)
  for (int l = 0; l < Ll; ++l) {
    ln_kernel<<<Bb * NLR, 256, 0, stream>>>(H, nullptr, XNb, e_n1g + l * Dm, e_n1b + l * Dm, Dm, 0);
    qkv_gemm_kernel<<<64 * 24, 256, 0, stream>>>(
        XNb, eqkvT + (size_t)l * 1536 * 512, e_qkvb + l * 1536, BIGb,
        Bb * NLR, Dm, NLR, 8, 8);
    fattn_kernel<<<dim3(4, 8, 16), 256, 0, stream>>>(
        Q_e, K_e, V_e, AOb, A_lr, e_ebW + l * NHh, e_ebs + l, NLR);
    mgemm_kernel<<<64 * 8, 256, 0, stream>>>(
        AOb, eprojT + (size_t)l * 512 * 512, e_projb + l * Dm, H,
        H, nullptr, Bb * NLR, Dm, Dm, 0, 8);
    ln_kernel<<<Bb * NLR, 256, 0, stream>>>(H, nullptr, XNb, e_n2g + l * Dm, e_n2b + l * Dm, Dm, 0);
    mgemm_kernel<<<64 * 32, 256, 0, stream>>>(
        XNb, ef1T + (size_t)l * 2048 * 512, e_f1b + l * FF, nullptr,
        nullptr, BIGb, Bb * NLR, FF, Dm, 1, 8);
    mgemm_kernel<<<64 * 8, 256, 0, stream>>>(
        BIGb, ef2T + (size_t)l * 512 * 2048, e_f2b + l * Dm, H,
        H, nullptr, Bb * NLR, Dm, FF, 0, 8);
  }

  // ---- upsampler ----  (M=8192: 128 m-tiles, mgrp=16)
  ln_kernel<<<Bb * NLR, 256, 0, stream>>>(H, nullptr, XNb, encn_g, encn_b, Dm, 0);
  transpose_kernel<bf><<<dim3(16, 8, Bb), 256, 0, stream>>>(XNb, AOb, NLR, Dm);
  mgemm_kernel<<<128 * 8, 256, 0, stream>>>(
      AOb, up1T, up1b, nullptr, nullptr, BIGb, Bb * Dm, NHR, NLR, 1, 16);
  mgemm_kernel<<<128 * 8, 256, 0, stream>>>(
      BIGb, up2T, up2b, nullptr, Hf, nullptr, Bb * Dm, NHR, NHR, 0, 16);
  transpose_kernel<float><<<dim3(16, 16, Bb), 256, 0, stream>>>(Hf, H, Dm, NHR);

  // ---- refiner ----  (M=8192: mgrp=16)
  ln_kernel<<<Bb * NHR, 256, 0, stream>>>(H, nullptr, XNb, r_n1g, r_n1b, Dm, 0);
  qkv_gemm_kernel<<<128 * 24, 256, 0, stream>>>(
      XNb, rqkvT, r_qkvb, BIGb, Bb * NHR, Dm, NHR, 9, 16);
  fattn_kernel<<<dim3(8, 8, 16), 256, 0, stream>>>(
      Q_r, K_r, V_r, AOb, nullptr, nullptr, nullptr, NHR);
  mgemm_kernel<<<128 * 8, 256, 0, stream>>>(
      AOb, rprojT, r_projb, H, H, nullptr, Bb * NHR, Dm, Dm, 0, 16);
  ln_kernel<<<Bb * NHR, 256, 0, stream>>>(H, nullptr, XNb, r_n2g, r_n2b, Dm, 0);
  mgemm_kernel<<<128 * 32, 256, 0, stream>>>(
      XNb, rf1T, r_f1b, nullptr, nullptr, BIGb, Bb * NHR, FF, Dm, 1, 16);
  mgemm_kernel<<<128 * 8, 256, 0, stream>>>(
      BIGb, rf2T, r_f2b, H, H, nullptr, Bb * NHR, Dm, FF, 0, 16);

  // ---- decoder ----
  ln_kernel<<<Bb * NHR, 256, 0, stream>>>(H, nullptr, XNb, hrn_g, hrn_b, Dm, 0);
  mgemm_kernel<<<128 * 8, 256, 0, stream>>>(
      XNb, Sb, nullptr, nullptr, nullptr, AOb, Bb * NHR, Dm, Dm, 0, 16);
  dec_mfma_kernel<<<dim3(36, Bb), 256, 0, stream>>>(
      AOb, XNb, dec_b, (float*)d_out);
}

// Round 9
// 911.054 us; speedup vs baseline: 7.0511x; 1.0004x over previous
//
#include <hip/hip_runtime.h>
#include <hip/hip_bf16.h>
#include <math.h>

#define DEV __device__ __forceinline__

typedef __attribute__((ext_vector_type(8))) short bf16x8;
typedef __attribute__((ext_vector_type(4))) float f32x4;

DEV float gelu_f(float x) { return 0.5f * x * (1.0f + erff(x * 0.70710678118654752f)); }

DEV float block_reduce(float v, bool is_sum, float* red) {
#pragma unroll
  for (int off = 32; off > 0; off >>= 1) {
    float o = __shfl_down(v, off, 64);
    v = is_sum ? (v + o) : fmaxf(v, o);
  }
  __syncthreads();
  if ((threadIdx.x & 63) == 0) red[threadIdx.x >> 6] = v;
  __syncthreads();
  return is_sum ? (red[0] + red[1] + red[2] + red[3])
                : fmaxf(fmaxf(red[0], red[1]), fmaxf(red[2], red[3]));
}

DEV short bf16s(float x) {
  __hip_bfloat16 v = __float2bfloat16(x);
  return *reinterpret_cast<short*>(&v);
}

// async 16B global->LDS (gfx950). dest = wave-uniform base + lane*16.
DEV void async16(void* lds, const void* g) {
  __builtin_amdgcn_global_load_lds(
      (const __attribute__((address_space(1))) unsigned int*)g,
      (__attribute__((address_space(3))) unsigned int*)lds, 16, 0, 0);
}

// ---------- conversion kernels ----------
__global__ __launch_bounds__(256) void conv_kernel(
    const float* __restrict__ X, __hip_bfloat16* __restrict__ Y, int n) {
  int i = blockIdx.x * 256 + threadIdx.x;
  if (i < n) Y[i] = __float2bfloat16(X[i]);
}

__global__ __launch_bounds__(256) void tconv_kernel(
    const float* __restrict__ X, __hip_bfloat16* __restrict__ Y, int R, int C) {
  __shared__ float t[32][33];
  const float* xb = X + (size_t)blockIdx.z * R * C;
  __hip_bfloat16* yb = Y + (size_t)blockIdx.z * R * C;
  int c0 = blockIdx.x * 32, r0 = blockIdx.y * 32;
  int tx = threadIdx.x & 31, ty = threadIdx.x >> 5;
  for (int i = ty; i < 32; i += 8) t[i][tx] = xb[(size_t)(r0 + i) * C + c0 + tx];
  __syncthreads();
  for (int i = ty; i < 32; i += 8)
    yb[(size_t)(c0 + i) * R + r0 + tx] = __float2bfloat16(t[tx][i]);
}

__global__ __launch_bounds__(256) void build_s_kernel(
    const float* __restrict__ W, __hip_bfloat16* __restrict__ S, int D, int Kk) {
  int i = blockIdx.x * 256 + threadIdx.x;
  if (i >= D * D) return;
  int d = i / D, e = i % D;
  float s = 0.f;
  for (int k = 0; k < Kk; ++k) {
    s += W[(size_t)k * D * D + i];
    s += W[(size_t)k * D * D + (size_t)e * D + d];
  }
  S[i] = __float2bfloat16(s / (2.0f * Kk));
}

// ---------- MFMA GEMM: 64x64 tile, swizzled LDS, async staging, XCD-local ----------
__global__ __launch_bounds__(256) void mgemm_kernel(
    const __hip_bfloat16* __restrict__ A, const __hip_bfloat16* __restrict__ Bt,
    const float* __restrict__ bias, const float* __restrict__ resid,
    float* __restrict__ outf, __hip_bfloat16* __restrict__ outb,
    int M, int N, int K, int act, int mgrp) {
  __shared__ __align__(16) short As[64 * 64];
  __shared__ __align__(16) short Bs[64 * 64];
  const int tid = threadIdx.x;
  const int lane = tid & 63, wave = tid >> 6;
  const int quad = lane >> 4, l15 = lane & 15;
  const int bid = blockIdx.x;
  const int g = bid & 7, sidx = bid >> 3;
  const int mt = g * mgrp + sidx % mgrp;
  const int nt = sidx / mgrp;
  const int row0 = mt * 64, col0 = nt * 64;
  const short* Ag = (const short*)A;
  const short* Bg = (const short*)Bt;
  f32x4 acc[4] = {};

  for (int k0 = 0; k0 < K; k0 += 64) {
    __syncthreads();
#pragma unroll
    for (int i = 0; i < 2; ++i) {
      int c = (wave * 2 + i) * 64 + lane;  // chunk 0..511
      int r = c >> 3, pp = c & 7;
      int kc = pp ^ (r & 7);
      async16(&As[(wave * 2 + i) * 512], &Ag[(size_t)(row0 + r) * K + k0 + kc * 8]);
      async16(&Bs[(wave * 2 + i) * 512], &Bg[(size_t)(col0 + r) * K + k0 + kc * 8]);
    }
    __syncthreads();
#pragma unroll
    for (int kh = 0; kh < 2; ++kh) {
      const int ch = ((quad + kh * 4) ^ (l15 & 7)) * 8;
      bf16x8 af = *(const bf16x8*)&As[(wave * 16 + l15) * 64 + ch];
#pragma unroll
      for (int ni = 0; ni < 4; ++ni) {
        bf16x8 bq = *(const bf16x8*)&Bs[(ni * 16 + l15) * 64 + ch];
        acc[ni] = __builtin_amdgcn_mfma_f32_16x16x32_bf16(af, bq, acc[ni], 0, 0, 0);
      }
    }
  }

#pragma unroll
  for (int ni = 0; ni < 4; ++ni) {
    int cc = col0 + ni * 16 + l15;
    float bb = bias ? bias[cc] : 0.f;
#pragma unroll
    for (int r = 0; r < 4; ++r) {
      int rr = row0 + wave * 16 + quad * 4 + r;
      size_t idx = (size_t)rr * N + cc;
      float v = acc[ni][r] + bb;
      if (act) v = gelu_f(v);
      if (resid) v += resid[idx];
      if (outf) outf[idx] = v;
      if (outb) outb[idx] = __float2bfloat16(v);
    }
  }
}

// ---------- QKV GEMM (64x64) with head-layout scatter epilogue ----------
__global__ __launch_bounds__(256) void qkv_gemm_kernel(
    const __hip_bfloat16* __restrict__ A, const __hip_bfloat16* __restrict__ Bt,
    const float* __restrict__ bias, __hip_bfloat16* __restrict__ qkv,
    int M, int K, int nseq, int lgn, int mgrp) {
  __shared__ __align__(16) short As[64 * 64];
  __shared__ __align__(16) short Bs[64 * 64];
  const int tid = threadIdx.x;
  const int lane = tid & 63, wave = tid >> 6;
  const int quad = lane >> 4, l15 = lane & 15;
  const int bid = blockIdx.x;
  const int g = bid & 7, sidx = bid >> 3;
  const int mt = g * mgrp + sidx % mgrp;
  const int nt = sidx / mgrp;
  const int row0 = mt * 64, col0 = nt * 64;
  const short* Ag = (const short*)A;
  const short* Bg = (const short*)Bt;
  f32x4 acc[4] = {};

  for (int k0 = 0; k0 < K; k0 += 64) {
    __syncthreads();
#pragma unroll
    for (int i = 0; i < 2; ++i) {
      int c = (wave * 2 + i) * 64 + lane;
      int r = c >> 3, pp = c & 7;
      int kc = pp ^ (r & 7);
      async16(&As[(wave * 2 + i) * 512], &Ag[(size_t)(row0 + r) * K + k0 + kc * 8]);
      async16(&Bs[(wave * 2 + i) * 512], &Bg[(size_t)(col0 + r) * K + k0 + kc * 8]);
    }
    __syncthreads();
#pragma unroll
    for (int kh = 0; kh < 2; ++kh) {
      const int ch = ((quad + kh * 4) ^ (l15 & 7)) * 8;
      bf16x8 af = *(const bf16x8*)&As[(wave * 16 + l15) * 64 + ch];
#pragma unroll
      for (int ni = 0; ni < 4; ++ni) {
        bf16x8 bq = *(const bf16x8*)&Bs[(ni * 16 + l15) * 64 + ch];
        acc[ni] = __builtin_amdgcn_mfma_f32_16x16x32_bf16(af, bq, acc[ni], 0, 0, 0);
      }
    }
  }

  const size_t PART = (size_t)M * 512;
#pragma unroll
  for (int ni = 0; ni < 4; ++ni) {
    int cc = col0 + ni * 16 + l15;  // 0..1535
    float bb = bias ? bias[cc] : 0.f;
    int which = cc >> 9;
    int h = (cc >> 6) & 7;
    int d = cc & 63;
#pragma unroll
    for (int r = 0; r < 4; ++r) {
      int rr = row0 + wave * 16 + quad * 4 + r;
      int b = rr >> lgn;
      int nn = rr & (nseq - 1);
      float v = acc[ni][r] + bb;
      size_t dst;
      if (which == 2) {
        dst = 2 * PART + (((size_t)b * 8 + h) * 64 + d) * nseq + nn;
      } else {
        dst = (size_t)which * PART + (((size_t)b * 8 + h) * nseq + nn) * 64 + d;
      }
      qkv[dst] = __float2bfloat16(v);
    }
  }
}

// ---------- fused flash attention (MFMA, XCD-local batches) ----------
// 1D grid = B*NH*(N/64). XCD g owns batches {2g, 2g+1}; all (h,qt) for one
// batch co-locate on one XCD so K/V/Abias re-reads hit that XCD's L2.
__global__ __launch_bounds__(256) void fattn_kernel(
    const __hip_bfloat16* __restrict__ Qh, const __hip_bfloat16* __restrict__ Kh,
    const __hip_bfloat16* __restrict__ Vt, __hip_bfloat16* __restrict__ O,
    const __hip_bfloat16* __restrict__ Abias, const float* __restrict__ ebW,
    const float* __restrict__ ebs, int N, int lgq) {
  __shared__ __align__(16) short Ks[64][72];
  __shared__ __align__(16) short Vs[64][72];
  __shared__ __align__(16) short Ps[4][16][72];
  const int bid = blockIdx.x;
  const int g = bid & 7, s = bid >> 3;
  const int bloc = s >> (lgq + 3);
  const int rem = s & ((8 << lgq) - 1);
  const int h = rem >> lgq;
  const int qt = rem & ((1 << lgq) - 1);
  const int b = g * 2 + bloc;
  const int tid = threadIdx.x, lane = tid & 63, wave = tid >> 6;
  const int quad = lane >> 4, l15 = lane & 15;
  const size_t hb = (size_t)b * 8 + h;
  const short* Qg = (const short*)Qh + hb * N * 64;
  const short* Kg = (const short*)Kh + hb * N * 64;
  const short* Vg = (const short*)Vt + hb * 64 * N;
  const float scale = 0.125f;
  const bool hasb = (Abias != nullptr);
  const float bscale = hasb ? ebs[0] * ebW[h] : 0.f;
  const int qrow_w = qt * 64 + wave * 16;

  bf16x8 qf0 = *(const bf16x8*)&Qg[(size_t)(qrow_w + l15) * 64 + quad * 8];
  bf16x8 qf1 = *(const bf16x8*)&Qg[(size_t)(qrow_w + l15) * 64 + quad * 8 + 32];

  float m_i[4], l_i[4];
  f32x4 oacc[4] = {};
#pragma unroll
  for (int r = 0; r < 4; ++r) { m_i[r] = -1e30f; l_i[r] = 0.f; }

  for (int k0 = 0; k0 < N; k0 += 64) {
    __syncthreads();
#pragma unroll
    for (int i = 0; i < 2; ++i) {
      int idx = i * 256 + tid;
      int r = idx >> 3, ch = idx & 7;
      *(uint4*)&Ks[r][ch * 8] = *(const uint4*)&Kg[(size_t)(k0 + r) * 64 + ch * 8];
      *(uint4*)&Vs[r][ch * 8] = *(const uint4*)&Vg[(size_t)r * N + k0 + ch * 8];
    }
    __syncthreads();

    f32x4 sv[4] = {};
#pragma unroll
    for (int ni = 0; ni < 4; ++ni) {
      bf16x8 kf0 = *(const bf16x8*)&Ks[ni * 16 + l15][quad * 8];
      bf16x8 kf1 = *(const bf16x8*)&Ks[ni * 16 + l15][quad * 8 + 32];
      sv[ni] = __builtin_amdgcn_mfma_f32_16x16x32_bf16(qf0, kf0, sv[ni], 0, 0, 0);
      sv[ni] = __builtin_amdgcn_mfma_f32_16x16x32_bf16(qf1, kf1, sv[ni], 0, 0, 0);
    }
    if (hasb) {
#pragma unroll
      for (int ni = 0; ni < 4; ++ni)
#pragma unroll
        for (int r = 0; r < 4; ++r) {
          int qq = qrow_w + quad * 4 + r;
          int kk = k0 + ni * 16 + l15;
          float ab = __bfloat162float(Abias[((size_t)b * N + qq) * N + kk]);
          sv[ni][r] = sv[ni][r] * scale + bscale * ab;
        }
    } else {
#pragma unroll
      for (int ni = 0; ni < 4; ++ni)
#pragma unroll
        for (int r = 0; r < 4; ++r) sv[ni][r] *= scale;
    }

    float mt[4];
#pragma unroll
    for (int r = 0; r < 4; ++r)
      mt[r] = fmaxf(fmaxf(sv[0][r], sv[1][r]), fmaxf(sv[2][r], sv[3][r]));
#pragma unroll
    for (int off = 1; off < 16; off <<= 1)
#pragma unroll
      for (int r = 0; r < 4; ++r) mt[r] = fmaxf(mt[r], __shfl_xor(mt[r], off, 64));

    float alpha[4];
#pragma unroll
    for (int r = 0; r < 4; ++r) {
      float mn = fmaxf(m_i[r], mt[r]);
      alpha[r] = __expf(m_i[r] - mn);
      m_i[r] = mn;
    }
    float ls[4] = {0.f, 0.f, 0.f, 0.f};
#pragma unroll
    for (int ni = 0; ni < 4; ++ni)
#pragma unroll
      for (int r = 0; r < 4; ++r) {
        float p = __expf(sv[ni][r] - m_i[r]);
        sv[ni][r] = p;
        ls[r] += p;
      }
#pragma unroll
    for (int off = 1; off < 16; off <<= 1)
#pragma unroll
      for (int r = 0; r < 4; ++r) ls[r] += __shfl_xor(ls[r], off, 64);
#pragma unroll
    for (int r = 0; r < 4; ++r) l_i[r] = l_i[r] * alpha[r] + ls[r];
#pragma unroll
    for (int ni = 0; ni < 4; ++ni)
#pragma unroll
      for (int r = 0; r < 4; ++r) oacc[ni][r] *= alpha[r];

#pragma unroll
    for (int ni = 0; ni < 4; ++ni)
#pragma unroll
      for (int r = 0; r < 4; ++r)
        Ps[wave][quad * 4 + r][ni * 16 + l15] = bf16s(sv[ni][r]);

    bf16x8 pf0 = *(const bf16x8*)&Ps[wave][l15][quad * 8];
    bf16x8 pf1 = *(const bf16x8*)&Ps[wave][l15][quad * 8 + 32];
#pragma unroll
    for (int ni = 0; ni < 4; ++ni) {
      bf16x8 vf0 = *(const bf16x8*)&Vs[ni * 16 + l15][quad * 8];
      bf16x8 vf1 = *(const bf16x8*)&Vs[ni * 16 + l15][quad * 8 + 32];
      oacc[ni] = __builtin_amdgcn_mfma_f32_16x16x32_bf16(pf0, vf0, oacc[ni], 0, 0, 0);
      oacc[ni] = __builtin_amdgcn_mfma_f32_16x16x32_bf16(pf1, vf1, oacc[ni], 0, 0, 0);
    }
  }

  float inv[4];
#pragma unroll
  for (int r = 0; r < 4; ++r) inv[r] = 1.f / l_i[r];
#pragma unroll
  for (int ni = 0; ni < 4; ++ni)
#pragma unroll
    for (int r = 0; r < 4; ++r) {
      int nn = qrow_w + quad * 4 + r;
      int col = h * 64 + ni * 16 + l15;
      O[((size_t)b * N + nn) * 512 + col] = __float2bfloat16(oacc[ni][r] * inv[r]);
    }
}

// ---------- decoder: 64x64 tiles, 36 triu pairs x 16 batches ----------
__global__ __launch_bounds__(256) void dec_mfma_kernel(
    const __hip_bfloat16* __restrict__ Tb_, const __hip_bfloat16* __restrict__ Hb_,
    const float* __restrict__ dec_b, float* __restrict__ out) {
  const int Nn = 512, K = 512;
  __shared__ __align__(16) short As[64 * 64];
  __shared__ __align__(16) short Bs[64 * 64];
  int p = blockIdx.x;  // 0..35
  int bb = blockIdx.y;
  int it = 0, rem = p;
  while (rem >= 8 - it) { rem -= 8 - it; ++it; }
  int jt = it + rem;
  const int row0 = it * 64, col0 = jt * 64;
  const int tid = threadIdx.x;
  const int lane = tid & 63, wave = tid >> 6;
  const int quad = lane >> 4, l15 = lane & 15;
  const int wr = (wave >> 1) * 32, wc = (wave & 1) * 32;
  const short* Ag = (const short*)(Tb_ + (size_t)bb * Nn * K);
  const short* Bg = (const short*)(Hb_ + (size_t)bb * Nn * K);
  f32x4 acc[2][2] = {};

  for (int k0 = 0; k0 < K; k0 += 64) {
    __syncthreads();
#pragma unroll
    for (int i = 0; i < 2; ++i) {
      int c = (wave * 2 + i) * 64 + lane;
      int r = c >> 3, pp = c & 7;
      int kc = pp ^ (r & 7);
      async16(&As[(wave * 2 + i) * 512], &Ag[(size_t)(row0 + r) * K + k0 + kc * 8]);
      async16(&Bs[(wave * 2 + i) * 512], &Bg[(size_t)(col0 + r) * K + k0 + kc * 8]);
    }
    __syncthreads();
#pragma unroll
    for (int kh = 0; kh < 2; ++kh) {
      const int ch = ((quad + kh * 4) ^ (l15 & 7)) * 8;
      bf16x8 af[2], bq[2];
#pragma unroll
      for (int mi = 0; mi < 2; ++mi)
        af[mi] = *(const bf16x8*)&As[(wr + mi * 16 + l15) * 64 + ch];
#pragma unroll
      for (int ni = 0; ni < 2; ++ni)
        bq[ni] = *(const bf16x8*)&Bs[(wc + ni * 16 + l15) * 64 + ch];
#pragma unroll
      for (int mi = 0; mi < 2; ++mi)
#pragma unroll
        for (int ni = 0; ni < 2; ++ni)
          acc[mi][ni] = __builtin_amdgcn_mfma_f32_16x16x32_bf16(af[mi], bq[ni], acc[mi][ni], 0, 0, 0);
    }
  }

  float db = dec_b[0];
  size_t obase = (size_t)bb * ((size_t)Nn * (Nn - 1) / 2);
#pragma unroll
  for (int mi = 0; mi < 2; ++mi) {
#pragma unroll
    for (int ni = 0; ni < 2; ++ni) {
      int j = col0 + wc + ni * 16 + l15;
#pragma unroll
      for (int r = 0; r < 4; ++r) {
        int i = row0 + wr + mi * 16 + quad * 4 + r;
        if (j > i) {
          float x = acc[mi][ni][r] + db;
          float sp = fmaxf(x, 0.f) + __logf(1.f + __expf(-fabsf(x)));
          out[obase + (size_t)i * (2 * Nn - i - 1) / 2 + (j - i - 1)] = sp;
        }
      }
    }
  }
}

// ---------- LayerNorm ----------
__global__ __launch_bounds__(256) void ln_kernel(
    const float* __restrict__ X, float* __restrict__ outf,
    __hip_bfloat16* __restrict__ outb, const float* __restrict__ g,
    const float* __restrict__ b, int D, int do_gelu) {
  __shared__ float red[4];
  int row = blockIdx.x;
  const float* x = X + (size_t)row * D;
  float s = 0.f, s2 = 0.f;
  for (int d = threadIdx.x; d < D; d += 256) {
    float v = x[d];
    s += v;
    s2 += v * v;
  }
  s = block_reduce(s, true, red);
  s2 = block_reduce(s2, true, red);
  float mean = s / D;
  float var = s2 / D - mean * mean;
  float inv = rsqrtf(var + 1e-5f);
  for (int d = threadIdx.x; d < D; d += 256) {
    float v = (x[d] - mean) * inv * g[d] + b[d];
    if (do_gelu) v = gelu_f(v);
    if (outf) outf[(size_t)row * D + d] = v;
    if (outb) outb[(size_t)row * D + d] = __float2bfloat16(v);
  }
}

// ---------- batched transpose ----------
template <typename T>
__global__ __launch_bounds__(256) void transpose_kernel(
    const T* __restrict__ X, T* __restrict__ Y, int R, int C) {
  __shared__ T t[32][33];
  const T* xb = X + (size_t)blockIdx.z * R * C;
  T* yb = Y + (size_t)blockIdx.z * R * C;
  int c0 = blockIdx.x * 32, r0 = blockIdx.y * 32;
  int tx = threadIdx.x & 31, ty = threadIdx.x >> 5;
  for (int i = ty; i < 32; i += 8) t[i][tx] = xb[(size_t)(r0 + i) * C + c0 + tx];
  __syncthreads();
  for (int i = ty; i < 32; i += 8) yb[(size_t)(c0 + i) * R + r0 + tx] = t[tx][i];
}

// ---------- host ----------
extern "C" void kernel_launch(void* const* d_in, const int* in_sizes, int n_in,
                              void* d_out, int out_size, void* d_ws, size_t ws_size,
                              hipStream_t stream) {
  const float *A_lr = (const float*)d_in[0], *X_lr = (const float*)d_in[1],
              *ip_W = (const float*)d_in[2], *ip_b = (const float*)d_in[3],
              *ip_g = (const float*)d_in[4], *ip_bt = (const float*)d_in[5],
              *e_n1g = (const float*)d_in[6], *e_n1b = (const float*)d_in[7],
              *e_qkvW = (const float*)d_in[8], *e_qkvb = (const float*)d_in[9],
              *e_projW = (const float*)d_in[10], *e_projb = (const float*)d_in[11],
              *e_ebW = (const float*)d_in[12], *e_ebs = (const float*)d_in[13],
              *e_n2g = (const float*)d_in[14], *e_n2b = (const float*)d_in[15],
              *e_f1W = (const float*)d_in[16], *e_f1b = (const float*)d_in[17],
              *e_f2W = (const float*)d_in[18], *e_f2b = (const float*)d_in[19],
              *encn_g = (const float*)d_in[20], *encn_b = (const float*)d_in[21],
              *up1W = (const float*)d_in[22], *up1b = (const float*)d_in[23],
              *up2W = (const float*)d_in[24], *up2b = (const float*)d_in[25],
              *r_n1g = (const float*)d_in[26], *r_n1b = (const float*)d_in[27],
              *r_qkvW = (const float*)d_in[28], *r_qkvb = (const float*)d_in[29],
              *r_projW = (const float*)d_in[30], *r_projb = (const float*)d_in[31],
              *r_n2g = (const float*)d_in[32], *r_n2b = (const float*)d_in[33],
              *r_f1W = (const float*)d_in[34], *r_f1b = (const float*)d_in[35],
              *r_f2W = (const float*)d_in[36], *r_f2b = (const float*)d_in[37],
              *hrn_g = (const float*)d_in[38], *hrn_b = (const float*)d_in[39],
              *dec_W = (const float*)d_in[40], *dec_b = (const float*)d_in[41];

  const int Bb = 16, NLR = 256, NHR = 512, Dm = 512, NHh = 8, FF = 2048, Ll = 4;
  typedef __hip_bfloat16 bf;

  float* ws = (float*)d_ws;
  float* H = ws;                                  // 4M fp32
  float* Hf = ws + 4194304;                       // 4M fp32
  bf* XNb = (bf*)(ws + 8388608);                  // 4M bf16
  bf* AOb = (bf*)(ws + 10485760);                 // 4M bf16 (Htb / Ttb / attn out)
  bf* BIGb = (bf*)(ws + 12582912);                // 16.78M bf16 (QKV slab / FFN hidden)
  bf* WB = (bf*)(ws + 20971520);                  // bf16 weights
  bf* Xlrb = (bf*)(ws + 29229056);                // 1.05M bf16 (X_lr, then A_lr bf16)

  size_t o = 0;
  bf* ipWt = WB + o;   o += (size_t)512 * 256;
  bf* eqkvT = WB + o;  o += (size_t)4 * 1536 * 512;
  bf* eprojT = WB + o; o += (size_t)4 * 512 * 512;
  bf* ef1T = WB + o;   o += (size_t)4 * 2048 * 512;
  bf* ef2T = WB + o;   o += (size_t)4 * 512 * 2048;
  bf* up1T = WB + o;   o += (size_t)512 * 256;
  bf* up2T = WB + o;   o += (size_t)512 * 512;
  bf* rqkvT = WB + o;  o += (size_t)1536 * 512;
  bf* rprojT = WB + o; o += (size_t)512 * 512;
  bf* rf1T = WB + o;   o += (size_t)2048 * 512;
  bf* rf2T = WB + o;   o += (size_t)512 * 2048;
  bf* Sb = WB + o;     o += (size_t)512 * 512;

  bf* Q_e = BIGb;
  bf* K_e = BIGb + 2097152;
  bf* V_e = BIGb + 4194304;
  bf* Q_r = BIGb;
  bf* K_r = BIGb + 4194304;
  bf* V_r = BIGb + 8388608;
  bf* Albrb = Xlrb;  // A_lr bf16 reuses Xlrb slot (dead after input projection)

  // ---- conversions ----
  tconv_kernel<<<dim3(16, 8, 1), 256, 0, stream>>>(ip_W, ipWt, 256, 512);
  tconv_kernel<<<dim3(48, 16, 4), 256, 0, stream>>>(e_qkvW, eqkvT, 512, 1536);
  tconv_kernel<<<dim3(16, 16, 4), 256, 0, stream>>>(e_projW, eprojT, 512, 512);
  tconv_kernel<<<dim3(64, 16, 4), 256, 0, stream>>>(e_f1W, ef1T, 512, 2048);
  tconv_kernel<<<dim3(16, 64, 4), 256, 0, stream>>>(e_f2W, ef2T, 2048, 512);
  tconv_kernel<<<dim3(16, 8, 1), 256, 0, stream>>>(up1W, up1T, 256, 512);
  tconv_kernel<<<dim3(16, 16, 1), 256, 0, stream>>>(up2W, up2T, 512, 512);
  tconv_kernel<<<dim3(48, 16, 1), 256, 0, stream>>>(r_qkvW, rqkvT, 512, 1536);
  tconv_kernel<<<dim3(16, 16, 1), 256, 0, stream>>>(r_projW, rprojT, 512, 512);
  tconv_kernel<<<dim3(64, 16, 1), 256, 0, stream>>>(r_f1W, rf1T, 512, 2048);
  tconv_kernel<<<dim3(16, 64, 1), 256, 0, stream>>>(r_f2W, rf2T, 2048, 512);
  conv_kernel<<<(1048576 + 255) / 256, 256, 0, stream>>>(X_lr, Xlrb, 1048576);
  build_s_kernel<<<(512 * 512 + 255) / 256, 256, 0, stream>>>(dec_W, Sb, Dm, 4);

  // ---- input projection ----
  mgemm_kernel<<<64 * 8, 256, 0, stream>>>(
      Xlrb, ipWt, ip_b, nullptr, Hf, nullptr, Bb * NLR, Dm, NLR, 0, 8);
  ln_kernel<<<Bb * NLR, 256, 0, stream>>>(Hf, H, nullptr, ip_g, ip_bt, Dm, 1);
  // Xlrb now dead -> convert A_lr into its slot
  conv_kernel<<<(1048576 + 255) / 256, 256, 0, stream>>>(A_lr, Albrb, 1048576);

  // ---- encoder ----  (M=4096: 64 m-tiles, mgrp=8)
  for (int l = 0; l < Ll; ++l) {
    ln_kernel<<<Bb * NLR, 256, 0, stream>>>(H, nullptr, XNb, e_n1g + l * Dm, e_n1b + l * Dm, Dm, 0);
    qkv_gemm_kernel<<<64 * 24, 256, 0, stream>>>(
        XNb, eqkvT + (size_t)l * 1536 * 512, e_qkvb + l * 1536, BIGb,
        Bb * NLR, Dm, NLR, 8, 8);
    fattn_kernel<<<16 * 8 * 4, 256, 0, stream>>>(
        Q_e, K_e, V_e, AOb, Albrb, e_ebW + l * NHh, e_ebs + l, NLR, 2);
    mgemm_kernel<<<64 * 8, 256, 0, stream>>>(
        AOb, eprojT + (size_t)l * 512 * 512, e_projb + l * Dm, H,
        H, nullptr, Bb * NLR, Dm, Dm, 0, 8);
    ln_kernel<<<Bb * NLR, 256, 0, stream>>>(H, nullptr, XNb, e_n2g + l * Dm, e_n2b + l * Dm, Dm, 0);
    mgemm_kernel<<<64 * 32, 256, 0, stream>>>(
        XNb, ef1T + (size_t)l * 2048 * 512, e_f1b + l * FF, nullptr,
        nullptr, BIGb, Bb * NLR, FF, Dm, 1, 8);
    mgemm_kernel<<<64 * 8, 256, 0, stream>>>(
        BIGb, ef2T + (size_t)l * 512 * 2048, e_f2b + l * Dm, H,
        H, nullptr, Bb * NLR, Dm, FF, 0, 8);
  }

  // ---- upsampler ----  (M=8192: 128 m-tiles, mgrp=16)
  ln_kernel<<<Bb * NLR, 256, 0, stream>>>(H, nullptr, XNb, encn_g, encn_b, Dm, 0);
  transpose_kernel<bf><<<dim3(16, 8, Bb), 256, 0, stream>>>(XNb, AOb, NLR, Dm);
  mgemm_kernel<<<128 * 8, 256, 0, stream>>>(
      AOb, up1T, up1b, nullptr, nullptr, BIGb, Bb * Dm, NHR, NLR, 1, 16);
  mgemm_kernel<<<128 * 8, 256, 0, stream>>>(
      BIGb, up2T, up2b, nullptr, Hf, nullptr, Bb * Dm, NHR, NHR, 0, 16);
  transpose_kernel<float><<<dim3(16, 16, Bb), 256, 0, stream>>>(Hf, H, Dm, NHR);

  // ---- refiner ----  (M=8192: mgrp=16)
  ln_kernel<<<Bb * NHR, 256, 0, stream>>>(H, nullptr, XNb, r_n1g, r_n1b, Dm, 0);
  qkv_gemm_kernel<<<128 * 24, 256, 0, stream>>>(
      XNb, rqkvT, r_qkvb, BIGb, Bb * NHR, Dm, NHR, 9, 16);
  fattn_kernel<<<16 * 8 * 8, 256, 0, stream>>>(
      Q_r, K_r, V_r, AOb, nullptr, nullptr, nullptr, NHR, 3);
  mgemm_kernel<<<128 * 8, 256, 0, stream>>>(
      AOb, rprojT, r_projb, H, H, nullptr, Bb * NHR, Dm, Dm, 0, 16);
  ln_kernel<<<Bb * NHR, 256, 0, stream>>>(H, nullptr, XNb, r_n2g, r_n2b, Dm, 0);
  mgemm_kernel<<<128 * 32, 256, 0, stream>>>(
      XNb, rf1T, r_f1b, nullptr, nullptr, BIGb, Bb * NHR, FF, Dm, 1, 16);
  mgemm_kernel<<<128 * 8, 256, 0, stream>>>(
      BIGb, rf2T, r_f2b, H, H, nullptr, Bb * NHR, Dm, FF, 0, 16);

  // ---- decoder ----
  ln_kernel<<<Bb * NHR, 256, 0, stream>>>(H, nullptr, XNb, hrn_g, hrn_b, Dm, 0);
  mgemm_kernel<<<128 * 8, 256, 0, stream>>>(
      XNb, Sb, nullptr, nullptr, nullptr, AOb, Bb * NHR, Dm, Dm, 0, 16);
  dec_mfma_kernel<<<dim3(36, Bb), 256, 0, stream>>>(
      AOb, XNb, dec_b, (float*)d_out);
}

// Round 10
// 901.438 us; speedup vs baseline: 7.1263x; 1.0107x over previous
//
#include <hip/hip_runtime.h>
#include <hip/hip_bf16.h>
#include <math.h>

#define DEV __device__ __forceinline__

typedef __attribute__((ext_vector_type(8))) short bf16x8;
typedef __attribute__((ext_vector_type(4))) float f32x4;

DEV float gelu_f(float x) { return 0.5f * x * (1.0f + erff(x * 0.70710678118654752f)); }

DEV float block_reduce(float v, bool is_sum, float* red) {
#pragma unroll
  for (int off = 32; off > 0; off >>= 1) {
    float o = __shfl_down(v, off, 64);
    v = is_sum ? (v + o) : fmaxf(v, o);
  }
  __syncthreads();
  if ((threadIdx.x & 63) == 0) red[threadIdx.x >> 6] = v;
  __syncthreads();
  return is_sum ? (red[0] + red[1] + red[2] + red[3])
                : fmaxf(fmaxf(red[0], red[1]), fmaxf(red[2], red[3]));
}

DEV short bf16s(float x) {
  __hip_bfloat16 v = __float2bfloat16(x);
  return *reinterpret_cast<short*>(&v);
}

// async 16B global->LDS (gfx950). dest = wave-uniform base + lane*16.
DEV void async16(void* lds, const void* g) {
  __builtin_amdgcn_global_load_lds(
      (const __attribute__((address_space(1))) unsigned int*)g,
      (__attribute__((address_space(3))) unsigned int*)lds, 16, 0, 0);
}

// ---------- fused conversions ----------
__global__ __launch_bounds__(256) void conv2_kernel(
    const float* __restrict__ X1, __hip_bfloat16* __restrict__ Y1,
    const float* __restrict__ X2, __hip_bfloat16* __restrict__ Y2, int n) {
  int i = blockIdx.x * 256 + threadIdx.x;
  if (i < n) {
    Y1[i] = __float2bfloat16(X1[i]);
    Y2[i] = __float2bfloat16(X2[i]);
  }
}

struct CvArgs {
  const float* s[11];
  __hip_bfloat16* d[11];
};

// one kernel for all 11 weight transposes (fp32 RxC -> bf16 CxR, batched)
__global__ __launch_bounds__(256) void multi_tconv_kernel(CvArgs a) {
  const int Rj[11] = {256, 512, 512, 512, 2048, 256, 512, 512, 512, 512, 2048};
  const int Cj[11] = {512, 1536, 512, 2048, 512, 512, 512, 1536, 512, 2048, 512};
  const int Nj[11] = {1, 4, 4, 4, 4, 1, 1, 1, 1, 1, 1};
  __shared__ float t[32][33];
  int rem = blockIdx.x, j = 0;
  for (; j < 11; ++j) {
    int tj = (Rj[j] >> 5) * (Cj[j] >> 5) * Nj[j];
    if (rem < tj) break;
    rem -= tj;
  }
  const int R = Rj[j], C = Cj[j];
  const int perb = (R >> 5) * (C >> 5);
  const int z = rem / perb;
  const int tt = rem % perb;
  const int tc = C >> 5;
  const int r0 = (tt / tc) << 5, c0 = (tt % tc) << 5;
  const float* xb = a.s[j] + (size_t)z * R * C;
  __hip_bfloat16* yb = a.d[j] + (size_t)z * R * C;
  int tx = threadIdx.x & 31, ty = threadIdx.x >> 5;
  for (int i = ty; i < 32; i += 8) t[i][tx] = xb[(size_t)(r0 + i) * C + c0 + tx];
  __syncthreads();
  for (int i = ty; i < 32; i += 8)
    yb[(size_t)(c0 + i) * R + r0 + tx] = __float2bfloat16(t[tx][i]);
}

__global__ __launch_bounds__(256) void build_s_kernel(
    const float* __restrict__ W, __hip_bfloat16* __restrict__ S, int D, int Kk) {
  int i = blockIdx.x * 256 + threadIdx.x;
  if (i >= D * D) return;
  int d = i / D, e = i % D;
  float s = 0.f;
  for (int k = 0; k < Kk; ++k) {
    s += W[(size_t)k * D * D + i];
    s += W[(size_t)k * D * D + (size_t)e * D + d];
  }
  S[i] = __float2bfloat16(s / (2.0f * Kk));
}

// ---------- MFMA GEMM: 64x64, dbuf async staging, swizzled LDS, XCD-local ----------
__global__ __launch_bounds__(256) void mgemm_kernel(
    const __hip_bfloat16* __restrict__ A, const __hip_bfloat16* __restrict__ Bt,
    const float* __restrict__ bias, const float* __restrict__ resid,
    float* __restrict__ outf, __hip_bfloat16* __restrict__ outb,
    int M, int N, int K, int act, int mgrp) {
  __shared__ __align__(16) short As[2][64 * 64];
  __shared__ __align__(16) short Bs[2][64 * 64];
  const int tid = threadIdx.x;
  const int lane = tid & 63, wave = tid >> 6;
  const int quad = lane >> 4, l15 = lane & 15;
  const int bid = blockIdx.x;
  const int g = bid & 7, sidx = bid >> 3;
  const int mt = g * mgrp + sidx % mgrp;
  const int nt = sidx / mgrp;
  const int row0 = mt * 64, col0 = nt * 64;
  const short* Ag = (const short*)A;
  const short* Bg = (const short*)Bt;

  auto stage = [&](int bsel, int k0) {
#pragma unroll
    for (int i = 0; i < 2; ++i) {
      int c = (wave * 2 + i) * 64 + lane;
      int r = c >> 3, pp = c & 7;
      int kc = pp ^ (r & 7);
      async16(&As[bsel][(wave * 2 + i) * 512], &Ag[(size_t)(row0 + r) * K + k0 + kc * 8]);
      async16(&Bs[bsel][(wave * 2 + i) * 512], &Bg[(size_t)(col0 + r) * K + k0 + kc * 8]);
    }
  };

  f32x4 acc[4] = {};
  const int nk = K >> 6;
  stage(0, 0);
  for (int t = 0; t < nk; ++t) {
    const int cur = t & 1;
    __syncthreads();  // drains loads for buf cur
    if (t + 1 < nk) stage(cur ^ 1, (t + 1) << 6);  // overlaps compute below
#pragma unroll
    for (int kh = 0; kh < 2; ++kh) {
      const int ch = ((quad + kh * 4) ^ (l15 & 7)) * 8;
      bf16x8 af = *(const bf16x8*)&As[cur][(wave * 16 + l15) * 64 + ch];
#pragma unroll
      for (int ni = 0; ni < 4; ++ni) {
        bf16x8 bq = *(const bf16x8*)&Bs[cur][(ni * 16 + l15) * 64 + ch];
        acc[ni] = __builtin_amdgcn_mfma_f32_16x16x32_bf16(af, bq, acc[ni], 0, 0, 0);
      }
    }
  }

#pragma unroll
  for (int ni = 0; ni < 4; ++ni) {
    int cc = col0 + ni * 16 + l15;
    float bb = bias ? bias[cc] : 0.f;
#pragma unroll
    for (int r = 0; r < 4; ++r) {
      int rr = row0 + wave * 16 + quad * 4 + r;
      size_t idx = (size_t)rr * N + cc;
      float v = acc[ni][r] + bb;
      if (act) v = gelu_f(v);
      if (resid) v += resid[idx];
      if (outf) outf[idx] = v;
      if (outb) outb[idx] = __float2bfloat16(v);
    }
  }
}

// ---------- QKV GEMM (64x64, dbuf) with head-layout scatter epilogue ----------
__global__ __launch_bounds__(256) void qkv_gemm_kernel(
    const __hip_bfloat16* __restrict__ A, const __hip_bfloat16* __restrict__ Bt,
    const float* __restrict__ bias, __hip_bfloat16* __restrict__ qkv,
    int M, int K, int nseq, int lgn, int mgrp) {
  __shared__ __align__(16) short As[2][64 * 64];
  __shared__ __align__(16) short Bs[2][64 * 64];
  const int tid = threadIdx.x;
  const int lane = tid & 63, wave = tid >> 6;
  const int quad = lane >> 4, l15 = lane & 15;
  const int bid = blockIdx.x;
  const int g = bid & 7, sidx = bid >> 3;
  const int mt = g * mgrp + sidx % mgrp;
  const int nt = sidx / mgrp;
  const int row0 = mt * 64, col0 = nt * 64;
  const short* Ag = (const short*)A;
  const short* Bg = (const short*)Bt;

  auto stage = [&](int bsel, int k0) {
#pragma unroll
    for (int i = 0; i < 2; ++i) {
      int c = (wave * 2 + i) * 64 + lane;
      int r = c >> 3, pp = c & 7;
      int kc = pp ^ (r & 7);
      async16(&As[bsel][(wave * 2 + i) * 512], &Ag[(size_t)(row0 + r) * K + k0 + kc * 8]);
      async16(&Bs[bsel][(wave * 2 + i) * 512], &Bg[(size_t)(col0 + r) * K + k0 + kc * 8]);
    }
  };

  f32x4 acc[4] = {};
  const int nk = K >> 6;
  stage(0, 0);
  for (int t = 0; t < nk; ++t) {
    const int cur = t & 1;
    __syncthreads();
    if (t + 1 < nk) stage(cur ^ 1, (t + 1) << 6);
#pragma unroll
    for (int kh = 0; kh < 2; ++kh) {
      const int ch = ((quad + kh * 4) ^ (l15 & 7)) * 8;
      bf16x8 af = *(const bf16x8*)&As[cur][(wave * 16 + l15) * 64 + ch];
#pragma unroll
      for (int ni = 0; ni < 4; ++ni) {
        bf16x8 bq = *(const bf16x8*)&Bs[cur][(ni * 16 + l15) * 64 + ch];
        acc[ni] = __builtin_amdgcn_mfma_f32_16x16x32_bf16(af, bq, acc[ni], 0, 0, 0);
      }
    }
  }

  const size_t PART = (size_t)M * 512;
#pragma unroll
  for (int ni = 0; ni < 4; ++ni) {
    int cc = col0 + ni * 16 + l15;  // 0..1535
    float bb = bias ? bias[cc] : 0.f;
    int which = cc >> 9;
    int h = (cc >> 6) & 7;
    int d = cc & 63;
#pragma unroll
    for (int r = 0; r < 4; ++r) {
      int rr = row0 + wave * 16 + quad * 4 + r;
      int b = rr >> lgn;
      int nn = rr & (nseq - 1);
      float v = acc[ni][r] + bb;
      size_t dst;
      if (which == 2) {
        dst = 2 * PART + (((size_t)b * 8 + h) * 64 + d) * nseq + nn;
      } else {
        dst = (size_t)which * PART + (((size_t)b * 8 + h) * nseq + nn) * 64 + d;
      }
      qkv[dst] = __float2bfloat16(v);
    }
  }
}

// ---------- fused flash attention (MFMA, dbuf K/V staging, XCD-local) ----------
__global__ __launch_bounds__(256) void fattn_kernel(
    const __hip_bfloat16* __restrict__ Qh, const __hip_bfloat16* __restrict__ Kh,
    const __hip_bfloat16* __restrict__ Vt, __hip_bfloat16* __restrict__ O,
    const __hip_bfloat16* __restrict__ Abias, const float* __restrict__ ebW,
    const float* __restrict__ ebs, int N, int lgq) {
  __shared__ __align__(16) short Ks[2][64 * 64];
  __shared__ __align__(16) short Vs[2][64 * 64];
  __shared__ __align__(16) short Ps[4][16][72];
  const int bid = blockIdx.x;
  const int g = bid & 7, s = bid >> 3;
  const int bloc = s >> (lgq + 3);
  const int rem = s & ((8 << lgq) - 1);
  const int h = rem >> lgq;
  const int qt = rem & ((1 << lgq) - 1);
  const int b = g * 2 + bloc;
  const int tid = threadIdx.x, lane = tid & 63, wave = tid >> 6;
  const int quad = lane >> 4, l15 = lane & 15;
  const size_t hb = (size_t)b * 8 + h;
  const short* Qg = (const short*)Qh + hb * N * 64;
  const short* Kg = (const short*)Kh + hb * N * 64;
  const short* Vg = (const short*)Vt + hb * 64 * N;
  const float scale = 0.125f;
  const bool hasb = (Abias != nullptr);
  const float bscale = hasb ? ebs[0] * ebW[h] : 0.f;
  const int qrow_w = qt * 64 + wave * 16;

  auto stageKV = [&](int bsel, int k0) {
#pragma unroll
    for (int i = 0; i < 2; ++i) {
      int c = (wave * 2 + i) * 64 + lane;
      int r = c >> 3, pp = c & 7;
      int kc = pp ^ (r & 7);
      async16(&Ks[bsel][(wave * 2 + i) * 512], &Kg[(size_t)(k0 + r) * 64 + kc * 8]);
      async16(&Vs[bsel][(wave * 2 + i) * 512], &Vg[(size_t)r * N + k0 + kc * 8]);
    }
  };

  bf16x8 qf[2];
  qf[0] = *(const bf16x8*)&Qg[(size_t)(qrow_w + l15) * 64 + quad * 8];
  qf[1] = *(const bf16x8*)&Qg[(size_t)(qrow_w + l15) * 64 + quad * 8 + 32];

  float m_i[4], l_i[4];
  f32x4 oacc[4] = {};
#pragma unroll
  for (int r = 0; r < 4; ++r) { m_i[r] = -1e30f; l_i[r] = 0.f; }

  const int ntl = N >> 6;
  stageKV(0, 0);
  for (int t = 0; t < ntl; ++t) {
    const int cur = t & 1;
    const int k0 = t << 6;
    __syncthreads();
    if (t + 1 < ntl) stageKV(cur ^ 1, (t + 1) << 6);

    f32x4 sv[4] = {};
#pragma unroll
    for (int kh = 0; kh < 2; ++kh) {
      const int ch = ((quad + kh * 4) ^ (l15 & 7)) * 8;
#pragma unroll
      for (int ni = 0; ni < 4; ++ni) {
        bf16x8 kf = *(const bf16x8*)&Ks[cur][(ni * 16 + l15) * 64 + ch];
        sv[ni] = __builtin_amdgcn_mfma_f32_16x16x32_bf16(qf[kh], kf, sv[ni], 0, 0, 0);
      }
    }
    if (hasb) {
#pragma unroll
      for (int ni = 0; ni < 4; ++ni)
#pragma unroll
        for (int r = 0; r < 4; ++r) {
          int qq = qrow_w + quad * 4 + r;
          int kk = k0 + ni * 16 + l15;
          float ab = __bfloat162float(Abias[((size_t)b * N + qq) * N + kk]);
          sv[ni][r] = sv[ni][r] * scale + bscale * ab;
        }
    } else {
#pragma unroll
      for (int ni = 0; ni < 4; ++ni)
#pragma unroll
        for (int r = 0; r < 4; ++r) sv[ni][r] *= scale;
    }

    float mt[4];
#pragma unroll
    for (int r = 0; r < 4; ++r)
      mt[r] = fmaxf(fmaxf(sv[0][r], sv[1][r]), fmaxf(sv[2][r], sv[3][r]));
#pragma unroll
    for (int off = 1; off < 16; off <<= 1)
#pragma unroll
      for (int r = 0; r < 4; ++r) mt[r] = fmaxf(mt[r], __shfl_xor(mt[r], off, 64));

    float alpha[4];
#pragma unroll
    for (int r = 0; r < 4; ++r) {
      float mn = fmaxf(m_i[r], mt[r]);
      alpha[r] = __expf(m_i[r] - mn);
      m_i[r] = mn;
    }
    float ls[4] = {0.f, 0.f, 0.f, 0.f};
#pragma unroll
    for (int ni = 0; ni < 4; ++ni)
#pragma unroll
      for (int r = 0; r < 4; ++r) {
        float p = __expf(sv[ni][r] - m_i[r]);
        sv[ni][r] = p;
        ls[r] += p;
      }
#pragma unroll
    for (int off = 1; off < 16; off <<= 1)
#pragma unroll
      for (int r = 0; r < 4; ++r) ls[r] += __shfl_xor(ls[r], off, 64);
#pragma unroll
    for (int r = 0; r < 4; ++r) l_i[r] = l_i[r] * alpha[r] + ls[r];
#pragma unroll
    for (int ni = 0; ni < 4; ++ni)
#pragma unroll
      for (int r = 0; r < 4; ++r) oacc[ni][r] *= alpha[r];

#pragma unroll
    for (int ni = 0; ni < 4; ++ni)
#pragma unroll
      for (int r = 0; r < 4; ++r)
        Ps[wave][quad * 4 + r][ni * 16 + l15] = bf16s(sv[ni][r]);

    bf16x8 pf0 = *(const bf16x8*)&Ps[wave][l15][quad * 8];
    bf16x8 pf1 = *(const bf16x8*)&Ps[wave][l15][quad * 8 + 32];
#pragma unroll
    for (int kh = 0; kh < 2; ++kh) {
      const int ch = ((quad + kh * 4) ^ (l15 & 7)) * 8;
#pragma unroll
      for (int ni = 0; ni < 4; ++ni) {
        bf16x8 vf = *(const bf16x8*)&Vs[cur][(ni * 16 + l15) * 64 + ch];
        oacc[ni] = __builtin_amdgcn_mfma_f32_16x16x32_bf16(kh ? pf1 : pf0, vf, oacc[ni], 0, 0, 0);
      }
    }
  }

  float inv[4];
#pragma unroll
  for (int r = 0; r < 4; ++r) inv[r] = 1.f / l_i[r];
#pragma unroll
  for (int ni = 0; ni < 4; ++ni)
#pragma unroll
    for (int r = 0; r < 4; ++r) {
      int nn = qrow_w + quad * 4 + r;
      int col = h * 64 + ni * 16 + l15;
      O[((size_t)b * N + nn) * 512 + col] = __float2bfloat16(oacc[ni][r] * inv[r]);
    }
}

// ---------- decoder: 64x64 tiles (dbuf), 36 triu pairs x 16 batches ----------
__global__ __launch_bounds__(256) void dec_mfma_kernel(
    const __hip_bfloat16* __restrict__ Tb_, const __hip_bfloat16* __restrict__ Hb_,
    const float* __restrict__ dec_b, float* __restrict__ out) {
  const int Nn = 512, K = 512;
  __shared__ __align__(16) short As[2][64 * 64];
  __shared__ __align__(16) short Bs[2][64 * 64];
  int p = blockIdx.x;  // 0..35
  int bb = blockIdx.y;
  int it = 0, rem = p;
  while (rem >= 8 - it) { rem -= 8 - it; ++it; }
  int jt = it + rem;
  const int row0 = it * 64, col0 = jt * 64;
  const int tid = threadIdx.x;
  const int lane = tid & 63, wave = tid >> 6;
  const int quad = lane >> 4, l15 = lane & 15;
  const int wr = (wave >> 1) * 32, wc = (wave & 1) * 32;
  const short* Ag = (const short*)(Tb_ + (size_t)bb * Nn * K);
  const short* Bg = (const short*)(Hb_ + (size_t)bb * Nn * K);

  auto stage = [&](int bsel, int k0) {
#pragma unroll
    for (int i = 0; i < 2; ++i) {
      int c = (wave * 2 + i) * 64 + lane;
      int r = c >> 3, pp = c & 7;
      int kc = pp ^ (r & 7);
      async16(&As[bsel][(wave * 2 + i) * 512], &Ag[(size_t)(row0 + r) * K + k0 + kc * 8]);
      async16(&Bs[bsel][(wave * 2 + i) * 512], &Bg[(size_t)(col0 + r) * K + k0 + kc * 8]);
    }
  };

  f32x4 acc[2][2] = {};
  const int nk = K >> 6;
  stage(0, 0);
  for (int t = 0; t < nk; ++t) {
    const int cur = t & 1;
    __syncthreads();
    if (t + 1 < nk) stage(cur ^ 1, (t + 1) << 6);
#pragma unroll
    for (int kh = 0; kh < 2; ++kh) {
      const int ch = ((quad + kh * 4) ^ (l15 & 7)) * 8;
      bf16x8 af[2], bq[2];
#pragma unroll
      for (int mi = 0; mi < 2; ++mi)
        af[mi] = *(const bf16x8*)&As[cur][(wr + mi * 16 + l15) * 64 + ch];
#pragma unroll
      for (int ni = 0; ni < 2; ++ni)
        bq[ni] = *(const bf16x8*)&Bs[cur][(wc + ni * 16 + l15) * 64 + ch];
#pragma unroll
      for (int mi = 0; mi < 2; ++mi)
#pragma unroll
        for (int ni = 0; ni < 2; ++ni)
          acc[mi][ni] = __builtin_amdgcn_mfma_f32_16x16x32_bf16(af[mi], bq[ni], acc[mi][ni], 0, 0, 0);
    }
  }

  float db = dec_b[0];
  size_t obase = (size_t)bb * ((size_t)Nn * (Nn - 1) / 2);
#pragma unroll
  for (int mi = 0; mi < 2; ++mi) {
#pragma unroll
    for (int ni = 0; ni < 2; ++ni) {
      int j = col0 + wc + ni * 16 + l15;
#pragma unroll
      for (int r = 0; r < 4; ++r) {
        int i = row0 + wr + mi * 16 + quad * 4 + r;
        if (j > i) {
          float x = acc[mi][ni][r] + db;
          float sp = fmaxf(x, 0.f) + __logf(1.f + __expf(-fabsf(x)));
          out[obase + (size_t)i * (2 * Nn - i - 1) / 2 + (j - i - 1)] = sp;
        }
      }
    }
  }
}

// ---------- LayerNorm ----------
__global__ __launch_bounds__(256) void ln_kernel(
    const float* __restrict__ X, float* __restrict__ outf,
    __hip_bfloat16* __restrict__ outb, const float* __restrict__ g,
    const float* __restrict__ b, int D, int do_gelu) {
  __shared__ float red[4];
  int row = blockIdx.x;
  const float* x = X + (size_t)row * D;
  float s = 0.f, s2 = 0.f;
  for (int d = threadIdx.x; d < D; d += 256) {
    float v = x[d];
    s += v;
    s2 += v * v;
  }
  s = block_reduce(s, true, red);
  s2 = block_reduce(s2, true, red);
  float mean = s / D;
  float var = s2 / D - mean * mean;
  float inv = rsqrtf(var + 1e-5f);
  for (int d = threadIdx.x; d < D; d += 256) {
    float v = (x[d] - mean) * inv * g[d] + b[d];
    if (do_gelu) v = gelu_f(v);
    if (outf) outf[(size_t)row * D + d] = v;
    if (outb) outb[(size_t)row * D + d] = __float2bfloat16(v);
  }
}

// ---------- batched transpose ----------
template <typename T>
__global__ __launch_bounds__(256) void transpose_kernel(
    const T* __restrict__ X, T* __restrict__ Y, int R, int C) {
  __shared__ T t[32][33];
  const T* xb = X + (size_t)blockIdx.z * R * C;
  T* yb = Y + (size_t)blockIdx.z * R * C;
  int c0 = blockIdx.x * 32, r0 = blockIdx.y * 32;
  int tx = threadIdx.x & 31, ty = threadIdx.x >> 5;
  for (int i = ty; i < 32; i += 8) t[i][tx] = xb[(size_t)(r0 + i) * C + c0 + tx];
  __syncthreads();
  for (int i = ty; i < 32; i += 8) yb[(size_t)(c0 + i) * R + r0 + tx] = t[tx][i];
}

// ---------- host ----------
extern "C" void kernel_launch(void* const* d_in, const int* in_sizes, int n_in,
                              void* d_out, int out_size, void* d_ws, size_t ws_size,
                              hipStream_t stream) {
  const float *A_lr = (const float*)d_in[0], *X_lr = (const float*)d_in[1],
              *ip_W = (const float*)d_in[2], *ip_b = (const float*)d_in[3],
              *ip_g = (const float*)d_in[4], *ip_bt = (const float*)d_in[5],
              *e_n1g = (const float*)d_in[6], *e_n1b = (const float*)d_in[7],
              *e_qkvW = (const float*)d_in[8], *e_qkvb = (const float*)d_in[9],
              *e_projW = (const float*)d_in[10], *e_projb = (const float*)d_in[11],
              *e_ebW = (const float*)d_in[12], *e_ebs = (const float*)d_in[13],
              *e_n2g = (const float*)d_in[14], *e_n2b = (const float*)d_in[15],
              *e_f1W = (const float*)d_in[16], *e_f1b = (const float*)d_in[17],
              *e_f2W = (const float*)d_in[18], *e_f2b = (const float*)d_in[19],
              *encn_g = (const float*)d_in[20], *encn_b = (const float*)d_in[21],
              *up1W = (const float*)d_in[22], *up1b = (const float*)d_in[23],
              *up2W = (const float*)d_in[24], *up2b = (const float*)d_in[25],
              *r_n1g = (const float*)d_in[26], *r_n1b = (const float*)d_in[27],
              *r_qkvW = (const float*)d_in[28], *r_qkvb = (const float*)d_in[29],
              *r_projW = (const float*)d_in[30], *r_projb = (const float*)d_in[31],
              *r_n2g = (const float*)d_in[32], *r_n2b = (const float*)d_in[33],
              *r_f1W = (const float*)d_in[34], *r_f1b = (const float*)d_in[35],
              *r_f2W = (const float*)d_in[36], *r_f2b = (const float*)d_in[37],
              *hrn_g = (const float*)d_in[38], *hrn_b = (const float*)d_in[39],
              *dec_W = (const float*)d_in[40], *dec_b = (const float*)d_in[41];

  const int Bb = 16, NLR = 256, NHR = 512, Dm = 512, NHh = 8, FF = 2048, Ll = 4;
  typedef __hip_bfloat16 bf;

  float* ws = (float*)d_ws;
  float* H = ws;                                  // 4M fp32
  float* Hf = ws + 4194304;                       // 4M fp32
  bf* XNb = (bf*)(ws + 8388608);                  // 4M bf16
  bf* AOb = (bf*)(ws + 10485760);                 // 4M bf16 (Htb / Ttb / attn out)
  bf* BIGb = (bf*)(ws + 12582912);                // 16.78M bf16 (QKV slab / FFN hidden)
  bf* WB = (bf*)(ws + 20971520);                  // bf16 weights
  bf* Xlrb = (bf*)(ws + 29229056);                // 1.05M bf16
  bf* Albrb = (bf*)(ws + 29753344);               // 1.05M bf16 (A_lr)

  size_t o = 0;
  bf* ipWt = WB + o;   o += (size_t)512 * 256;
  bf* eqkvT = WB + o;  o += (size_t)4 * 1536 * 512;
  bf* eprojT = WB + o; o += (size_t)4 * 512 * 512;
  bf* ef1T = WB + o;   o += (size_t)4 * 2048 * 512;
  bf* ef2T = WB + o;   o += (size_t)4 * 512 * 2048;
  bf* up1T = WB + o;   o += (size_t)512 * 256;
  bf* up2T = WB + o;   o += (size_t)512 * 512;
  bf* rqkvT = WB + o;  o += (size_t)1536 * 512;
  bf* rprojT = WB + o; o += (size_t)512 * 512;
  bf* rf1T = WB + o;   o += (size_t)2048 * 512;
  bf* rf2T = WB + o;   o += (size_t)512 * 2048;
  bf* Sb = WB + o;     o += (size_t)512 * 512;

  bf* Q_e = BIGb;
  bf* K_e = BIGb + 2097152;
  bf* V_e = BIGb + 4194304;
  bf* Q_r = BIGb;
  bf* K_r = BIGb + 4194304;
  bf* V_r = BIGb + 8388608;

  // ---- conversions (3 dispatches) ----
  CvArgs cv;
  cv.s[0] = ip_W;   cv.d[0] = ipWt;
  cv.s[1] = e_qkvW; cv.d[1] = eqkvT;
  cv.s[2] = e_projW; cv.d[2] = eprojT;
  cv.s[3] = e_f1W;  cv.d[3] = ef1T;
  cv.s[4] = e_f2W;  cv.d[4] = ef2T;
  cv.s[5] = up1W;   cv.d[5] = up1T;
  cv.s[6] = up2W;   cv.d[6] = up2T;
  cv.s[7] = r_qkvW; cv.d[7] = rqkvT;
  cv.s[8] = r_projW; cv.d[8] = rprojT;
  cv.s[9] = r_f1W;  cv.d[9] = rf1T;
  cv.s[10] = r_f2W; cv.d[10] = rf2T;
  multi_tconv_kernel<<<15872, 256, 0, stream>>>(cv);
  conv2_kernel<<<(1048576 + 255) / 256, 256, 0, stream>>>(
      X_lr, Xlrb, A_lr, Albrb, 1048576);
  build_s_kernel<<<(512 * 512 + 255) / 256, 256, 0, stream>>>(dec_W, Sb, Dm, 4);

  // ---- input projection ----
  mgemm_kernel<<<64 * 8, 256, 0, stream>>>(
      Xlrb, ipWt, ip_b, nullptr, Hf, nullptr, Bb * NLR, Dm, NLR, 0, 8);
  ln_kernel<<<Bb * NLR, 256, 0, stream>>>(Hf, H, nullptr, ip_g, ip_bt, Dm, 1);

  // ---- encoder ----  (M=4096: 64 m-tiles, mgrp=8)
  for (int l = 0; l < Ll; ++l) {
    ln_kernel<<<Bb * NLR, 256, 0, stream>>>(H, nullptr, XNb, e_n1g + l * Dm, e_n1b + l * Dm, Dm, 0);
    qkv_gemm_kernel<<<64 * 24, 256, 0, stream>>>(
        XNb, eqkvT + (size_t)l * 1536 * 512, e_qkvb + l * 1536, BIGb,
        Bb * NLR, Dm, NLR, 8, 8);
    fattn_kernel<<<16 * 8 * 4, 256, 0, stream>>>(
        Q_e, K_e, V_e, AOb, Albrb, e_ebW + l * NHh, e_ebs + l, NLR, 2);
    mgemm_kernel<<<64 * 8, 256, 0, stream>>>(
        AOb, eprojT + (size_t)l * 512 * 512, e_projb + l * Dm, H,
        H, nullptr, Bb * NLR, Dm, Dm, 0, 8);
    ln_kernel<<<Bb * NLR, 256, 0, stream>>>(H, nullptr, XNb, e_n2g + l * Dm, e_n2b + l * Dm, Dm, 0);
    mgemm_kernel<<<64 * 32, 256, 0, stream>>>(
        XNb, ef1T + (size_t)l * 2048 * 512, e_f1b + l * FF, nullptr,
        nullptr, BIGb, Bb * NLR, FF, Dm, 1, 8);
    mgemm_kernel<<<64 * 8, 256, 0, stream>>>(
        BIGb, ef2T + (size_t)l * 512 * 2048, e_f2b + l * Dm, H,
        H, nullptr, Bb * NLR, Dm, FF, 0, 8);
  }

  // ---- upsampler ----  (M=8192: 128 m-tiles, mgrp=16)
  ln_kernel<<<Bb * NLR, 256, 0, stream>>>(H, nullptr, XNb, encn_g, encn_b, Dm, 0);
  transpose_kernel<bf><<<dim3(16, 8, Bb), 256, 0, stream>>>(XNb, AOb, NLR, Dm);
  mgemm_kernel<<<128 * 8, 256, 0, stream>>>(
      AOb, up1T, up1b, nullptr, nullptr, BIGb, Bb * Dm, NHR, NLR, 1, 16);
  mgemm_kernel<<<128 * 8, 256, 0, stream>>>(
      BIGb, up2T, up2b, nullptr, Hf, nullptr, Bb * Dm, NHR, NHR, 0, 16);
  transpose_kernel<float><<<dim3(16, 16, Bb), 256, 0, stream>>>(Hf, H, Dm, NHR);

  // ---- refiner ----  (M=8192: mgrp=16)
  ln_kernel<<<Bb * NHR, 256, 0, stream>>>(H, nullptr, XNb, r_n1g, r_n1b, Dm, 0);
  qkv_gemm_kernel<<<128 * 24, 256, 0, stream>>>(
      XNb, rqkvT, r_qkvb, BIGb, Bb * NHR, Dm, NHR, 9, 16);
  fattn_kernel<<<16 * 8 * 8, 256, 0, stream>>>(
      Q_r, K_r, V_r, AOb, nullptr, nullptr, nullptr, NHR, 3);
  mgemm_kernel<<<128 * 8, 256, 0, stream>>>(
      AOb, rprojT, r_projb, H, H, nullptr, Bb * NHR, Dm, Dm, 0, 16);
  ln_kernel<<<Bb * NHR, 256, 0, stream>>>(H, nullptr, XNb, r_n2g, r_n2b, Dm, 0);
  mgemm_kernel<<<128 * 32, 256, 0, stream>>>(
      XNb, rf1T, r_f1b, nullptr, nullptr, BIGb, Bb * NHR, FF, Dm, 1, 16);
  mgemm_kernel<<<128 * 8, 256, 0, stream>>>(
      BIGb, rf2T, r_f2b, H, H, nullptr, Bb * NHR, Dm, FF, 0, 16);

  // ---- decoder ----
  ln_kernel<<<Bb * NHR, 256, 0, stream>>>(H, nullptr, XNb, hrn_g, hrn_b, Dm, 0);
  mgemm_kernel<<<128 * 8, 256, 0, stream>>>(
      XNb, Sb, nullptr, nullptr, nullptr, AOb, Bb * NHR, Dm, Dm, 0, 16);
  dec_mfma_kernel<<<dim3(36, Bb), 256, 0, stream>>>(
      AOb, XNb, dec_b, (float*)d_out);
}